// Round 1
// baseline (285.877 us; speedup 1.0000x reference)
//
#include <hip/hip_runtime.h>

#define ND   2048
#define BB   16384

typedef unsigned short u16;
typedef unsigned int u32;
typedef __attribute__((ext_vector_type(8))) short short8;
typedef __attribute__((ext_vector_type(4))) float f32x4;

__device__ inline float bf2f(u16 u) {
    union { u32 i; float f; } v; v.i = ((u32)u) << 16; return v.f;
}
__device__ inline u16 f2bf(float f) {
    union { float f; u32 i; } v; v.f = f;
    u32 i = v.i + 0x7fffu + ((v.i >> 16) & 1u);
    return (u16)(i >> 16);
}
__device__ inline float seluf(float x) {
    const float sc = 1.0507009873554805f, al = 1.6732632423543772f;
    return x > 0.f ? sc * x : sc * al * expm1f(x);
}
__device__ inline short8 packbf8(float4 f0, float4 f1) {
    short8 a;
    a[0] = (short)f2bf(f0.x); a[1] = (short)f2bf(f0.y);
    a[2] = (short)f2bf(f0.z); a[3] = (short)f2bf(f0.w);
    a[4] = (short)f2bf(f1.x); a[5] = (short)f2bf(f1.y);
    a[6] = (short)f2bf(f1.z); a[7] = (short)f2bf(f1.w);
    return a;
}

// ---------------- dtype sniffer ----------------
__global__ void detectk(const void* __restrict__ demb, u32* __restrict__ flag) {
    const u16* p = (const u16*)demb;
    int tid = threadIdx.x;  // 256
    int sane = 0;
    #pragma unroll
    for (int i = 0; i < 2; i++) {
        u16 u = p[4 * tid + 2 * i];
        int e = (u >> 7) & 0xFF;
        if (u == 0 || (e >= 0x66 && e <= 0x8C)) sane++;
    }
    __shared__ int red[256];
    red[tid] = sane; __syncthreads();
    for (int o = 128; o > 0; o >>= 1) {
        if (tid < o) red[tid] += red[tid + o];
        __syncthreads();
    }
    if (tid == 0) flag[0] = (red[0] < 300) ? 1u : 0u;
}

// ---------------- canonical bf16 conversion (26 segments, one launch) -------
#define NSEG 26
struct CvtArgs { const void* src[NSEG]; int off[NSEG]; int n[NSEG]; };

__global__ __launch_bounds__(256) void cvtk(CvtArgs a, u16* __restrict__ base,
                                            const u32* __restrict__ flag) {
    int seg = blockIdx.y;
    int n = a.n[seg];
    const void* s = a.src[seg];
    u16* d = base + a.off[seg];
    bool f32 = flag[0] != 0;
    int stride = gridDim.x * blockDim.x;
    for (int i = blockIdx.x * blockDim.x + threadIdx.x; i < n; i += stride)
        d[i] = f32 ? f2bf(((const float*)s)[i]) : ((const u16*)s)[i];
}

// ---------------- transpose (bf16, tiled 32x32) ----------------
__device__ inline void tpose_body(const u16* in, int R, int C,
                                  u16* out, int ldo, int ooff,
                                  u16 (*tile)[33]) {
    int c0 = blockIdx.x * 32, r0 = blockIdx.y * 32;
    int x = c0 + threadIdx.x;
    for (int i = threadIdx.y; i < 32; i += 8) {
        int r = r0 + i;
        tile[i][threadIdx.x] = (r < R && x < C) ? in[(size_t)r * C + x] : (u16)0;
    }
    __syncthreads();
    int rr = r0 + threadIdx.x;
    for (int i = threadIdx.y; i < 32; i += 8) {
        int cc = c0 + i;
        if (cc < C && rr < R) out[(size_t)cc * ldo + ooff + rr] = tile[threadIdx.x][i];
    }
}

__global__ void tpose_smalls(const u16* s0, const u16* s1, const u16* s2,
                             const u16* s3, const u16* s4, const u16* s5,
                             u16* W1T, u16* W2T, u16* WcTe, u16* WcTp) {
    __shared__ u16 tile[32][33];
    const u16* in; u16* out; int ldo, ooff;
    switch (blockIdx.z) {
        case 0:  in = s0; out = W1T;  ldo = 128; ooff = 0;   break;
        case 1:  in = s1; out = W2T;  ldo = 128; ooff = 0;   break;
        case 2:  in = s2; out = WcTe; ldo = 256; ooff = 0;   break;
        case 3:  in = s3; out = WcTe; ldo = 256; ooff = 128; break;
        case 4:  in = s4; out = WcTp; ldo = 256; ooff = 0;   break;
        default: in = s5; out = WcTp; ldo = 256; ooff = 128; break;
    }
    tpose_body(in, 128, 128, out, ldo, ooff, tile);
}

// ---------------- column-sum partials of embeddings (f32, deterministic) ----
__global__ __launch_bounds__(256) void colsump(const u16* __restrict__ demb,
                                               const u16* __restrict__ pemb,
                                               float* __restrict__ part) {
    int m = blockIdx.y;
    const u16* e = m ? pemb : demb;
    int t = threadIdx.x;
    int c2 = t & 63, rg = t >> 6;               // 64 dim-pairs x 4 row groups
    int r0 = blockIdx.x * 64;
    float s0 = 0.f, s1 = 0.f;
    for (int i = 0; i < 16; i++) {
        u32 v = *(const u32*)(e + (size_t)(r0 + i * 4 + rg) * 128 + c2 * 2);
        s0 += bf2f((u16)(v & 0xffffu));
        s1 += bf2f((u16)(v >> 16));
    }
    __shared__ float t0[256], t1[256];
    t0[t] = s0; t1[t] = s1;
    __syncthreads();
    if (t < 64) {
        float a0 = t0[t] + t0[t + 64] + t0[t + 128] + t0[t + 192];
        float a1 = t1[t] + t1[t + 64] + t1[t + 128] + t1[t + 192];
        part[(size_t)m * 4096 + blockIdx.x * 128 + t * 2 + 0] = a0;
        part[(size_t)m * 4096 + blockIdx.x * 128 + t * 2 + 1] = a1;
    }
}

// ---------------- combined biases + colsum finalization ----------------
__global__ void biasc(const u16* a0, const u16* a1, const u16* a2, u16* o0,
                      const u16* b0, const u16* b1, const u16* b2, u16* o1,
                      const float* __restrict__ part,
                      float* __restrict__ csd, float* __restrict__ csp) {
    int t = threadIdx.x;  // 128
    o0[t] = f2bf(bf2f(a0[t]) + bf2f(a1[t]) + bf2f(a2[t]));
    o1[t] = f2bf(bf2f(b0[t]) + bf2f(b1[t]) + bf2f(b2[t]));
    float sd = 0.f, sp = 0.f;
    for (int b = 0; b < 32; b++) {
        sd += part[b * 128 + t];
        sp += part[4096 + b * 128 + t];
    }
    csd[t] = sd;
    csp[t] = sp;
}

// ---------------- ko / qs projections ----------
__global__ __launch_bounds__(128) void koqs(
    const u16* __restrict__ demb, const u16* __restrict__ pemb,
    const u16* __restrict__ Wa1d, const u16* __restrict__ ba1d,
    const u16* __restrict__ Wa1p, const u16* __restrict__ ba1p,
    float* __restrict__ ko_d, float* __restrict__ qs_d,
    float* __restrict__ ko_p, float* __restrict__ qs_p) {
    int row = blockIdx.x, m = blockIdx.y, tid = threadIdx.x;
    const u16* src; const u16* W; const u16* bias; float* out;
    switch (m) {
        case 0:  src = pemb; W = Wa1d;            bias = nullptr; out = ko_d; break;
        case 1:  src = demb; W = Wa1d + 128 * 32; bias = ba1d;    out = qs_d; break;
        case 2:  src = demb; W = Wa1p;            bias = nullptr; out = ko_p; break;
        default: src = pemb; W = Wa1p + 128 * 32; bias = ba1p;    out = qs_p; break;
    }
    __shared__ float x[128];
    __shared__ float red[128];
    x[tid] = bf2f(src[(size_t)row * 128 + tid]);
    __syncthreads();
    int a = tid & 31, part = tid >> 5;
    float s = 0.f;
    #pragma unroll
    for (int k = 0; k < 32; k++) s += x[part * 32 + k] * bf2f(W[(part * 32 + k) * 32 + a]);
    red[tid] = s;
    __syncthreads();
    if (part == 0) {
        float t = red[a] + red[a + 32] + red[a + 64] + red[a + 96];
        if (bias) t += bf2f(bias[a]);
        out[(size_t)row * 32 + a] = t;
    }
}

// ---------------- CSR build: one pass over each adjacency ----------------
// m=0: e_p (row lists AND col lists via global atomics), m=1: e_e, m=2: p_p
struct CS {
    const void* adj[3];
    u16* ridx[3]; u32* rcnt[3];
    u16* cidx; u32* ccnt;        // e_p column lists (pre-zeroed ccnt)
};

__global__ __launch_bounds__(256) void csrbuild(CS c, const u32* __restrict__ flag) {
    int m = blockIdx.y, r = blockIdx.x, t = threadIdx.x;
    bool f32 = flag[0] != 0;
    __shared__ u32 lcnt;
    if (t == 0) lcnt = 0;
    __syncthreads();
    float v[8];
    int c0 = t * 8;
    if (f32) {
        const float4* p = (const float4*)((const float*)c.adj[m] + (size_t)r * 2048 + c0);
        float4 x = p[0], y = p[1];
        v[0] = x.x; v[1] = x.y; v[2] = x.z; v[3] = x.w;
        v[4] = y.x; v[5] = y.y; v[6] = y.z; v[7] = y.w;
    } else {
        const uint4* p = (const uint4*)((const u16*)c.adj[m] + (size_t)r * 2048 + c0);
        uint4 x = p[0];
        u32 u[4] = {x.x, x.y, x.z, x.w};
        #pragma unroll
        for (int i = 0; i < 4; i++) {
            v[2 * i + 0] = (u[i] & 0xffffu) ? 1.f : 0.f;
            v[2 * i + 1] = (u[i] >> 16)     ? 1.f : 0.f;
        }
    }
    u16* ridx = c.ridx[m] + (size_t)r * 2048;
    #pragma unroll
    for (int i = 0; i < 8; i++) {
        if (v[i] != 0.f) {
            u32 p = atomicAdd(&lcnt, 1u);
            ridx[p] = (u16)(c0 + i);
            if (m == 0) {
                u32 q = atomicAdd(&c.ccnt[c0 + i], 1u);
                c.cidx[(size_t)(c0 + i) * 2048 + q] = (u16)r;
            }
        }
    }
    __syncthreads();
    if (t == 0) c.rcnt[m][r] = lcnt;
}

// ---------------- sparse attention/avg aggregation ----------------
// One wave per row. attn: out[r,:] = (colsum(other) + sum_nz (e-1)*other_j)
//                                    / (2048 + sum_nz (e-1))
// avg:  out[r,:] = (sum_nz other_j) / (nnz + 1e-8)
struct SP {
    const u16* idx[4]; const u32* cnt[4];
    const float* ko[4]; const float* qs[4];
    const u16* w2[4]; const u16* b2[4];
    const u16* emb[4]; const float* csum[4];
    u16* out[4]; int ooff[4]; int attn[4];
};

__global__ __launch_bounds__(256) void spagg(SP a) {
    int task = blockIdx.y;
    int tid = threadIdx.x;
    int wv = tid >> 6, lane = tid & 63;
    int r = blockIdx.x * 4 + wv;
    const u16* idx = a.idx[task] + (size_t)r * 2048;
    int nnz = (int)a.cnt[task][r];
    int isat = a.attn[task];
    const u16* emb = a.emb[task];
    const float* ko = a.ko[task];

    float qsr[32], w2h[32];
    float b2v = 0.f;
    if (isat) {
        const float4* qp = (const float4*)(a.qs[task] + (size_t)r * 32);
        #pragma unroll
        for (int i = 0; i < 8; i++) {
            float4 v = qp[i];
            qsr[4 * i + 0] = v.x; qsr[4 * i + 1] = v.y;
            qsr[4 * i + 2] = v.z; qsr[4 * i + 3] = v.w;
        }
        #pragma unroll
        for (int i = 0; i < 32; i++) w2h[i] = bf2f(a.w2[task][i]);
        b2v = bf2f(a.b2[task][0]);
    }

    float acc0 = 0.f, acc1 = 0.f, wsum = 0.f;

    for (int base = 0; base < nnz; base += 64) {
        int i = base + lane;
        float w = 0.f;
        int j = 0;
        if (i < nnz) {
            j = (int)idx[i];
            if (isat) {
                const float4* kp = (const float4*)(ko + (size_t)j * 32);
                float s = 0.f;
                #pragma unroll
                for (int q = 0; q < 8; q++) {
                    float4 kv = kp[q];
                    s += fmaxf(qsr[4 * q + 0] + kv.x, 0.f) * w2h[4 * q + 0];
                    s += fmaxf(qsr[4 * q + 1] + kv.y, 0.f) * w2h[4 * q + 1];
                    s += fmaxf(qsr[4 * q + 2] + kv.z, 0.f) * w2h[4 * q + 2];
                    s += fmaxf(qsr[4 * q + 3] + kv.w, 0.f) * w2h[4 * q + 3];
                }
                w = __expf(fmaxf(s + b2v, 0.f)) - 1.f;
            } else {
                w = 1.f;
            }
        }
        int cend = min(64, nnz - base);
        #pragma unroll 4
        for (int k = 0; k < cend; k++) {
            float wk = __shfl(w, k);
            int jk = __shfl(j, k);
            u32 pe = *(const u32*)(emb + (size_t)jk * 128 + lane * 2);
            acc0 = fmaf(wk, bf2f((u16)(pe & 0xffffu)), acc0);
            acc1 = fmaf(wk, bf2f((u16)(pe >> 16)), acc1);
            wsum += wk;
        }
    }

    float v0, v1;
    if (isat) {
        float sc = 1.f / (2048.f + wsum);
        v0 = (a.csum[task][lane * 2 + 0] + acc0) * sc;
        v1 = (a.csum[task][lane * 2 + 1] + acc1) * sc;
    } else {
        float sc = 1.f / (wsum + 1e-8f);
        v0 = acc0 * sc;
        v1 = acc1 * sc;
    }
    u32 pk = (u32)f2bf(v0) | ((u32)f2bf(v1) << 16);
    *(u32*)(a.out[task] + (size_t)r * 256 + a.ooff[task] + lane * 2) = pk;
}

// ---------------- MFMA GEMM: canonical LDS-tiled (guide §5) --------------
struct GD4 {
    const void* A[4]; const u16* BT[4]; u16* C[4];
    const u16* bias[4]; const float* rs[4];
    int lda[4], ldb[4], ldc[4], coff[4], kiters[4], act[4], araw[4], rsmode[4];
};

#define PADK 136

__global__ __launch_bounds__(256, 2) void gemmL(GD4 g, const u32* __restrict__ flag) {
    __shared__ __align__(16) u16 As[16][PADK];
    __shared__ __align__(16) u16 Bs[128][PADK];
    int z = blockIdx.y;
    bool af32 = g.araw[z] && (flag[0] != 0);
    const void* A = g.A[z];
    const u16* BT = g.BT[z];
    int lda = g.lda[z], ldb = g.ldb[z];
    int kiters = g.kiters[z];
    int tid = threadIdx.x;
    int lane = tid & 63, wv = tid >> 6;
    int mrow = lane & 15, quad = lane >> 4;
    int m0 = blockIdx.x * 16;
    int c0 = wv * 32;
    int sr = tid >> 4, sk = (tid & 15) * 8;
    f32x4 acc0 = {0.f, 0.f, 0.f, 0.f}, acc1 = {0.f, 0.f, 0.f, 0.f};

    short8 ra, rb[8];
    auto ldstage = [&](int kb) {
        if (af32) {
            const float* A32 = (const float*)A;
            const float4* p = (const float4*)(A32 + (size_t)(m0 + sr) * lda + kb + sk);
            float4 f0 = p[0], f1 = p[1];
            ra = packbf8(f0, f1);
        } else {
            ra = *(const short8*)((const u16*)A + (size_t)(m0 + sr) * lda + kb + sk);
        }
        const u16* bbase = BT + (size_t)sr * ldb + kb + sk;
        #pragma unroll
        for (int i = 0; i < 8; i++)
            rb[i] = *(const short8*)(bbase + (size_t)i * 16 * ldb);
    };
    auto ststage = [&]() {
        *(short8*)(&As[sr][sk]) = ra;
        #pragma unroll
        for (int i = 0; i < 8; i++)
            *(short8*)(&Bs[i * 16 + sr][sk]) = rb[i];
    };
    auto compute = [&]() {
        #pragma unroll
        for (int ks = 0; ks < 4; ks++) {
            short8 af = *(const short8*)(&As[mrow][ks * 32 + quad * 8]);
            short8 b0 = *(const short8*)(&Bs[c0 + mrow][ks * 32 + quad * 8]);
            short8 b1 = *(const short8*)(&Bs[c0 + 16 + mrow][ks * 32 + quad * 8]);
            acc0 = __builtin_amdgcn_mfma_f32_16x16x32_bf16(af, b0, acc0, 0, 0, 0);
            acc1 = __builtin_amdgcn_mfma_f32_16x16x32_bf16(af, b1, acc1, 0, 0, 0);
        }
    };

    ldstage(0);
    #pragma unroll 1
    for (int it = 0; it < kiters - 1; ++it) {
        ststage();
        __syncthreads();
        ldstage((it + 1) * 128);
        compute();
        __syncthreads();
    }
    ststage();
    __syncthreads();
    compute();

    const float* rs = g.rs[z];
    int rsmode = g.rsmode[z];
    const u16* bi = g.bias[z];
    u16* C = g.C[z];
    int ldc = g.ldc[z], coff = g.coff[z], act = g.act[z];
    int n0 = c0 + mrow, n1 = n0 + 16;
    float bv0 = bi ? bf2f(bi[n0]) : 0.f;
    float bv1 = bi ? bf2f(bi[n1]) : 0.f;
    #pragma unroll
    for (int r = 0; r < 4; r++) {
        int row = m0 + quad * 4 + r;
        float v0 = acc0[r], v1 = acc1[r];
        if (rsmode == 1) { float sc = rs[row]; v0 *= sc; v1 *= sc; }
        else if (rsmode == 2) {
            float t = 0.f;
            #pragma unroll
            for (int p = 0; p < 8; p++) t += rs[row + p * 2048];
            float sc = 1.f / t;
            v0 *= sc; v1 *= sc;
        }
        v0 += bv0; v1 += bv1;
        if (act) { v0 = seluf(v0); v1 = seluf(v1); }
        C[(size_t)row * ldc + coff + n0] = f2bf(v0);
        C[(size_t)row * ldc + coff + n1] = f2bf(v1);
    }
}

// ---------------- pair gather ----------
__global__ __launch_bounds__(256) void xbuild(
    const u16* __restrict__ he, const u16* __restrict__ hp,
    const int* __restrict__ di, const int* __restrict__ dr, u16* __restrict__ X) {
    int idx = blockIdx.x * 256 + threadIdx.x;  // < B*64
    int d2 = idx & 63;
    int b = idx >> 6;
    int ia = di[b], ic = dr[b];
    u32 ue = ((const u32*)he)[ia * 64 + d2];
    u32 up = ((const u32*)hp)[ic * 64 + d2];
    float lo = bf2f((u16)(ue & 0xffff)) * bf2f((u16)(up & 0xffff));
    float hi = bf2f((u16)(ue >> 16)) * bf2f((u16)(up >> 16));
    ((u32*)X)[idx] = (u32)f2bf(lo) | ((u32)f2bf(hi) << 16);
}

// ---------------- z, sigmoid, loss (FLOAT32 out: out[0]=loss, out[1+b]=sig) --
__global__ __launch_bounds__(256) void zloss(
    const u16* __restrict__ X2, const u16* __restrict__ wpred,
    const u16* __restrict__ bpred, const int* __restrict__ labels,
    float* __restrict__ out, float* __restrict__ part) {
    __shared__ float wp[128];
    __shared__ float ls[256];
    int tid = threadIdx.x;
    if (tid < 128) wp[tid] = bf2f(wpred[tid]);
    __syncthreads();
    int b = blockIdx.x * 256 + tid;
    const uint4* xp = (const uint4*)(X2 + (size_t)b * 128);
    float z = 0.f;
    #pragma unroll
    for (int i = 0; i < 16; i++) {
        uint4 q = xp[i];
        u32 u[4] = {q.x, q.y, q.z, q.w};
        #pragma unroll
        for (int c = 0; c < 4; c++) {
            z += bf2f((u16)(u[c] & 0xffff)) * wp[i * 8 + c * 2];
            z += bf2f((u16)(u[c] >> 16)) * wp[i * 8 + c * 2 + 1];
        }
    }
    z += bf2f(bpred[0]);
    out[1 + b] = 1.f / (1.f + __expf(-z));
    float y = (float)labels[b];
    ls[tid] = fmaxf(z, 0.f) - z * y + log1pf(__expf(-fabsf(z)));
    __syncthreads();
    for (int o = 128; o > 0; o >>= 1) {
        if (tid < o) ls[tid] += ls[tid + o];
        __syncthreads();
    }
    if (tid == 0) part[blockIdx.x] = ls[0];
}

__global__ void finloss(const float* __restrict__ part, float* __restrict__ out) {
    __shared__ float s[64];
    s[threadIdx.x] = part[threadIdx.x];
    __syncthreads();
    for (int o = 32; o > 0; o >>= 1) {
        if (threadIdx.x < o) s[threadIdx.x] += s[threadIdx.x + o];
        __syncthreads();
    }
    if (threadIdx.x == 0) out[0] = s[0] * (1.f / 16384.f);
}

// ---------------- launch ----------------
extern "C" void kernel_launch(void* const* d_in, const int* in_sizes, int n_in,
                              void* d_out, int out_size, void* d_ws, size_t ws_size,
                              hipStream_t stream) {
    const void* e_p_adj = d_in[0];
    const void* e_e_adj = d_in[1];
    const void* p_p_adj = d_in[2];
    const int* in_dis  = (const int*)d_in[3];
    const int* in_drug = (const int*)d_in[4];
    const int* labels  = (const int*)d_in[5];
    float* out = (float*)d_out;

    // -------- workspace layout (~50 MB) --------
    char* ws = (char*)d_ws;
    size_t off = 0;
    auto take = [&](size_t bytes) { char* p = ws + off; off = (off + bytes + 255) & ~(size_t)255; return p; };
    u16*   A_e   = (u16*)take((size_t)2048 * 256 * 2);
    u16*   A_p   = (u16*)take((size_t)2048 * 256 * 2);
    u16*   WcTe  = (u16*)take((size_t)128 * 256 * 2);
    u16*   WcTp  = (u16*)take((size_t)128 * 256 * 2);
    u16*   W1T   = (u16*)take((size_t)128 * 128 * 2);
    u16*   W2T   = (u16*)take((size_t)128 * 128 * 2);
    u16*   b_e   = (u16*)take(256);
    u16*   b_p   = (u16*)take(256);
    u16*   h_e   = (u16*)take((size_t)2048 * 128 * 2);
    u16*   h_p   = (u16*)take((size_t)2048 * 128 * 2);
    float* ko_d  = (float*)take((size_t)2048 * 32 * 4);
    float* qs_d  = (float*)take((size_t)2048 * 32 * 4);
    float* ko_p  = (float*)take((size_t)2048 * 32 * 4);
    float* qs_p  = (float*)take((size_t)2048 * 32 * 4);
    float* cspart = (float*)take((size_t)2 * 32 * 128 * 4);
    float* csd   = (float*)take(128 * 4);
    float* csp   = (float*)take(128 * 4);
    float* part  = (float*)take(64 * 4);
    u32*   flag  = (u32*)take(256);
    u16*   canon = (u16*)take((size_t)700000 * 2);
    u16*   X     = (u16*)take((size_t)BB * 128 * 2);
    u16*   X1    = (u16*)take((size_t)BB * 128 * 2);
    u16*   X2    = (u16*)take((size_t)BB * 128 * 2);
    u16*   idx0  = (u16*)take((size_t)2048 * 2048 * 2);  // e_p rows (disease)
    u16*   idx1  = (u16*)take((size_t)2048 * 2048 * 2);  // e_p cols (drug)
    u16*   idx2  = (u16*)take((size_t)2048 * 2048 * 2);  // e_e rows
    u16*   idx3  = (u16*)take((size_t)2048 * 2048 * 2);  // p_p rows
    u32*   cnt0  = (u32*)take(2048 * 4);
    u32*   cnt2  = (u32*)take(2048 * 4);
    u32*   cnt3  = (u32*)take(2048 * 4);
    u32*   cntT  = (u32*)take(2048 * 4);                 // e_p col counts (zeroed)

    // -------- canonical parameter table --------
    const int segidx[NSEG] = {6, 7, 14, 18, 8, 22, 11, 24, 26, 28,
                              15, 16, 17, 19, 20, 21,
                              9, 10, 12, 13, 23, 25, 27, 29, 30, 31};
    const int segn[NSEG]   = {262144, 262144, 8192, 8192, 16384, 16384, 16384, 16384, 16384, 16384,
                              32, 32, 1, 32, 32, 1,
                              128, 128, 128, 128, 128, 128, 128, 128, 128, 1};
    CvtArgs ca;
    u16* cp[NSEG];
    {
        int o = 0;
        for (int i = 0; i < NSEG; i++) {
            ca.src[i] = d_in[segidx[i]];
            ca.off[i] = o;
            ca.n[i] = segn[i];
            cp[i] = canon + o;
            o += (segn[i] + 15) & ~15;
        }
    }
    u16 *cdemb = cp[0], *cpemb = cp[1], *cWa1d = cp[2], *cWa1p = cp[3];
    u16 *cWdg = cp[4], *cWd2 = cp[5], *cWpg = cp[6], *cWp3 = cp[7];
    u16 *cW1 = cp[8], *cW2 = cp[9];
    u16 *cba1d = cp[10], *cWa2d = cp[11], *cba2d = cp[12];
    u16 *cba1p = cp[13], *cWa2p = cp[14], *cba2p = cp[15];
    u16 *cbdg_lin = cp[16], *cbdg = cp[17], *cbpg_lin = cp[18], *cbpg = cp[19];
    u16 *cbd2 = cp[20], *cbp3 = cp[21], *cmb1 = cp[22], *cmb2 = cp[23];
    u16 *cWpred = cp[24], *cbpred = cp[25];

    // -------- 0. dtype detection + canonicalization --------
    detectk<<<1, 256, 0, stream>>>(d_in[6], flag);
    cvtk<<<dim3(64, NSEG), 256, 0, stream>>>(ca, canon, flag);

    // -------- 1. CSR build (single pass over each adjacency) --------
    hipMemsetAsync(cntT, 0, 2048 * sizeof(u32), stream);
    {
        CS cs;
        cs.adj[0] = e_p_adj; cs.ridx[0] = idx0; cs.rcnt[0] = cnt0;
        cs.adj[1] = e_e_adj; cs.ridx[1] = idx2; cs.rcnt[1] = cnt2;
        cs.adj[2] = p_p_adj; cs.ridx[2] = idx3; cs.rcnt[2] = cnt3;
        cs.cidx = idx1; cs.ccnt = cntT;
        csrbuild<<<dim3(2048, 3), 256, 0, stream>>>(cs, flag);
    }

    // -------- 2. small prep --------
    colsump<<<dim3(32, 2), 256, 0, stream>>>(cdemb, cpemb, cspart);
    tpose_smalls<<<dim3(4, 4, 6), dim3(32, 8), 0, stream>>>(
        cW1, cW2, cWdg, cWd2, cWpg, cWp3, W1T, W2T, WcTe, WcTp);
    biasc<<<1, 128, 0, stream>>>(cbdg_lin, cbdg, cbd2, b_e, cbpg_lin, cbpg, cbp3, b_p,
                                 cspart, csd, csp);
    koqs<<<dim3(2048, 4), 128, 0, stream>>>(cdemb, cpemb, cWa1d, cba1d, cWa1p, cba1p,
                                            ko_d, qs_d, ko_p, qs_p);

    // -------- 3. sparse attention + avg aggregation --------
    {
        SP sp;
        // task0: disease-side attention (neighbors = drugs)
        sp.idx[0] = idx0; sp.cnt[0] = cnt0; sp.ko[0] = ko_d; sp.qs[0] = qs_d;
        sp.w2[0] = cWa2d; sp.b2[0] = cba2d; sp.emb[0] = cpemb; sp.csum[0] = csp;
        sp.out[0] = A_e; sp.ooff[0] = 0; sp.attn[0] = 1;
        // task1: e_e average (neighbors = diseases)
        sp.idx[1] = idx2; sp.cnt[1] = cnt2; sp.ko[1] = ko_d; sp.qs[1] = qs_d;
        sp.w2[1] = cWa2d; sp.b2[1] = cba2d; sp.emb[1] = cdemb; sp.csum[1] = csd;
        sp.out[1] = A_e; sp.ooff[1] = 128; sp.attn[1] = 0;
        // task2: drug-side attention (neighbors = diseases, e_p columns)
        sp.idx[2] = idx1; sp.cnt[2] = cntT; sp.ko[2] = ko_p; sp.qs[2] = qs_p;
        sp.w2[2] = cWa2p; sp.b2[2] = cba2p; sp.emb[2] = cdemb; sp.csum[2] = csd;
        sp.out[2] = A_p; sp.ooff[2] = 0; sp.attn[2] = 1;
        // task3: p_p average (neighbors = drugs)
        sp.idx[3] = idx3; sp.cnt[3] = cnt3; sp.ko[3] = ko_p; sp.qs[3] = qs_p;
        sp.w2[3] = cWa2p; sp.b2[3] = cba2p; sp.emb[3] = cpemb; sp.csum[3] = csp;
        sp.out[3] = A_p; sp.ooff[3] = 128; sp.attn[3] = 0;
        spagg<<<dim3(512, 4), 256, 0, stream>>>(sp);
    }

    auto setd = [](GD4& g, int z, const void* A, int lda, const u16* BT, int ldb,
                   u16* C, int ldc, int coff, int ki, const u16* bi,
                   const float* rs, int act, int araw, int rm) {
        g.A[z] = A; g.lda[z] = lda; g.BT[z] = BT; g.ldb[z] = ldb;
        g.C[z] = C; g.ldc[z] = ldc; g.coff[z] = coff; g.kiters[z] = ki;
        g.bias[z] = bi; g.rs[z] = rs; g.act[z] = act; g.araw[z] = araw; g.rsmode[z] = rm;
    };

    // -------- 4. combine GEMMs (bias + SELU), batched ----------------------
    {
        GD4 g;
        setd(g, 0, A_e, 256, WcTe, 256, h_e, 128, 0, 2, b_e, nullptr, 1, 0, 0);
        setd(g, 1, A_p, 256, WcTp, 256, h_p, 128, 0, 2, b_p, nullptr, 1, 0, 0);
        setd(g, 2, A_e, 256, WcTe, 256, h_e, 128, 0, 2, b_e, nullptr, 1, 0, 0);
        setd(g, 3, A_e, 256, WcTe, 256, h_e, 128, 0, 2, b_e, nullptr, 1, 0, 0);
        gemmL<<<dim3(128, 2), 256, 0, stream>>>(g, flag);
    }

    // -------- 5. pair MLP --------
    xbuild<<<4096, 256, 0, stream>>>(h_e, h_p, in_dis, in_drug, X);
    {
        GD4 g;
        setd(g, 0, X, 128, W1T, 128, X1, 128, 0, 1, cmb1, nullptr, 1, 0, 0);
        setd(g, 1, X, 128, W1T, 128, X1, 128, 0, 1, cmb1, nullptr, 1, 0, 0);
        setd(g, 2, X, 128, W1T, 128, X1, 128, 0, 1, cmb1, nullptr, 1, 0, 0);
        setd(g, 3, X, 128, W1T, 128, X1, 128, 0, 1, cmb1, nullptr, 1, 0, 0);
        gemmL<<<dim3(1024, 1), 256, 0, stream>>>(g, flag);
    }
    {
        GD4 g;
        setd(g, 0, X1, 128, W2T, 128, X2, 128, 0, 1, cmb2, nullptr, 1, 0, 0);
        setd(g, 1, X1, 128, W2T, 128, X2, 128, 0, 1, cmb2, nullptr, 1, 0, 0);
        setd(g, 2, X1, 128, W2T, 128, X2, 128, 0, 1, cmb2, nullptr, 1, 0, 0);
        setd(g, 3, X1, 128, W2T, 128, X2, 128, 0, 1, cmb2, nullptr, 1, 0, 0);
        gemmL<<<dim3(1024, 1), 256, 0, stream>>>(g, flag);
    }

    // -------- 6. z / sigmoid / loss --------
    zloss<<<64, 256, 0, stream>>>(X2, cWpred, cbpred, labels, out, part);
    finloss<<<1, 64, 0, stream>>>(part, out);
}

// Round 2
// 253.985 us; speedup vs baseline: 1.1256x; 1.1256x over previous
//
#include <hip/hip_runtime.h>

#define ND   2048
#define BB   16384

typedef unsigned short u16;
typedef unsigned int u32;
typedef __attribute__((ext_vector_type(8))) short short8;
typedef __attribute__((ext_vector_type(4))) float f32x4;

__device__ inline float bf2f(u16 u) {
    union { u32 i; float f; } v; v.i = ((u32)u) << 16; return v.f;
}
__device__ inline u16 f2bf(float f) {
    union { float f; u32 i; } v; v.f = f;
    u32 i = v.i + 0x7fffu + ((v.i >> 16) & 1u);
    return (u16)(i >> 16);
}
__device__ inline float seluf(float x) {
    const float sc = 1.0507009873554805f, al = 1.6732632423543772f;
    return x > 0.f ? sc * x : sc * al * expm1f(x);
}
__device__ inline short8 packbf8(float4 f0, float4 f1) {
    short8 a;
    a[0] = (short)f2bf(f0.x); a[1] = (short)f2bf(f0.y);
    a[2] = (short)f2bf(f0.z); a[3] = (short)f2bf(f0.w);
    a[4] = (short)f2bf(f1.x); a[5] = (short)f2bf(f1.y);
    a[6] = (short)f2bf(f1.z); a[7] = (short)f2bf(f1.w);
    return a;
}

// ---------------- dtype sniffer ----------------
__global__ void detectk(const void* __restrict__ demb, u32* __restrict__ flag) {
    const u16* p = (const u16*)demb;
    int tid = threadIdx.x;  // 256
    int sane = 0;
    #pragma unroll
    for (int i = 0; i < 2; i++) {
        u16 u = p[4 * tid + 2 * i];
        int e = (u >> 7) & 0xFF;
        if (u == 0 || (e >= 0x66 && e <= 0x8C)) sane++;
    }
    __shared__ int red[256];
    red[tid] = sane; __syncthreads();
    for (int o = 128; o > 0; o >>= 1) {
        if (tid < o) red[tid] += red[tid + o];
        __syncthreads();
    }
    if (tid == 0) flag[0] = (red[0] < 300) ? 1u : 0u;
}

// ---------------- canonical bf16 conversion (26 segments, one launch) -------
#define NSEG 26
struct CvtArgs { const void* src[NSEG]; int off[NSEG]; int n[NSEG]; };

__global__ __launch_bounds__(256) void cvtk(CvtArgs a, u16* __restrict__ base,
                                            const u32* __restrict__ flag) {
    int seg = blockIdx.y;
    int n = a.n[seg];
    const void* s = a.src[seg];
    u16* d = base + a.off[seg];
    bool f32 = flag[0] != 0;
    int stride = gridDim.x * blockDim.x;
    for (int i = blockIdx.x * blockDim.x + threadIdx.x; i < n; i += stride)
        d[i] = f32 ? f2bf(((const float*)s)[i]) : ((const u16*)s)[i];
}

// ---------------- transpose (bf16, tiled 32x32) ----------------
__device__ inline void tpose_body(const u16* in, int R, int C,
                                  u16* out, int ldo, int ooff,
                                  u16 (*tile)[33]) {
    int c0 = blockIdx.x * 32, r0 = blockIdx.y * 32;
    int x = c0 + threadIdx.x;
    for (int i = threadIdx.y; i < 32; i += 8) {
        int r = r0 + i;
        tile[i][threadIdx.x] = (r < R && x < C) ? in[(size_t)r * C + x] : (u16)0;
    }
    __syncthreads();
    int rr = r0 + threadIdx.x;
    for (int i = threadIdx.y; i < 32; i += 8) {
        int cc = c0 + i;
        if (cc < C && rr < R) out[(size_t)cc * ldo + ooff + rr] = tile[threadIdx.x][i];
    }
}

__global__ void tpose_smalls(const u16* s0, const u16* s1, const u16* s2,
                             const u16* s3, const u16* s4, const u16* s5,
                             u16* W1T, u16* W2T, u16* WcTe, u16* WcTp) {
    __shared__ u16 tile[32][33];
    const u16* in; u16* out; int ldo, ooff;
    switch (blockIdx.z) {
        case 0:  in = s0; out = W1T;  ldo = 128; ooff = 0;   break;
        case 1:  in = s1; out = W2T;  ldo = 128; ooff = 0;   break;
        case 2:  in = s2; out = WcTe; ldo = 256; ooff = 0;   break;
        case 3:  in = s3; out = WcTe; ldo = 256; ooff = 128; break;
        case 4:  in = s4; out = WcTp; ldo = 256; ooff = 0;   break;
        default: in = s5; out = WcTp; ldo = 256; ooff = 128; break;
    }
    tpose_body(in, 128, 128, out, ldo, ooff, tile);
}

// ---------------- column-sum partials of embeddings (f32, deterministic) ----
__global__ __launch_bounds__(256) void colsump(const u16* __restrict__ demb,
                                               const u16* __restrict__ pemb,
                                               float* __restrict__ part) {
    int m = blockIdx.y;
    const u16* e = m ? pemb : demb;
    int t = threadIdx.x;
    int c2 = t & 63, rg = t >> 6;               // 64 dim-pairs x 4 row groups
    int r0 = blockIdx.x * 64;
    float s0 = 0.f, s1 = 0.f;
    for (int i = 0; i < 16; i++) {
        u32 v = *(const u32*)(e + (size_t)(r0 + i * 4 + rg) * 128 + c2 * 2);
        s0 += bf2f((u16)(v & 0xffffu));
        s1 += bf2f((u16)(v >> 16));
    }
    __shared__ float t0[256], t1[256];
    t0[t] = s0; t1[t] = s1;
    __syncthreads();
    if (t < 64) {
        float a0 = t0[t] + t0[t + 64] + t0[t + 128] + t0[t + 192];
        float a1 = t1[t] + t1[t + 64] + t1[t + 128] + t1[t + 192];
        part[(size_t)m * 4096 + blockIdx.x * 128 + t * 2 + 0] = a0;
        part[(size_t)m * 4096 + blockIdx.x * 128 + t * 2 + 1] = a1;
    }
}

// ---------------- combined biases + colsum finalization ----------------
__global__ void biasc(const u16* a0, const u16* a1, const u16* a2, u16* o0,
                      const u16* b0, const u16* b1, const u16* b2, u16* o1,
                      const float* __restrict__ part,
                      float* __restrict__ csd, float* __restrict__ csp) {
    int t = threadIdx.x;  // 128
    o0[t] = f2bf(bf2f(a0[t]) + bf2f(a1[t]) + bf2f(a2[t]));
    o1[t] = f2bf(bf2f(b0[t]) + bf2f(b1[t]) + bf2f(b2[t]));
    float sd = 0.f, sp = 0.f;
    for (int b = 0; b < 32; b++) {
        sd += part[b * 128 + t];
        sp += part[4096 + b * 128 + t];
    }
    csd[t] = sd;
    csp[t] = sp;
}

// ---------------- ko / qs projections ----------
__global__ __launch_bounds__(128) void koqs(
    const u16* __restrict__ demb, const u16* __restrict__ pemb,
    const u16* __restrict__ Wa1d, const u16* __restrict__ ba1d,
    const u16* __restrict__ Wa1p, const u16* __restrict__ ba1p,
    float* __restrict__ ko_d, float* __restrict__ qs_d,
    float* __restrict__ ko_p, float* __restrict__ qs_p) {
    int row = blockIdx.x, m = blockIdx.y, tid = threadIdx.x;
    const u16* src; const u16* W; const u16* bias; float* out;
    switch (m) {
        case 0:  src = pemb; W = Wa1d;            bias = nullptr; out = ko_d; break;
        case 1:  src = demb; W = Wa1d + 128 * 32; bias = ba1d;    out = qs_d; break;
        case 2:  src = demb; W = Wa1p;            bias = nullptr; out = ko_p; break;
        default: src = pemb; W = Wa1p + 128 * 32; bias = ba1p;    out = qs_p; break;
    }
    __shared__ float x[128];
    __shared__ float red[128];
    x[tid] = bf2f(src[(size_t)row * 128 + tid]);
    __syncthreads();
    int a = tid & 31, part = tid >> 5;
    float s = 0.f;
    #pragma unroll
    for (int k = 0; k < 32; k++) s += x[part * 32 + k] * bf2f(W[(part * 32 + k) * 32 + a]);
    red[tid] = s;
    __syncthreads();
    if (part == 0) {
        float t = red[a] + red[a + 32] + red[a + 64] + red[a + 96];
        if (bias) t += bf2f(bias[a]);
        out[(size_t)row * 32 + a] = t;
    }
}

// ---------------- CSR build: one pass, wave-scan compaction ----------------
// m=0: e_p (row lists AND col lists via global atomics), m=1: e_e, m=2: p_p
struct CS {
    const void* adj[3];
    u16* ridx[3]; u32* rcnt[3];
    u16* cidx; u32* ccnt;        // e_p column lists (pre-zeroed ccnt)
};

__global__ __launch_bounds__(256) void csrbuild(CS c, const u32* __restrict__ flag) {
    int m = blockIdx.y, r = blockIdx.x, t = threadIdx.x;
    int lane = t & 63;
    bool f32 = flag[0] != 0;
    __shared__ u32 lcnt;
    if (t == 0) lcnt = 0;
    __syncthreads();
    float v[8];
    int c0 = t * 8;
    if (f32) {
        const float4* p = (const float4*)((const float*)c.adj[m] + (size_t)r * 2048 + c0);
        float4 x = p[0], y = p[1];
        v[0] = x.x; v[1] = x.y; v[2] = x.z; v[3] = x.w;
        v[4] = y.x; v[5] = y.y; v[6] = y.z; v[7] = y.w;
    } else {
        const uint4* p = (const uint4*)((const u16*)c.adj[m] + (size_t)r * 2048 + c0);
        uint4 x = p[0];
        u32 u[4] = {x.x, x.y, x.z, x.w};
        #pragma unroll
        for (int i = 0; i < 4; i++) {
            v[2 * i + 0] = (u[i] & 0xffffu) ? 1.f : 0.f;
            v[2 * i + 1] = (u[i] >> 16)     ? 1.f : 0.f;
        }
    }
    int cnt = 0;
    #pragma unroll
    for (int i = 0; i < 8; i++) cnt += (v[i] != 0.f) ? 1 : 0;
    // wave inclusive prefix scan of cnt
    int pfx = cnt;
    #pragma unroll
    for (int o = 1; o < 64; o <<= 1) {
        int s = __shfl_up(pfx, o, 64);
        if (lane >= o) pfx += s;
    }
    int wtot = __shfl(pfx, 63, 64);
    u32 wb = 0;
    if (lane == 0) wb = atomicAdd(&lcnt, (u32)wtot);
    wb = __shfl((int)wb, 0, 64);
    int o = (int)wb + pfx - cnt;
    u16* ridx = c.ridx[m] + (size_t)r * 2048;
    #pragma unroll
    for (int i = 0; i < 8; i++) {
        if (v[i] != 0.f) {
            ridx[o++] = (u16)(c0 + i);
            if (m == 0) {
                u32 q = atomicAdd(&c.ccnt[c0 + i], 1u);
                c.cidx[(size_t)(c0 + i) * 2048 + q] = (u16)r;
            }
        }
    }
    __syncthreads();
    if (t == 0) c.rcnt[m][r] = lcnt;
}

// ---------------- sparse attention/avg aggregation (v2: wide gather) --------
// One wave per row. Lane decomposition: grp = lane>>4 (4 neighbor slots),
// dim = lane&15 (16B dim slice). One dwordx4/lane = 4 full rows per iter.
// attn: out[r,:] = (colsum(other) + sum_nz (e-1)*other_j) / (2048 + sum_nz (e-1))
// avg:  out[r,:] = (sum_nz other_j) / (nnz + 1e-8)
struct SP {
    const u16* idx[4]; const u32* cnt[4];
    const float* ko[4]; const float* qs[4];
    const u16* w2[4]; const u16* b2[4];
    const u16* emb[4]; const float* csum[4];
    u16* out[4]; int ooff[4]; int attn[4];
};

__global__ __launch_bounds__(256) void spagg(SP a) {
    int task = blockIdx.y;
    int tid = threadIdx.x;
    int wv = tid >> 6, lane = tid & 63;
    int grp = lane >> 4, dim = lane & 15;
    int r = blockIdx.x * 4 + wv;
    const u16* idx = a.idx[task] + (size_t)r * 2048;
    int nnz = (int)a.cnt[task][r];
    int isat = a.attn[task];
    const u16* emb = a.emb[task];
    const float* ko = a.ko[task];

    float qsr[32], w2h[32];
    float b2v = 0.f;
    if (isat) {
        const float4* qp = (const float4*)(a.qs[task] + (size_t)r * 32);
        #pragma unroll
        for (int i = 0; i < 8; i++) {
            float4 v = qp[i];
            qsr[4 * i + 0] = v.x; qsr[4 * i + 1] = v.y;
            qsr[4 * i + 2] = v.z; qsr[4 * i + 3] = v.w;
        }
        #pragma unroll
        for (int i = 0; i < 32; i++) w2h[i] = bf2f(a.w2[task][i]);
        b2v = bf2f(a.b2[task][0]);
    }

    float acc[8];
    #pragma unroll
    for (int t = 0; t < 8; t++) acc[t] = 0.f;
    float wsuml = 0.f;

    for (int base = 0; base < nnz; base += 64) {
        int i = base + lane;
        float w = 0.f;
        int j = 0;
        if (i < nnz) {
            j = (int)idx[i];
            if (isat) {
                const float4* kp = (const float4*)(ko + (size_t)j * 32);
                float s = 0.f;
                #pragma unroll
                for (int q = 0; q < 8; q++) {
                    float4 kv = kp[q];
                    s += fmaxf(qsr[4 * q + 0] + kv.x, 0.f) * w2h[4 * q + 0];
                    s += fmaxf(qsr[4 * q + 1] + kv.y, 0.f) * w2h[4 * q + 1];
                    s += fmaxf(qsr[4 * q + 2] + kv.z, 0.f) * w2h[4 * q + 2];
                    s += fmaxf(qsr[4 * q + 3] + kv.w, 0.f) * w2h[4 * q + 3];
                }
                w = __expf(fmaxf(s + b2v, 0.f)) - 1.f;
            } else {
                w = 1.f;
            }
        }
        wsuml += w;
        int cend = min(64, nnz - base);
        // 4 neighbor rows per iteration; inactive slots carry w=0,j=0 -> no-op
        #pragma unroll 4
        for (int k4 = 0; k4 < cend; k4 += 4) {
            int kk = k4 + grp;
            float wk = __shfl(w, kk, 64);
            int jk = __shfl(j, kk, 64);
            const uint4* p = (const uint4*)((const char*)emb + jk * 256 + dim * 16);
            uint4 vv = *p;
            u32 u[4] = {vv.x, vv.y, vv.z, vv.w};
            #pragma unroll
            for (int cc = 0; cc < 4; cc++) {
                acc[2 * cc + 0] = fmaf(wk, bf2f((u16)(u[cc] & 0xffffu)), acc[2 * cc + 0]);
                acc[2 * cc + 1] = fmaf(wk, bf2f((u16)(u[cc] >> 16)), acc[2 * cc + 1]);
            }
        }
    }

    // sum partial accumulators across the 4 groups
    #pragma unroll
    for (int t = 0; t < 8; t++) {
        acc[t] += __shfl_xor(acc[t], 32, 64);
        acc[t] += __shfl_xor(acc[t], 16, 64);
    }
    // full-wave weight sum
    #pragma unroll
    for (int o = 32; o > 0; o >>= 1) wsuml += __shfl_xor(wsuml, o, 64);

    if (grp == 0) {
        float v[8];
        if (isat) {
            float sc = 1.f / (2048.f + wsuml);
            const float* cs = a.csum[task] + dim * 8;
            #pragma unroll
            for (int t = 0; t < 8; t++) v[t] = (cs[t] + acc[t]) * sc;
        } else {
            float sc = 1.f / (wsuml + 1e-8f);
            #pragma unroll
            for (int t = 0; t < 8; t++) v[t] = acc[t] * sc;
        }
        uint4 pk;
        pk.x = (u32)f2bf(v[0]) | ((u32)f2bf(v[1]) << 16);
        pk.y = (u32)f2bf(v[2]) | ((u32)f2bf(v[3]) << 16);
        pk.z = (u32)f2bf(v[4]) | ((u32)f2bf(v[5]) << 16);
        pk.w = (u32)f2bf(v[6]) | ((u32)f2bf(v[7]) << 16);
        *(uint4*)(a.out[task] + (size_t)r * 256 + a.ooff[task] + dim * 8) = pk;
    }
}

// ---------------- MFMA GEMM: canonical LDS-tiled (guide §5) --------------
struct GD4 {
    const void* A[4]; const u16* BT[4]; u16* C[4];
    const u16* bias[4]; const float* rs[4];
    int lda[4], ldb[4], ldc[4], coff[4], kiters[4], act[4], araw[4], rsmode[4];
};

#define PADK 136

__global__ __launch_bounds__(256, 2) void gemmL(GD4 g, const u32* __restrict__ flag) {
    __shared__ __align__(16) u16 As[16][PADK];
    __shared__ __align__(16) u16 Bs[128][PADK];
    int z = blockIdx.y;
    bool af32 = g.araw[z] && (flag[0] != 0);
    const void* A = g.A[z];
    const u16* BT = g.BT[z];
    int lda = g.lda[z], ldb = g.ldb[z];
    int kiters = g.kiters[z];
    int tid = threadIdx.x;
    int lane = tid & 63, wv = tid >> 6;
    int mrow = lane & 15, quad = lane >> 4;
    int m0 = blockIdx.x * 16;
    int c0 = wv * 32;
    int sr = tid >> 4, sk = (tid & 15) * 8;
    f32x4 acc0 = {0.f, 0.f, 0.f, 0.f}, acc1 = {0.f, 0.f, 0.f, 0.f};

    short8 ra, rb[8];
    auto ldstage = [&](int kb) {
        if (af32) {
            const float* A32 = (const float*)A;
            const float4* p = (const float4*)(A32 + (size_t)(m0 + sr) * lda + kb + sk);
            float4 f0 = p[0], f1 = p[1];
            ra = packbf8(f0, f1);
        } else {
            ra = *(const short8*)((const u16*)A + (size_t)(m0 + sr) * lda + kb + sk);
        }
        const u16* bbase = BT + (size_t)sr * ldb + kb + sk;
        #pragma unroll
        for (int i = 0; i < 8; i++)
            rb[i] = *(const short8*)(bbase + (size_t)i * 16 * ldb);
    };
    auto ststage = [&]() {
        *(short8*)(&As[sr][sk]) = ra;
        #pragma unroll
        for (int i = 0; i < 8; i++)
            *(short8*)(&Bs[i * 16 + sr][sk]) = rb[i];
    };
    auto compute = [&]() {
        #pragma unroll
        for (int ks = 0; ks < 4; ks++) {
            short8 af = *(const short8*)(&As[mrow][ks * 32 + quad * 8]);
            short8 b0 = *(const short8*)(&Bs[c0 + mrow][ks * 32 + quad * 8]);
            short8 b1 = *(const short8*)(&Bs[c0 + 16 + mrow][ks * 32 + quad * 8]);
            acc0 = __builtin_amdgcn_mfma_f32_16x16x32_bf16(af, b0, acc0, 0, 0, 0);
            acc1 = __builtin_amdgcn_mfma_f32_16x16x32_bf16(af, b1, acc1, 0, 0, 0);
        }
    };

    ldstage(0);
    #pragma unroll 1
    for (int it = 0; it < kiters - 1; ++it) {
        ststage();
        __syncthreads();
        ldstage((it + 1) * 128);
        compute();
        __syncthreads();
    }
    ststage();
    __syncthreads();
    compute();

    const float* rs = g.rs[z];
    int rsmode = g.rsmode[z];
    const u16* bi = g.bias[z];
    u16* C = g.C[z];
    int ldc = g.ldc[z], coff = g.coff[z], act = g.act[z];
    int n0 = c0 + mrow, n1 = n0 + 16;
    float bv0 = bi ? bf2f(bi[n0]) : 0.f;
    float bv1 = bi ? bf2f(bi[n1]) : 0.f;
    #pragma unroll
    for (int r = 0; r < 4; r++) {
        int row = m0 + quad * 4 + r;
        float v0 = acc0[r], v1 = acc1[r];
        if (rsmode == 1) { float sc = rs[row]; v0 *= sc; v1 *= sc; }
        else if (rsmode == 2) {
            float t = 0.f;
            #pragma unroll
            for (int p = 0; p < 8; p++) t += rs[row + p * 2048];
            float sc = 1.f / t;
            v0 *= sc; v1 *= sc;
        }
        v0 += bv0; v1 += bv1;
        if (act) { v0 = seluf(v0); v1 = seluf(v1); }
        C[(size_t)row * ldc + coff + n0] = f2bf(v0);
        C[(size_t)row * ldc + coff + n1] = f2bf(v1);
    }
}

// ---------------- pair gather ----------
__global__ __launch_bounds__(256) void xbuild(
    const u16* __restrict__ he, const u16* __restrict__ hp,
    const int* __restrict__ di, const int* __restrict__ dr, u16* __restrict__ X) {
    int idx = blockIdx.x * 256 + threadIdx.x;  // < B*64
    int d2 = idx & 63;
    int b = idx >> 6;
    int ia = di[b], ic = dr[b];
    u32 ue = ((const u32*)he)[ia * 64 + d2];
    u32 up = ((const u32*)hp)[ic * 64 + d2];
    float lo = bf2f((u16)(ue & 0xffff)) * bf2f((u16)(up & 0xffff));
    float hi = bf2f((u16)(ue >> 16)) * bf2f((u16)(up >> 16));
    ((u32*)X)[idx] = (u32)f2bf(lo) | ((u32)f2bf(hi) << 16);
}

// ---------------- z, sigmoid, loss (FLOAT32 out: out[0]=loss, out[1+b]=sig) --
__global__ __launch_bounds__(256) void zloss(
    const u16* __restrict__ X2, const u16* __restrict__ wpred,
    const u16* __restrict__ bpred, const int* __restrict__ labels,
    float* __restrict__ out, float* __restrict__ part) {
    __shared__ float wp[128];
    __shared__ float ls[256];
    int tid = threadIdx.x;
    if (tid < 128) wp[tid] = bf2f(wpred[tid]);
    __syncthreads();
    int b = blockIdx.x * 256 + tid;
    const uint4* xp = (const uint4*)(X2 + (size_t)b * 128);
    float z = 0.f;
    #pragma unroll
    for (int i = 0; i < 16; i++) {
        uint4 q = xp[i];
        u32 u[4] = {q.x, q.y, q.z, q.w};
        #pragma unroll
        for (int c = 0; c < 4; c++) {
            z += bf2f((u16)(u[c] & 0xffff)) * wp[i * 8 + c * 2];
            z += bf2f((u16)(u[c] >> 16)) * wp[i * 8 + c * 2 + 1];
        }
    }
    z += bf2f(bpred[0]);
    out[1 + b] = 1.f / (1.f + __expf(-z));
    float y = (float)labels[b];
    ls[tid] = fmaxf(z, 0.f) - z * y + log1pf(__expf(-fabsf(z)));
    __syncthreads();
    for (int o = 128; o > 0; o >>= 1) {
        if (tid < o) ls[tid] += ls[tid + o];
        __syncthreads();
    }
    if (tid == 0) part[blockIdx.x] = ls[0];
}

__global__ void finloss(const float* __restrict__ part, float* __restrict__ out) {
    __shared__ float s[64];
    s[threadIdx.x] = part[threadIdx.x];
    __syncthreads();
    for (int o = 32; o > 0; o >>= 1) {
        if (threadIdx.x < o) s[threadIdx.x] += s[threadIdx.x + o];
        __syncthreads();
    }
    if (threadIdx.x == 0) out[0] = s[0] * (1.f / 16384.f);
}

// ---------------- launch ----------------
extern "C" void kernel_launch(void* const* d_in, const int* in_sizes, int n_in,
                              void* d_out, int out_size, void* d_ws, size_t ws_size,
                              hipStream_t stream) {
    const void* e_p_adj = d_in[0];
    const void* e_e_adj = d_in[1];
    const void* p_p_adj = d_in[2];
    const int* in_dis  = (const int*)d_in[3];
    const int* in_drug = (const int*)d_in[4];
    const int* labels  = (const int*)d_in[5];
    float* out = (float*)d_out;

    // -------- workspace layout (~50 MB) --------
    char* ws = (char*)d_ws;
    size_t off = 0;
    auto take = [&](size_t bytes) { char* p = ws + off; off = (off + bytes + 255) & ~(size_t)255; return p; };
    u16*   A_e   = (u16*)take((size_t)2048 * 256 * 2);
    u16*   A_p   = (u16*)take((size_t)2048 * 256 * 2);
    u16*   WcTe  = (u16*)take((size_t)128 * 256 * 2);
    u16*   WcTp  = (u16*)take((size_t)128 * 256 * 2);
    u16*   W1T   = (u16*)take((size_t)128 * 128 * 2);
    u16*   W2T   = (u16*)take((size_t)128 * 128 * 2);
    u16*   b_e   = (u16*)take(256);
    u16*   b_p   = (u16*)take(256);
    u16*   h_e   = (u16*)take((size_t)2048 * 128 * 2);
    u16*   h_p   = (u16*)take((size_t)2048 * 128 * 2);
    float* ko_d  = (float*)take((size_t)2048 * 32 * 4);
    float* qs_d  = (float*)take((size_t)2048 * 32 * 4);
    float* ko_p  = (float*)take((size_t)2048 * 32 * 4);
    float* qs_p  = (float*)take((size_t)2048 * 32 * 4);
    float* cspart = (float*)take((size_t)2 * 32 * 128 * 4);
    float* csd   = (float*)take(128 * 4);
    float* csp   = (float*)take(128 * 4);
    float* part  = (float*)take(64 * 4);
    u32*   flag  = (u32*)take(256);
    u16*   canon = (u16*)take((size_t)700000 * 2);
    u16*   X     = (u16*)take((size_t)BB * 128 * 2);
    u16*   X1    = (u16*)take((size_t)BB * 128 * 2);
    u16*   X2    = (u16*)take((size_t)BB * 128 * 2);
    u16*   idx0  = (u16*)take((size_t)2048 * 2048 * 2);  // e_p rows (disease)
    u16*   idx1  = (u16*)take((size_t)2048 * 2048 * 2);  // e_p cols (drug)
    u16*   idx2  = (u16*)take((size_t)2048 * 2048 * 2);  // e_e rows
    u16*   idx3  = (u16*)take((size_t)2048 * 2048 * 2);  // p_p rows
    u32*   cnt0  = (u32*)take(2048 * 4);
    u32*   cnt2  = (u32*)take(2048 * 4);
    u32*   cnt3  = (u32*)take(2048 * 4);
    u32*   cntT  = (u32*)take(2048 * 4);                 // e_p col counts (zeroed)

    // -------- canonical parameter table --------
    const int segidx[NSEG] = {6, 7, 14, 18, 8, 22, 11, 24, 26, 28,
                              15, 16, 17, 19, 20, 21,
                              9, 10, 12, 13, 23, 25, 27, 29, 30, 31};
    const int segn[NSEG]   = {262144, 262144, 8192, 8192, 16384, 16384, 16384, 16384, 16384, 16384,
                              32, 32, 1, 32, 32, 1,
                              128, 128, 128, 128, 128, 128, 128, 128, 128, 1};
    CvtArgs ca;
    u16* cp[NSEG];
    {
        int o = 0;
        for (int i = 0; i < NSEG; i++) {
            ca.src[i] = d_in[segidx[i]];
            ca.off[i] = o;
            ca.n[i] = segn[i];
            cp[i] = canon + o;
            o += (segn[i] + 15) & ~15;
        }
    }
    u16 *cdemb = cp[0], *cpemb = cp[1], *cWa1d = cp[2], *cWa1p = cp[3];
    u16 *cWdg = cp[4], *cWd2 = cp[5], *cWpg = cp[6], *cWp3 = cp[7];
    u16 *cW1 = cp[8], *cW2 = cp[9];
    u16 *cba1d = cp[10], *cWa2d = cp[11], *cba2d = cp[12];
    u16 *cba1p = cp[13], *cWa2p = cp[14], *cba2p = cp[15];
    u16 *cbdg_lin = cp[16], *cbdg = cp[17], *cbpg_lin = cp[18], *cbpg = cp[19];
    u16 *cbd2 = cp[20], *cbp3 = cp[21], *cmb1 = cp[22], *cmb2 = cp[23];
    u16 *cWpred = cp[24], *cbpred = cp[25];

    // -------- 0. dtype detection + canonicalization --------
    detectk<<<1, 256, 0, stream>>>(d_in[6], flag);
    cvtk<<<dim3(64, NSEG), 256, 0, stream>>>(ca, canon, flag);

    // -------- 1. CSR build (single pass over each adjacency) --------
    hipMemsetAsync(cntT, 0, 2048 * sizeof(u32), stream);
    {
        CS cs;
        cs.adj[0] = e_p_adj; cs.ridx[0] = idx0; cs.rcnt[0] = cnt0;
        cs.adj[1] = e_e_adj; cs.ridx[1] = idx2; cs.rcnt[1] = cnt2;
        cs.adj[2] = p_p_adj; cs.ridx[2] = idx3; cs.rcnt[2] = cnt3;
        cs.cidx = idx1; cs.ccnt = cntT;
        csrbuild<<<dim3(2048, 3), 256, 0, stream>>>(cs, flag);
    }

    // -------- 2. small prep --------
    colsump<<<dim3(32, 2), 256, 0, stream>>>(cdemb, cpemb, cspart);
    tpose_smalls<<<dim3(4, 4, 6), dim3(32, 8), 0, stream>>>(
        cW1, cW2, cWdg, cWd2, cWpg, cWp3, W1T, W2T, WcTe, WcTp);
    biasc<<<1, 128, 0, stream>>>(cbdg_lin, cbdg, cbd2, b_e, cbpg_lin, cbpg, cbp3, b_p,
                                 cspart, csd, csp);
    koqs<<<dim3(2048, 4), 128, 0, stream>>>(cdemb, cpemb, cWa1d, cba1d, cWa1p, cba1p,
                                            ko_d, qs_d, ko_p, qs_p);

    // -------- 3. sparse attention + avg aggregation --------
    {
        SP sp;
        // task0: disease-side attention (neighbors = drugs)
        sp.idx[0] = idx0; sp.cnt[0] = cnt0; sp.ko[0] = ko_d; sp.qs[0] = qs_d;
        sp.w2[0] = cWa2d; sp.b2[0] = cba2d; sp.emb[0] = cpemb; sp.csum[0] = csp;
        sp.out[0] = A_e; sp.ooff[0] = 0; sp.attn[0] = 1;
        // task1: e_e average (neighbors = diseases)
        sp.idx[1] = idx2; sp.cnt[1] = cnt2; sp.ko[1] = ko_d; sp.qs[1] = qs_d;
        sp.w2[1] = cWa2d; sp.b2[1] = cba2d; sp.emb[1] = cdemb; sp.csum[1] = csd;
        sp.out[1] = A_e; sp.ooff[1] = 128; sp.attn[1] = 0;
        // task2: drug-side attention (neighbors = diseases, e_p columns)
        sp.idx[2] = idx1; sp.cnt[2] = cntT; sp.ko[2] = ko_p; sp.qs[2] = qs_p;
        sp.w2[2] = cWa2p; sp.b2[2] = cba2p; sp.emb[2] = cdemb; sp.csum[2] = csd;
        sp.out[2] = A_p; sp.ooff[2] = 0; sp.attn[2] = 1;
        // task3: p_p average (neighbors = drugs)
        sp.idx[3] = idx3; sp.cnt[3] = cnt3; sp.ko[3] = ko_p; sp.qs[3] = qs_p;
        sp.w2[3] = cWa2p; sp.b2[3] = cba2p; sp.emb[3] = cpemb; sp.csum[3] = csp;
        sp.out[3] = A_p; sp.ooff[3] = 128; sp.attn[3] = 0;
        spagg<<<dim3(512, 4), 256, 0, stream>>>(sp);
    }

    auto setd = [](GD4& g, int z, const void* A, int lda, const u16* BT, int ldb,
                   u16* C, int ldc, int coff, int ki, const u16* bi,
                   const float* rs, int act, int araw, int rm) {
        g.A[z] = A; g.lda[z] = lda; g.BT[z] = BT; g.ldb[z] = ldb;
        g.C[z] = C; g.ldc[z] = ldc; g.coff[z] = coff; g.kiters[z] = ki;
        g.bias[z] = bi; g.rs[z] = rs; g.act[z] = act; g.araw[z] = araw; g.rsmode[z] = rm;
    };

    // -------- 4. combine GEMMs (bias + SELU), batched ----------------------
    {
        GD4 g;
        setd(g, 0, A_e, 256, WcTe, 256, h_e, 128, 0, 2, b_e, nullptr, 1, 0, 0);
        setd(g, 1, A_p, 256, WcTp, 256, h_p, 128, 0, 2, b_p, nullptr, 1, 0, 0);
        setd(g, 2, A_e, 256, WcTe, 256, h_e, 128, 0, 2, b_e, nullptr, 1, 0, 0);
        setd(g, 3, A_e, 256, WcTe, 256, h_e, 128, 0, 2, b_e, nullptr, 1, 0, 0);
        gemmL<<<dim3(128, 2), 256, 0, stream>>>(g, flag);
    }

    // -------- 5. pair MLP --------
    xbuild<<<4096, 256, 0, stream>>>(h_e, h_p, in_dis, in_drug, X);
    {
        GD4 g;
        setd(g, 0, X, 128, W1T, 128, X1, 128, 0, 1, cmb1, nullptr, 1, 0, 0);
        setd(g, 1, X, 128, W1T, 128, X1, 128, 0, 1, cmb1, nullptr, 1, 0, 0);
        setd(g, 2, X, 128, W1T, 128, X1, 128, 0, 1, cmb1, nullptr, 1, 0, 0);
        setd(g, 3, X, 128, W1T, 128, X1, 128, 0, 1, cmb1, nullptr, 1, 0, 0);
        gemmL<<<dim3(1024, 1), 256, 0, stream>>>(g, flag);
    }
    {
        GD4 g;
        setd(g, 0, X1, 128, W2T, 128, X2, 128, 0, 1, cmb2, nullptr, 1, 0, 0);
        setd(g, 1, X1, 128, W2T, 128, X2, 128, 0, 1, cmb2, nullptr, 1, 0, 0);
        setd(g, 2, X1, 128, W2T, 128, X2, 128, 0, 1, cmb2, nullptr, 1, 0, 0);
        setd(g, 3, X1, 128, W2T, 128, X2, 128, 0, 1, cmb2, nullptr, 1, 0, 0);
        gemmL<<<dim3(1024, 1), 256, 0, stream>>>(g, flag);
    }

    // -------- 6. z / sigmoid / loss --------
    zloss<<<64, 256, 0, stream>>>(X2, cWpred, cbpred, labels, out, part);
    finloss<<<1, 64, 0, stream>>>(part, out);
}

// Round 4
// 242.634 us; speedup vs baseline: 1.1782x; 1.0468x over previous
//
#include <hip/hip_runtime.h>

#define ND   2048
#define BB   16384

typedef unsigned short u16;
typedef unsigned int u32;
typedef __attribute__((ext_vector_type(8))) short short8;
typedef __attribute__((ext_vector_type(4))) float f32x4;

__device__ inline float bf2f(u16 u) {
    union { u32 i; float f; } v; v.i = ((u32)u) << 16; return v.f;
}
__device__ inline u16 f2bf(float f) {
    union { float f; u32 i; } v; v.f = f;
    u32 i = v.i + 0x7fffu + ((v.i >> 16) & 1u);
    return (u16)(i >> 16);
}
__device__ inline float seluf(float x) {
    const float sc = 1.0507009873554805f, al = 1.6732632423543772f;
    return x > 0.f ? sc * x : sc * al * expm1f(x);
}

// ---------------- dtype sniffer ----------------
__global__ void detectk(const void* __restrict__ demb, u32* __restrict__ flag) {
    const u16* p = (const u16*)demb;
    int tid = threadIdx.x;  // 256
    int sane = 0;
    #pragma unroll
    for (int i = 0; i < 2; i++) {
        u16 u = p[4 * tid + 2 * i];
        int e = (u >> 7) & 0xFF;
        if (u == 0 || (e >= 0x66 && e <= 0x8C)) sane++;
    }
    __shared__ int red[256];
    red[tid] = sane; __syncthreads();
    for (int o = 128; o > 0; o >>= 1) {
        if (tid < o) red[tid] += red[tid + o];
        __syncthreads();
    }
    if (tid == 0) flag[0] = (red[0] < 300) ? 1u : 0u;
}

// ---------------- canonical bf16 conversion (26 segments, one launch) -------
#define NSEG 26
struct CvtArgs { const void* src[NSEG]; int off[NSEG]; int n[NSEG]; };

__global__ __launch_bounds__(256) void cvtk(CvtArgs a, u16* __restrict__ base,
                                            const u32* __restrict__ flag) {
    int seg = blockIdx.y;
    int n = a.n[seg];
    const void* s = a.src[seg];
    u16* d = base + a.off[seg];
    bool f32 = flag[0] != 0;
    int stride = gridDim.x * blockDim.x;
    for (int i = blockIdx.x * blockDim.x + threadIdx.x; i < n; i += stride)
        d[i] = f32 ? f2bf(((const float*)s)[i]) : ((const u16*)s)[i];
}

// ---------------- transpose (bf16, tiled 32x32) ----------------
__device__ inline void tpose_body(const u16* in, int R, int C,
                                  u16* out, int ldo, int ooff,
                                  u16 (*tile)[33]) {
    int c0 = blockIdx.x * 32, r0 = blockIdx.y * 32;
    int x = c0 + threadIdx.x;
    for (int i = threadIdx.y; i < 32; i += 8) {
        int r = r0 + i;
        tile[i][threadIdx.x] = (r < R && x < C) ? in[(size_t)r * C + x] : (u16)0;
    }
    __syncthreads();
    int rr = r0 + threadIdx.x;
    for (int i = threadIdx.y; i < 32; i += 8) {
        int cc = c0 + i;
        if (cc < C && rr < R) out[(size_t)cc * ldo + ooff + rr] = tile[threadIdx.x][i];
    }
}

__global__ void tpose_smalls(const u16* s0, const u16* s1, const u16* s2,
                             const u16* s3, const u16* s4, const u16* s5,
                             u16* W1T, u16* W2T, u16* WcTe, u16* WcTp) {
    __shared__ u16 tile[32][33];
    const u16* in; u16* out; int ldo, ooff;
    switch (blockIdx.z) {
        case 0:  in = s0; out = W1T;  ldo = 128; ooff = 0;   break;
        case 1:  in = s1; out = W2T;  ldo = 128; ooff = 0;   break;
        case 2:  in = s2; out = WcTe; ldo = 256; ooff = 0;   break;
        case 3:  in = s3; out = WcTe; ldo = 256; ooff = 128; break;
        case 4:  in = s4; out = WcTp; ldo = 256; ooff = 0;   break;
        default: in = s5; out = WcTp; ldo = 256; ooff = 128; break;
    }
    tpose_body(in, 128, 128, out, ldo, ooff, tile);
}

// ---------------- column-sum partials of embeddings (f32, deterministic) ----
__global__ __launch_bounds__(256) void colsump(const u16* __restrict__ demb,
                                               const u16* __restrict__ pemb,
                                               float* __restrict__ part) {
    int m = blockIdx.y;
    const u16* e = m ? pemb : demb;
    int t = threadIdx.x;
    int c2 = t & 63, rg = t >> 6;               // 64 dim-pairs x 4 row groups
    int r0 = blockIdx.x * 64;
    float s0 = 0.f, s1 = 0.f;
    for (int i = 0; i < 16; i++) {
        u32 v = *(const u32*)(e + (size_t)(r0 + i * 4 + rg) * 128 + c2 * 2);
        s0 += bf2f((u16)(v & 0xffffu));
        s1 += bf2f((u16)(v >> 16));
    }
    __shared__ float t0[256], t1[256];
    t0[t] = s0; t1[t] = s1;
    __syncthreads();
    if (t < 64) {
        float a0 = t0[t] + t0[t + 64] + t0[t + 128] + t0[t + 192];
        float a1 = t1[t] + t1[t + 64] + t1[t + 128] + t1[t + 192];
        part[(size_t)m * 4096 + blockIdx.x * 128 + t * 2 + 0] = a0;
        part[(size_t)m * 4096 + blockIdx.x * 128 + t * 2 + 1] = a1;
    }
}

// ---------------- combined biases + colsum finalization ----------------
__global__ void biasc(const u16* a0, const u16* a1, const u16* a2, u16* o0,
                      const u16* b0, const u16* b1, const u16* b2, u16* o1,
                      const float* __restrict__ part,
                      float* __restrict__ csd, float* __restrict__ csp) {
    int t = threadIdx.x;  // 128
    o0[t] = f2bf(bf2f(a0[t]) + bf2f(a1[t]) + bf2f(a2[t]));
    o1[t] = f2bf(bf2f(b0[t]) + bf2f(b1[t]) + bf2f(b2[t]));
    float sd = 0.f, sp = 0.f;
    for (int b = 0; b < 32; b++) {
        sd += part[b * 128 + t];
        sp += part[4096 + b * 128 + t];
    }
    csd[t] = sd;
    csp[t] = sp;
}

// ---------------- ko / qs projections ----------
__global__ __launch_bounds__(128) void koqs(
    const u16* __restrict__ demb, const u16* __restrict__ pemb,
    const u16* __restrict__ Wa1d, const u16* __restrict__ ba1d,
    const u16* __restrict__ Wa1p, const u16* __restrict__ ba1p,
    float* __restrict__ ko_d, float* __restrict__ qs_d,
    float* __restrict__ ko_p, float* __restrict__ qs_p) {
    int row = blockIdx.x, m = blockIdx.y, tid = threadIdx.x;
    const u16* src; const u16* W; const u16* bias; float* out;
    switch (m) {
        case 0:  src = pemb; W = Wa1d;            bias = nullptr; out = ko_d; break;
        case 1:  src = demb; W = Wa1d + 128 * 32; bias = ba1d;    out = qs_d; break;
        case 2:  src = demb; W = Wa1p;            bias = nullptr; out = ko_p; break;
        default: src = pemb; W = Wa1p + 128 * 32; bias = ba1p;    out = qs_p; break;
    }
    __shared__ float x[128];
    __shared__ float red[128];
    x[tid] = bf2f(src[(size_t)row * 128 + tid]);
    __syncthreads();
    int a = tid & 31, part = tid >> 5;
    float s = 0.f;
    #pragma unroll
    for (int k = 0; k < 32; k++) s += x[part * 32 + k] * bf2f(W[(part * 32 + k) * 32 + a]);
    red[tid] = s;
    __syncthreads();
    if (part == 0) {
        float t = red[a] + red[a + 32] + red[a + 64] + red[a + 96];
        if (bias) t += bf2f(bias[a]);
        out[(size_t)row * 32 + a] = t;
    }
}

// ---------------- CSR row lists: one streaming pass, no global atomics -----
struct CS {
    const void* adj[3];
    u16* ridx[3]; u32* rcnt[3];
};

__global__ __launch_bounds__(256) void csrbuild(CS c, const u32* __restrict__ flag) {
    int m = blockIdx.y, r = blockIdx.x, t = threadIdx.x;
    int lane = t & 63;
    bool f32 = flag[0] != 0;
    __shared__ u32 lcnt;
    if (t == 0) lcnt = 0;
    __syncthreads();
    float v[8];
    int c0 = t * 8;
    if (f32) {
        const float4* p = (const float4*)((const float*)c.adj[m] + (size_t)r * 2048 + c0);
        float4 x = p[0], y = p[1];
        v[0] = x.x; v[1] = x.y; v[2] = x.z; v[3] = x.w;
        v[4] = y.x; v[5] = y.y; v[6] = y.z; v[7] = y.w;
    } else {
        const uint4* p = (const uint4*)((const u16*)c.adj[m] + (size_t)r * 2048 + c0);
        uint4 x = p[0];
        u32 u[4] = {x.x, x.y, x.z, x.w};
        #pragma unroll
        for (int i = 0; i < 4; i++) {
            v[2 * i + 0] = (u[i] & 0xffffu) ? 1.f : 0.f;
            v[2 * i + 1] = (u[i] >> 16)     ? 1.f : 0.f;
        }
    }
    int cnt = 0;
    #pragma unroll
    for (int i = 0; i < 8; i++) cnt += (v[i] != 0.f) ? 1 : 0;
    // wave inclusive prefix scan of cnt
    int pfx = cnt;
    #pragma unroll
    for (int o = 1; o < 64; o <<= 1) {
        int s = __shfl_up(pfx, o, 64);
        if (lane >= o) pfx += s;
    }
    int wtot = __shfl(pfx, 63, 64);
    u32 wb = 0;
    if (lane == 0) wb = atomicAdd(&lcnt, (u32)wtot);
    wb = __shfl((int)wb, 0, 64);
    int o = (int)wb + pfx - cnt;
    u16* ridx = c.ridx[m] + (size_t)r * 2048;
    #pragma unroll
    for (int i = 0; i < 8; i++) {
        if (v[i] != 0.f) ridx[o++] = (u16)(c0 + i);
    }
    __syncthreads();
    if (t == 0) c.rcnt[m][r] = lcnt;
}

// ---------------- e_p column lists from row CSR (entry-parallel) ----------
__global__ __launch_bounds__(128) void colbuild(const u16* __restrict__ idx0,
                                                const u32* __restrict__ cnt0,
                                                u16* __restrict__ cidx,
                                                u32* __restrict__ ccnt) {
    int r = blockIdx.x;
    int n = (int)cnt0[r];
    const u16* row = idx0 + (size_t)r * 2048;
    for (int i = threadIdx.x; i < n; i += 128) {
        int c = (int)row[i];
        u32 q = atomicAdd(&ccnt[c], 1u);
        cidx[(size_t)c * 2048 + q] = (u16)r;
    }
}

// ---------------- sparse attention/avg aggregation (wide gather) -----------
// One wave per row. Lane decomposition: grp = lane>>4 (4 neighbor slots),
// dim = lane&15 (16B dim slice). One dwordx4/lane = 4 full rows per iter.
// attn: out[r,:] = (colsum(other) + sum_nz (e-1)*other_j) / (2048 + sum_nz (e-1))
// avg:  out[r,:] = (sum_nz other_j) / (nnz + 1e-8)
struct SP {
    const u16* idx[4]; const u32* cnt[4];
    const float* ko[4]; const float* qs[4];
    const u16* w2[4]; const u16* b2[4];
    const u16* emb[4]; const float* csum[4];
    u16* out[4]; int ooff[4]; int attn[4];
};

__global__ __launch_bounds__(256) void spagg(SP a) {
    int task = blockIdx.y;
    int tid = threadIdx.x;
    int wv = tid >> 6, lane = tid & 63;
    int grp = lane >> 4, dim = lane & 15;
    int r = blockIdx.x * 4 + wv;
    const u16* idx = a.idx[task] + (size_t)r * 2048;
    int nnz = (int)a.cnt[task][r];
    int isat = a.attn[task];
    const u16* emb = a.emb[task];
    const float* ko = a.ko[task];

    float qsr[32], w2h[32];
    float b2v = 0.f;
    if (isat) {
        const float4* qp = (const float4*)(a.qs[task] + (size_t)r * 32);
        #pragma unroll
        for (int i = 0; i < 8; i++) {
            float4 v = qp[i];
            qsr[4 * i + 0] = v.x; qsr[4 * i + 1] = v.y;
            qsr[4 * i + 2] = v.z; qsr[4 * i + 3] = v.w;
        }
        #pragma unroll
        for (int i = 0; i < 32; i++) w2h[i] = bf2f(a.w2[task][i]);
        b2v = bf2f(a.b2[task][0]);
    }

    float acc[8];
    #pragma unroll
    for (int t = 0; t < 8; t++) acc[t] = 0.f;
    float wsuml = 0.f;

    for (int base = 0; base < nnz; base += 64) {
        int i = base + lane;
        float w = 0.f;
        int j = 0;
        if (i < nnz) {
            j = (int)idx[i];
            if (isat) {
                const float4* kp = (const float4*)(ko + (size_t)j * 32);
                float s = 0.f;
                #pragma unroll
                for (int q = 0; q < 8; q++) {
                    float4 kv = kp[q];
                    s += fmaxf(qsr[4 * q + 0] + kv.x, 0.f) * w2h[4 * q + 0];
                    s += fmaxf(qsr[4 * q + 1] + kv.y, 0.f) * w2h[4 * q + 1];
                    s += fmaxf(qsr[4 * q + 2] + kv.z, 0.f) * w2h[4 * q + 2];
                    s += fmaxf(qsr[4 * q + 3] + kv.w, 0.f) * w2h[4 * q + 3];
                }
                w = __expf(fmaxf(s + b2v, 0.f)) - 1.f;
            } else {
                w = 1.f;
            }
        }
        wsuml += w;
        int cend = min(64, nnz - base);
        // 4 neighbor rows per iteration; inactive slots carry w=0,j=0 -> no-op
        #pragma unroll 4
        for (int k4 = 0; k4 < cend; k4 += 4) {
            int kk = k4 + grp;
            float wk = __shfl(w, kk, 64);
            int jk = __shfl(j, kk, 64);
            const uint4* p = (const uint4*)((const char*)emb + jk * 256 + dim * 16);
            uint4 vv = *p;
            u32 u[4] = {vv.x, vv.y, vv.z, vv.w};
            #pragma unroll
            for (int cc = 0; cc < 4; cc++) {
                acc[2 * cc + 0] = fmaf(wk, bf2f((u16)(u[cc] & 0xffffu)), acc[2 * cc + 0]);
                acc[2 * cc + 1] = fmaf(wk, bf2f((u16)(u[cc] >> 16)), acc[2 * cc + 1]);
            }
        }
    }

    // sum partial accumulators across the 4 groups
    #pragma unroll
    for (int t = 0; t < 8; t++) {
        acc[t] += __shfl_xor(acc[t], 32, 64);
        acc[t] += __shfl_xor(acc[t], 16, 64);
    }
    // full-wave weight sum
    #pragma unroll
    for (int o = 32; o > 0; o >>= 1) wsuml += __shfl_xor(wsuml, o, 64);

    if (grp == 0) {
        float v[8];
        if (isat) {
            float sc = 1.f / (2048.f + wsuml);
            const float* cs = a.csum[task] + dim * 8;
            #pragma unroll
            for (int t = 0; t < 8; t++) v[t] = (cs[t] + acc[t]) * sc;
        } else {
            float sc = 1.f / (wsuml + 1e-8f);
            #pragma unroll
            for (int t = 0; t < 8; t++) v[t] = acc[t] * sc;
        }
        uint4 pk;
        pk.x = (u32)f2bf(v[0]) | ((u32)f2bf(v[1]) << 16);
        pk.y = (u32)f2bf(v[2]) | ((u32)f2bf(v[3]) << 16);
        pk.z = (u32)f2bf(v[4]) | ((u32)f2bf(v[5]) << 16);
        pk.w = (u32)f2bf(v[6]) | ((u32)f2bf(v[7]) << 16);
        *(uint4*)(a.out[task] + (size_t)r * 256 + a.ooff[task] + dim * 8) = pk;
    }
}

// ---------------- MFMA GEMM: canonical LDS-tiled (combine stage) -----------
struct GD4 {
    const void* A[4]; const u16* BT[4]; u16* C[4];
    const u16* bias[4]; const float* rs[4];
    int lda[4], ldb[4], ldc[4], coff[4], kiters[4], act[4], araw[4], rsmode[4];
};

#define PADK 136

__global__ __launch_bounds__(256, 2) void gemmL(GD4 g, const u32* __restrict__ flag) {
    __shared__ __align__(16) u16 As[16][PADK];
    __shared__ __align__(16) u16 Bs[128][PADK];
    int z = blockIdx.y;
    const void* A = g.A[z];
    const u16* BT = g.BT[z];
    int lda = g.lda[z], ldb = g.ldb[z];
    int kiters = g.kiters[z];
    int tid = threadIdx.x;
    int lane = tid & 63, wv = tid >> 6;
    int mrow = lane & 15, quad = lane >> 4;
    int m0 = blockIdx.x * 16;
    int c0 = wv * 32;
    int sr = tid >> 4, sk = (tid & 15) * 8;
    f32x4 acc0 = {0.f, 0.f, 0.f, 0.f}, acc1 = {0.f, 0.f, 0.f, 0.f};

    short8 ra, rb[8];
    auto ldstage = [&](int kb) {
        ra = *(const short8*)((const u16*)A + (size_t)(m0 + sr) * lda + kb + sk);
        const u16* bbase = BT + (size_t)sr * ldb + kb + sk;
        #pragma unroll
        for (int i = 0; i < 8; i++)
            rb[i] = *(const short8*)(bbase + (size_t)i * 16 * ldb);
    };
    auto ststage = [&]() {
        *(short8*)(&As[sr][sk]) = ra;
        #pragma unroll
        for (int i = 0; i < 8; i++)
            *(short8*)(&Bs[i * 16 + sr][sk]) = rb[i];
    };
    auto compute = [&]() {
        #pragma unroll
        for (int ks = 0; ks < 4; ks++) {
            short8 af = *(const short8*)(&As[mrow][ks * 32 + quad * 8]);
            short8 b0 = *(const short8*)(&Bs[c0 + mrow][ks * 32 + quad * 8]);
            short8 b1 = *(const short8*)(&Bs[c0 + 16 + mrow][ks * 32 + quad * 8]);
            acc0 = __builtin_amdgcn_mfma_f32_16x16x32_bf16(af, b0, acc0, 0, 0, 0);
            acc1 = __builtin_amdgcn_mfma_f32_16x16x32_bf16(af, b1, acc1, 0, 0, 0);
        }
    };

    ldstage(0);
    #pragma unroll 1
    for (int it = 0; it < kiters - 1; ++it) {
        ststage();
        __syncthreads();
        ldstage((it + 1) * 128);
        compute();
        __syncthreads();
    }
    ststage();
    __syncthreads();
    compute();

    const float* rs = g.rs[z];
    int rsmode = g.rsmode[z];
    const u16* bi = g.bias[z];
    u16* C = g.C[z];
    int ldc = g.ldc[z], coff = g.coff[z], act = g.act[z];
    int n0 = c0 + mrow, n1 = n0 + 16;
    float bv0 = bi ? bf2f(bi[n0]) : 0.f;
    float bv1 = bi ? bf2f(bi[n1]) : 0.f;
    #pragma unroll
    for (int r = 0; r < 4; r++) {
        int row = m0 + quad * 4 + r;
        float v0 = acc0[r], v1 = acc1[r];
        if (rsmode == 1) { float sc = rs[row]; v0 *= sc; v1 *= sc; }
        else if (rsmode == 2) {
            float t = 0.f;
            #pragma unroll
            for (int p = 0; p < 8; p++) t += rs[row + p * 2048];
            float sc = 1.f / t;
            v0 *= sc; v1 *= sc;
        }
        v0 += bv0; v1 += bv1;
        if (act) { v0 = seluf(v0); v1 = seluf(v1); }
        C[(size_t)row * ldc + coff + n0] = f2bf(v0);
        C[(size_t)row * ldc + coff + n1] = f2bf(v1);
    }
}

// ---------------- fused pair MLP: gather + GEMM1 + GEMM2 + z/sig/loss ------
// 256 blocks x 64 pairs. Xs holds X, then X1, both bf16. Ws holds W1 then W2.
#define PADX 136
__global__ __launch_bounds__(256, 2) void mlpfused(
    const u16* __restrict__ he, const u16* __restrict__ hp,
    const int* __restrict__ di, const int* __restrict__ dr,
    const u16* __restrict__ W1T, const u16* __restrict__ b1,
    const u16* __restrict__ W2T, const u16* __restrict__ b2,
    const u16* __restrict__ wpred, const u16* __restrict__ bpred,
    const int* __restrict__ labels,
    float* __restrict__ out, float* __restrict__ part) {
    __shared__ __align__(16) u16 Xs[64][PADX];
    __shared__ __align__(16) u16 Ws[128][PADX];
    __shared__ float wred[4];
    int tid = threadIdx.x;
    int lane = tid & 63, wv = tid >> 6;
    int mrow = lane & 15, quad = lane >> 4;
    int p0 = blockIdx.x * 64;

    // ---- stage X = he[ia] * hp[ic] (bf16 product) ----
    {
        int row = tid >> 2, sub = tid & 3;       // 64 rows x 4 threads
        int b = p0 + row;
        int ia = di[b], ic = dr[b];
        const uint4* pe = (const uint4*)(he + (size_t)ia * 128 + sub * 32);
        const uint4* pp = (const uint4*)(hp + (size_t)ic * 128 + sub * 32);
        #pragma unroll
        for (int q = 0; q < 4; q++) {
            uint4 ue = pe[q], up = pp[q];
            u32 eu[4] = {ue.x, ue.y, ue.z, ue.w};
            u32 pu[4] = {up.x, up.y, up.z, up.w};
            #pragma unroll
            for (int c = 0; c < 4; c++) {
                float lo = bf2f((u16)(eu[c] & 0xffffu)) * bf2f((u16)(pu[c] & 0xffffu));
                float hi = bf2f((u16)(eu[c] >> 16)) * bf2f((u16)(pu[c] >> 16));
                *(u32*)(&Xs[row][sub * 32 + q * 8 + c * 2]) =
                    (u32)f2bf(lo) | ((u32)f2bf(hi) << 16);
            }
        }
    }
    // ---- stage W1 ----
    {
        int n = tid >> 1, half = tid & 1;
        const short8* src = (const short8*)(W1T + (size_t)n * 128 + half * 64);
        short8* dst = (short8*)(&Ws[n][half * 64]);
        #pragma unroll
        for (int i = 0; i < 8; i++) dst[i] = src[i];
    }
    __syncthreads();

    // ---- GEMM1: X1 = selu(X @ W1 + b1) ----
    f32x4 acc[8];
    #pragma unroll
    for (int nt = 0; nt < 8; nt++) acc[nt] = {0.f, 0.f, 0.f, 0.f};
    #pragma unroll
    for (int ks = 0; ks < 4; ks++) {
        short8 af = *(const short8*)(&Xs[wv * 16 + mrow][ks * 32 + quad * 8]);
        #pragma unroll
        for (int nt = 0; nt < 8; nt++) {
            short8 bfv = *(const short8*)(&Ws[nt * 16 + mrow][ks * 32 + quad * 8]);
            acc[nt] = __builtin_amdgcn_mfma_f32_16x16x32_bf16(af, bfv, acc[nt], 0, 0, 0);
        }
    }
    __syncthreads();   // all waves done reading Xs/Ws
    #pragma unroll
    for (int nt = 0; nt < 8; nt++) {
        int col = nt * 16 + mrow;
        float bv = bf2f(b1[col]);
        #pragma unroll
        for (int r = 0; r < 4; r++) {
            int row = wv * 16 + quad * 4 + r;
            Xs[row][col] = f2bf(seluf(acc[nt][r] + bv));
        }
    }
    // ---- stage W2 ----
    {
        int n = tid >> 1, half = tid & 1;
        const short8* src = (const short8*)(W2T + (size_t)n * 128 + half * 64);
        short8* dst = (short8*)(&Ws[n][half * 64]);
        #pragma unroll
        for (int i = 0; i < 8; i++) dst[i] = src[i];
    }
    __syncthreads();

    // ---- GEMM2: X2 = selu(X1 @ W2 + b2) ----
    #pragma unroll
    for (int nt = 0; nt < 8; nt++) acc[nt] = {0.f, 0.f, 0.f, 0.f};
    #pragma unroll
    for (int ks = 0; ks < 4; ks++) {
        short8 af = *(const short8*)(&Xs[wv * 16 + mrow][ks * 32 + quad * 8]);
        #pragma unroll
        for (int nt = 0; nt < 8; nt++) {
            short8 bfv = *(const short8*)(&Ws[nt * 16 + mrow][ks * 32 + quad * 8]);
            acc[nt] = __builtin_amdgcn_mfma_f32_16x16x32_bf16(af, bfv, acc[nt], 0, 0, 0);
        }
    }

    // ---- z = X2 @ wpred + bpred; sigmoid; BCE loss ----
    float zp[4] = {0.f, 0.f, 0.f, 0.f};
    #pragma unroll
    for (int nt = 0; nt < 8; nt++) {
        int col = nt * 16 + mrow;
        float bv = bf2f(b2[col]);
        float wp = bf2f(wpred[col]);
        #pragma unroll
        for (int r = 0; r < 4; r++) {
            float x2 = bf2f(f2bf(seluf(acc[nt][r] + bv)));  // bf16 round-trip
            zp[r] = fmaf(x2, wp, zp[r]);
        }
    }
    // reduce over mrow (16 lanes within quad)
    #pragma unroll
    for (int r = 0; r < 4; r++) {
        #pragma unroll
        for (int o = 1; o < 16; o <<= 1) zp[r] += __shfl_xor(zp[r], o, 64);
    }
    float bpv = bf2f(bpred[0]);
    float lsum = 0.f;
    #pragma unroll
    for (int r = 0; r < 4; r++) {
        int b = p0 + wv * 16 + quad * 4 + r;
        float z = zp[r] + bpv;
        float sig = 1.f / (1.f + __expf(-z));
        if (mrow == 0) out[1 + b] = sig;
        float y = (float)labels[b];
        lsum += fmaxf(z, 0.f) - z * y + log1pf(__expf(-fabsf(z)));
    }
    // All 16 mrow lanes within a quad hold IDENTICAL lsum (zp was reduced
    // over mrow). The butterfly below sums across the 4 quads only (lane
    // bits 4-5), so NO duplicate scaling is needed: the result is exactly
    // the 16-row wave sum, identical on every lane.
    lsum += __shfl_xor(lsum, 16, 64);
    lsum += __shfl_xor(lsum, 32, 64);
    if (lane == 0) wred[wv] = lsum;
    __syncthreads();
    if (tid == 0) part[blockIdx.x] = wred[0] + wred[1] + wred[2] + wred[3];
}

__global__ void finloss(const float* __restrict__ part, float* __restrict__ out) {
    __shared__ float s[256];
    int t = threadIdx.x;
    s[t] = part[t];
    __syncthreads();
    for (int o = 128; o > 0; o >>= 1) {
        if (t < o) s[t] += s[t + o];
        __syncthreads();
    }
    if (t == 0) out[0] = s[0] * (1.f / 16384.f);
}

// ---------------- launch ----------------
extern "C" void kernel_launch(void* const* d_in, const int* in_sizes, int n_in,
                              void* d_out, int out_size, void* d_ws, size_t ws_size,
                              hipStream_t stream) {
    const void* e_p_adj = d_in[0];
    const void* e_e_adj = d_in[1];
    const void* p_p_adj = d_in[2];
    const int* in_dis  = (const int*)d_in[3];
    const int* in_drug = (const int*)d_in[4];
    const int* labels  = (const int*)d_in[5];
    float* out = (float*)d_out;

    // -------- workspace layout --------
    char* ws = (char*)d_ws;
    size_t off = 0;
    auto take = [&](size_t bytes) { char* p = ws + off; off = (off + bytes + 255) & ~(size_t)255; return p; };
    u16*   A_e   = (u16*)take((size_t)2048 * 256 * 2);
    u16*   A_p   = (u16*)take((size_t)2048 * 256 * 2);
    u16*   WcTe  = (u16*)take((size_t)128 * 256 * 2);
    u16*   WcTp  = (u16*)take((size_t)128 * 256 * 2);
    u16*   W1T   = (u16*)take((size_t)128 * 128 * 2);
    u16*   W2T   = (u16*)take((size_t)128 * 128 * 2);
    u16*   b_e   = (u16*)take(256);
    u16*   b_p   = (u16*)take(256);
    u16*   h_e   = (u16*)take((size_t)2048 * 128 * 2);
    u16*   h_p   = (u16*)take((size_t)2048 * 128 * 2);
    float* ko_d  = (float*)take((size_t)2048 * 32 * 4);
    float* qs_d  = (float*)take((size_t)2048 * 32 * 4);
    float* ko_p  = (float*)take((size_t)2048 * 32 * 4);
    float* qs_p  = (float*)take((size_t)2048 * 32 * 4);
    float* cspart = (float*)take((size_t)2 * 32 * 128 * 4);
    float* csd   = (float*)take(128 * 4);
    float* csp   = (float*)take(128 * 4);
    float* part  = (float*)take(256 * 4);
    u32*   flag  = (u32*)take(256);
    u16*   canon = (u16*)take((size_t)700000 * 2);
    u16*   idx0  = (u16*)take((size_t)2048 * 2048 * 2);  // e_p rows (disease)
    u16*   idx1  = (u16*)take((size_t)2048 * 2048 * 2);  // e_p cols (drug)
    u16*   idx2  = (u16*)take((size_t)2048 * 2048 * 2);  // e_e rows
    u16*   idx3  = (u16*)take((size_t)2048 * 2048 * 2);  // p_p rows
    u32*   cnt0  = (u32*)take(2048 * 4);
    u32*   cnt2  = (u32*)take(2048 * 4);
    u32*   cnt3  = (u32*)take(2048 * 4);
    u32*   cntT  = (u32*)take(2048 * 4);                 // e_p col counts (zeroed)

    // -------- canonical parameter table --------
    const int segidx[NSEG] = {6, 7, 14, 18, 8, 22, 11, 24, 26, 28,
                              15, 16, 17, 19, 20, 21,
                              9, 10, 12, 13, 23, 25, 27, 29, 30, 31};
    const int segn[NSEG]   = {262144, 262144, 8192, 8192, 16384, 16384, 16384, 16384, 16384, 16384,
                              32, 32, 1, 32, 32, 1,
                              128, 128, 128, 128, 128, 128, 128, 128, 128, 1};
    CvtArgs ca;
    u16* cp[NSEG];
    {
        int o = 0;
        for (int i = 0; i < NSEG; i++) {
            ca.src[i] = d_in[segidx[i]];
            ca.off[i] = o;
            ca.n[i] = segn[i];
            cp[i] = canon + o;
            o += (segn[i] + 15) & ~15;
        }
    }
    u16 *cdemb = cp[0], *cpemb = cp[1], *cWa1d = cp[2], *cWa1p = cp[3];
    u16 *cWdg = cp[4], *cWd2 = cp[5], *cWpg = cp[6], *cWp3 = cp[7];
    u16 *cW1 = cp[8], *cW2 = cp[9];
    u16 *cba1d = cp[10], *cWa2d = cp[11], *cba2d = cp[12];
    u16 *cba1p = cp[13], *cWa2p = cp[14], *cba2p = cp[15];
    u16 *cbdg_lin = cp[16], *cbdg = cp[17], *cbpg_lin = cp[18], *cbpg = cp[19];
    u16 *cbd2 = cp[20], *cbp3 = cp[21], *cmb1 = cp[22], *cmb2 = cp[23];
    u16 *cWpred = cp[24], *cbpred = cp[25];

    // -------- 0. dtype detection + canonicalization --------
    detectk<<<1, 256, 0, stream>>>(d_in[6], flag);
    cvtk<<<dim3(64, NSEG), 256, 0, stream>>>(ca, canon, flag);

    // -------- 1. CSR row lists (streaming) + e_p column lists --------
    hipMemsetAsync(cntT, 0, 2048 * sizeof(u32), stream);
    {
        CS cs;
        cs.adj[0] = e_p_adj; cs.ridx[0] = idx0; cs.rcnt[0] = cnt0;
        cs.adj[1] = e_e_adj; cs.ridx[1] = idx2; cs.rcnt[1] = cnt2;
        cs.adj[2] = p_p_adj; cs.ridx[2] = idx3; cs.rcnt[2] = cnt3;
        csrbuild<<<dim3(2048, 3), 256, 0, stream>>>(cs, flag);
    }
    colbuild<<<2048, 128, 0, stream>>>(idx0, cnt0, idx1, cntT);

    // -------- 2. small prep --------
    colsump<<<dim3(32, 2), 256, 0, stream>>>(cdemb, cpemb, cspart);
    tpose_smalls<<<dim3(4, 4, 6), dim3(32, 8), 0, stream>>>(
        cW1, cW2, cWdg, cWd2, cWpg, cWp3, W1T, W2T, WcTe, WcTp);
    biasc<<<1, 128, 0, stream>>>(cbdg_lin, cbdg, cbd2, b_e, cbpg_lin, cbpg, cbp3, b_p,
                                 cspart, csd, csp);
    koqs<<<dim3(2048, 4), 128, 0, stream>>>(cdemb, cpemb, cWa1d, cba1d, cWa1p, cba1p,
                                            ko_d, qs_d, ko_p, qs_p);

    // -------- 3. sparse attention + avg aggregation --------
    {
        SP sp;
        // task0: disease-side attention (neighbors = drugs)
        sp.idx[0] = idx0; sp.cnt[0] = cnt0; sp.ko[0] = ko_d; sp.qs[0] = qs_d;
        sp.w2[0] = cWa2d; sp.b2[0] = cba2d; sp.emb[0] = cpemb; sp.csum[0] = csp;
        sp.out[0] = A_e; sp.ooff[0] = 0; sp.attn[0] = 1;
        // task1: e_e average (neighbors = diseases)
        sp.idx[1] = idx2; sp.cnt[1] = cnt2; sp.ko[1] = ko_d; sp.qs[1] = qs_d;
        sp.w2[1] = cWa2d; sp.b2[1] = cba2d; sp.emb[1] = cdemb; sp.csum[1] = csd;
        sp.out[1] = A_e; sp.ooff[1] = 128; sp.attn[1] = 0;
        // task2: drug-side attention (neighbors = diseases, e_p columns)
        sp.idx[2] = idx1; sp.cnt[2] = cntT; sp.ko[2] = ko_p; sp.qs[2] = qs_p;
        sp.w2[2] = cWa2p; sp.b2[2] = cba2p; sp.emb[2] = cdemb; sp.csum[2] = csd;
        sp.out[2] = A_p; sp.ooff[2] = 0; sp.attn[2] = 1;
        // task3: p_p average (neighbors = drugs)
        sp.idx[3] = idx3; sp.cnt[3] = cnt3; sp.ko[3] = ko_p; sp.qs[3] = qs_p;
        sp.w2[3] = cWa2p; sp.b2[3] = cba2p; sp.emb[3] = cpemb; sp.csum[3] = csp;
        sp.out[3] = A_p; sp.ooff[3] = 128; sp.attn[3] = 0;
        spagg<<<dim3(512, 4), 256, 0, stream>>>(sp);
    }

    auto setd = [](GD4& g, int z, const void* A, int lda, const u16* BT, int ldb,
                   u16* C, int ldc, int coff, int ki, const u16* bi,
                   const float* rs, int act, int araw, int rm) {
        g.A[z] = A; g.lda[z] = lda; g.BT[z] = BT; g.ldb[z] = ldb;
        g.C[z] = C; g.ldc[z] = ldc; g.coff[z] = coff; g.kiters[z] = ki;
        g.bias[z] = bi; g.rs[z] = rs; g.act[z] = act; g.araw[z] = araw; g.rsmode[z] = rm;
    };

    // -------- 4. combine GEMMs (bias + SELU), batched ----------------------
    {
        GD4 g;
        setd(g, 0, A_e, 256, WcTe, 256, h_e, 128, 0, 2, b_e, nullptr, 1, 0, 0);
        setd(g, 1, A_p, 256, WcTp, 256, h_p, 128, 0, 2, b_p, nullptr, 1, 0, 0);
        setd(g, 2, A_e, 256, WcTe, 256, h_e, 128, 0, 2, b_e, nullptr, 1, 0, 0);
        setd(g, 3, A_e, 256, WcTe, 256, h_e, 128, 0, 2, b_e, nullptr, 1, 0, 0);
        gemmL<<<dim3(128, 2), 256, 0, stream>>>(g, flag);
    }

    // -------- 5. fused pair MLP + loss --------
    mlpfused<<<256, 256, 0, stream>>>(h_e, h_p, in_dis, in_drug,
                                      W1T, cmb1, W2T, cmb2,
                                      cWpred, cbpred, labels, out, part);
    finloss<<<1, 256, 0, stream>>>(part, out);
}

// Round 5
// 236.496 us; speedup vs baseline: 1.2088x; 1.0260x over previous
//
#include <hip/hip_runtime.h>

#define ND   2048
#define BB   16384

typedef unsigned short u16;
typedef unsigned int u32;
typedef __attribute__((ext_vector_type(8))) short short8;
typedef __attribute__((ext_vector_type(4))) float f32x4;

__device__ inline float bf2f(u16 u) {
    union { u32 i; float f; } v; v.i = ((u32)u) << 16; return v.f;
}
__device__ inline u16 f2bf(float f) {
    union { float f; u32 i; } v; v.f = f;
    u32 i = v.i + 0x7fffu + ((v.i >> 16) & 1u);
    return (u16)(i >> 16);
}
__device__ inline float seluf(float x) {
    const float sc = 1.0507009873554805f, al = 1.6732632423543772f;
    return x > 0.f ? sc * x : sc * al * expm1f(x);
}

// ---------------- dtype sniffer + counter zeroing ----------------
__global__ void detectk(const void* __restrict__ demb, u32* __restrict__ flag,
                        u32* __restrict__ cntT) {
    const u16* p = (const u16*)demb;
    int tid = threadIdx.x;  // 256
    // zero the e_p column counters (replaces a hipMemsetAsync launch)
    #pragma unroll
    for (int i = 0; i < 8; i++) cntT[i * 256 + tid] = 0u;
    int sane = 0;
    #pragma unroll
    for (int i = 0; i < 2; i++) {
        u16 u = p[4 * tid + 2 * i];
        int e = (u >> 7) & 0xFF;
        if (u == 0 || (e >= 0x66 && e <= 0x8C)) sane++;
    }
    __shared__ int red[256];
    red[tid] = sane; __syncthreads();
    for (int o = 128; o > 0; o >>= 1) {
        if (tid < o) red[tid] += red[tid + o];
        __syncthreads();
    }
    if (tid == 0) flag[0] = (red[0] < 300) ? 1u : 0u;
}

// ---------------- merged: canonical conversion + CSR row lists -------------
// blocks [0,6144): csrbuild role (m = bx>>11, r = bx&2047)
// blocks [6144,6144+1664): cvtk role (seg = idx>>6, 64 blocks/segment)
#define NSEG 26
struct CvtArgs { const void* src[NSEG]; int off[NSEG]; int n[NSEG]; };
struct CS {
    const void* adj[3];
    u16* ridx[3]; u32* rcnt[3];
};

__global__ __launch_bounds__(256) void cvtcsr(CvtArgs a, u16* __restrict__ base,
                                              CS c, const u32* __restrict__ flag) {
    int bx = blockIdx.x;
    int t = threadIdx.x;
    bool f32 = flag[0] != 0;
    if (bx < 6144) {
        // ---- CSR row-list role (streaming, wave-scan compaction) ----
        int m = bx >> 11, r = bx & 2047;
        int lane = t & 63;
        __shared__ u32 lcnt;
        if (t == 0) lcnt = 0;
        __syncthreads();
        float v[8];
        int c0 = t * 8;
        if (f32) {
            const float4* p = (const float4*)((const float*)c.adj[m] + (size_t)r * 2048 + c0);
            float4 x = p[0], y = p[1];
            v[0] = x.x; v[1] = x.y; v[2] = x.z; v[3] = x.w;
            v[4] = y.x; v[5] = y.y; v[6] = y.z; v[7] = y.w;
        } else {
            const uint4* p = (const uint4*)((const u16*)c.adj[m] + (size_t)r * 2048 + c0);
            uint4 x = p[0];
            u32 u[4] = {x.x, x.y, x.z, x.w};
            #pragma unroll
            for (int i = 0; i < 4; i++) {
                v[2 * i + 0] = (u[i] & 0xffffu) ? 1.f : 0.f;
                v[2 * i + 1] = (u[i] >> 16)     ? 1.f : 0.f;
            }
        }
        int cnt = 0;
        #pragma unroll
        for (int i = 0; i < 8; i++) cnt += (v[i] != 0.f) ? 1 : 0;
        int pfx = cnt;
        #pragma unroll
        for (int o = 1; o < 64; o <<= 1) {
            int s = __shfl_up(pfx, o, 64);
            if (lane >= o) pfx += s;
        }
        int wtot = __shfl(pfx, 63, 64);
        u32 wb = 0;
        if (lane == 0) wb = atomicAdd(&lcnt, (u32)wtot);
        wb = __shfl((int)wb, 0, 64);
        int o = (int)wb + pfx - cnt;
        u16* ridx = c.ridx[m] + (size_t)r * 2048;
        #pragma unroll
        for (int i = 0; i < 8; i++) {
            if (v[i] != 0.f) ridx[o++] = (u16)(c0 + i);
        }
        __syncthreads();
        if (t == 0) c.rcnt[m][r] = lcnt;
    } else {
        // ---- canonical bf16 conversion role ----
        int idx = bx - 6144;
        int seg = idx >> 6, xb = idx & 63;
        int n = a.n[seg];
        const void* s = a.src[seg];
        u16* d = base + a.off[seg];
        for (int i = xb * 256 + t; i < n; i += 16384)
            d[i] = f32 ? f2bf(((const float*)s)[i]) : ((const u16*)s)[i];
    }
}

// ---------------- merged prep: koqs + colbuild + tpose + colsump + biasc ---
// blocks [0,4096): koqs (2 rows per block, 8192 units)
// blocks [4096,6144): colbuild (2048 rows)
// blocks [6144,6240): tpose_smalls (96 tiles: z*16 + yb*4 + xb)
// blocks [6240,6304): colsump (64: m*32 + xb)
// block  6304: biasc
struct PR {
    // koqs
    const u16* demb; const u16* pemb;
    const u16* Wa1d; const u16* ba1d;
    const u16* Wa1p; const u16* ba1p;
    float* ko_d; float* qs_d; float* ko_p; float* qs_p;
    // colbuild
    const u16* idx0; const u32* cnt0; u16* cidx; u32* ccnt;
    // tpose sources / dests
    const u16* ts[6]; u16* W1T; u16* W2T; u16* WcTe; u16* WcTp;
    // colsump/biasc
    float* cspart;
    const u16* ba[3]; const u16* bb[3]; u16* b_e; u16* b_p;
    float* csd; float* csp;
};

__global__ __launch_bounds__(256) void prep2(PR p) {
    int bx = blockIdx.x;
    int tid = threadIdx.x;
    __shared__ float sx[2][128];
    __shared__ float sred[2][128];
    __shared__ u16 stile[32][33];
    __shared__ float st0[256], st1[256];

    if (bx < 4096) {
        // ---- koqs: unit = bx*2 + (tid>>7); row = unit & 2047, m = unit >> 11
        int sub = tid >> 7, t = tid & 127;
        int unit = bx * 2 + sub;
        int row = unit & 2047, m = unit >> 11;
        const u16* src; const u16* W; const u16* bias; float* out;
        switch (m) {
            case 0:  src = p.pemb; W = p.Wa1d;            bias = nullptr; out = p.ko_d; break;
            case 1:  src = p.demb; W = p.Wa1d + 128 * 32; bias = p.ba1d;  out = p.qs_d; break;
            case 2:  src = p.demb; W = p.Wa1p;            bias = nullptr; out = p.ko_p; break;
            default: src = p.pemb; W = p.Wa1p + 128 * 32; bias = p.ba1p;  out = p.qs_p; break;
        }
        sx[sub][t] = bf2f(src[(size_t)row * 128 + t]);
        __syncthreads();
        int a = t & 31, part = t >> 5;
        float s = 0.f;
        #pragma unroll
        for (int k = 0; k < 32; k++)
            s += sx[sub][part * 32 + k] * bf2f(W[(part * 32 + k) * 32 + a]);
        sred[sub][t] = s;
        __syncthreads();
        if (part == 0) {
            float tt = sred[sub][a] + sred[sub][a + 32] + sred[sub][a + 64] + sred[sub][a + 96];
            if (bias) tt += bf2f(bias[a]);
            out[(size_t)row * 32 + a] = tt;
        }
    } else if (bx < 6144) {
        // ---- colbuild: e_p column lists from row CSR (entry-parallel)
        int r = bx - 4096;
        int n = (int)p.cnt0[r];
        const u16* row = p.idx0 + (size_t)r * 2048;
        for (int i = tid; i < n; i += 256) {
            int cc = (int)row[i];
            u32 q = atomicAdd(&p.ccnt[cc], 1u);
            p.cidx[(size_t)cc * 2048 + q] = (u16)r;
        }
    } else if (bx < 6240) {
        // ---- tpose_smalls: 96 tiles
        int id = bx - 6144;
        int z = id >> 4, rem = id & 15;
        int c0 = (rem & 3) * 32, r0 = (rem >> 2) * 32;
        const u16* in = p.ts[z];
        u16* out; int ldo, ooff;
        switch (z) {
            case 0:  out = p.W1T;  ldo = 128; ooff = 0;   break;
            case 1:  out = p.W2T;  ldo = 128; ooff = 0;   break;
            case 2:  out = p.WcTe; ldo = 256; ooff = 0;   break;
            case 3:  out = p.WcTe; ldo = 256; ooff = 128; break;
            case 4:  out = p.WcTp; ldo = 256; ooff = 0;   break;
            default: out = p.WcTp; ldo = 256; ooff = 128; break;
        }
        int tx = tid & 31, ty = tid >> 5;   // 32 x 8
        int x = c0 + tx;
        for (int i = ty; i < 32; i += 8)
            stile[i][tx] = in[(size_t)(r0 + i) * 128 + x];
        __syncthreads();
        int rr = r0 + tx;
        for (int i = ty; i < 32; i += 8)
            out[(size_t)(c0 + i) * ldo + ooff + rr] = stile[tx][i];
    } else if (bx < 6304) {
        // ---- colsump: 64 blocks (m*32 + xb)
        int id = bx - 6240;
        int m = id >> 5, xb = id & 31;
        const u16* e = m ? p.pemb : p.demb;
        int c2 = tid & 63, rg = tid >> 6;
        int r0 = xb * 64;
        float s0 = 0.f, s1 = 0.f;
        for (int i = 0; i < 16; i++) {
            u32 v = *(const u32*)(e + (size_t)(r0 + i * 4 + rg) * 128 + c2 * 2);
            s0 += bf2f((u16)(v & 0xffffu));
            s1 += bf2f((u16)(v >> 16));
        }
        st0[tid] = s0; st1[tid] = s1;
        __syncthreads();
        if (tid < 64) {
            float a0 = st0[tid] + st0[tid + 64] + st0[tid + 128] + st0[tid + 192];
            float a1 = st1[tid] + st1[tid + 64] + st1[tid + 128] + st1[tid + 192];
            p.cspart[(size_t)m * 4096 + xb * 128 + tid * 2 + 0] = a0;
            p.cspart[(size_t)m * 4096 + xb * 128 + tid * 2 + 1] = a1;
        }
    } else {
        // ---- biasc (single block; 128 active threads). NOTE: reads cspart,
        // which colsump blocks of THIS SAME launch write -> must not fuse!
        // (kept separate: see biasfin kernel below)
    }
}

// biasc + colsum finalization must run after colsump blocks complete ->
// separate tiny kernel (cross-block dependency within prep2 is illegal).
__global__ void biasfin(PR p) {
    int t = threadIdx.x;  // 128
    p.b_e[t] = f2bf(bf2f(p.ba[0][t]) + bf2f(p.ba[1][t]) + bf2f(p.ba[2][t]));
    p.b_p[t] = f2bf(bf2f(p.bb[0][t]) + bf2f(p.bb[1][t]) + bf2f(p.bb[2][t]));
    float sd = 0.f, sp = 0.f;
    for (int b = 0; b < 32; b++) {
        sd += p.cspart[b * 128 + t];
        sp += p.cspart[4096 + b * 128 + t];
    }
    p.csd[t] = sd;
    p.csp[t] = sp;
}

// ---------------- sparse attention/avg aggregation (wide gather) -----------
struct SP {
    const u16* idx[4]; const u32* cnt[4];
    const float* ko[4]; const float* qs[4];
    const u16* w2[4]; const u16* b2[4];
    const u16* emb[4]; const float* csum[4];
    u16* out[4]; int ooff[4]; int attn[4];
};

__global__ __launch_bounds__(256) void spagg(SP a) {
    int task = blockIdx.y;
    int tid = threadIdx.x;
    int wv = tid >> 6, lane = tid & 63;
    int grp = lane >> 4, dim = lane & 15;
    int r = blockIdx.x * 4 + wv;
    const u16* idx = a.idx[task] + (size_t)r * 2048;
    int nnz = (int)a.cnt[task][r];
    int isat = a.attn[task];
    const u16* emb = a.emb[task];
    const float* ko = a.ko[task];

    float qsr[32], w2h[32];
    float b2v = 0.f;
    if (isat) {
        const float4* qp = (const float4*)(a.qs[task] + (size_t)r * 32);
        #pragma unroll
        for (int i = 0; i < 8; i++) {
            float4 v = qp[i];
            qsr[4 * i + 0] = v.x; qsr[4 * i + 1] = v.y;
            qsr[4 * i + 2] = v.z; qsr[4 * i + 3] = v.w;
        }
        #pragma unroll
        for (int i = 0; i < 32; i++) w2h[i] = bf2f(a.w2[task][i]);
        b2v = bf2f(a.b2[task][0]);
    }

    float acc[8];
    #pragma unroll
    for (int t = 0; t < 8; t++) acc[t] = 0.f;
    float wsuml = 0.f;

    for (int base = 0; base < nnz; base += 64) {
        int i = base + lane;
        float w = 0.f;
        int j = 0;
        if (i < nnz) {
            j = (int)idx[i];
            if (isat) {
                const float4* kp = (const float4*)(ko + (size_t)j * 32);
                float s = 0.f;
                #pragma unroll
                for (int q = 0; q < 8; q++) {
                    float4 kv = kp[q];
                    s += fmaxf(qsr[4 * q + 0] + kv.x, 0.f) * w2h[4 * q + 0];
                    s += fmaxf(qsr[4 * q + 1] + kv.y, 0.f) * w2h[4 * q + 1];
                    s += fmaxf(qsr[4 * q + 2] + kv.z, 0.f) * w2h[4 * q + 2];
                    s += fmaxf(qsr[4 * q + 3] + kv.w, 0.f) * w2h[4 * q + 3];
                }
                w = __expf(fmaxf(s + b2v, 0.f)) - 1.f;
                wsuml += w;
            }
        }
        int cend = min(64, nnz - base);
        #pragma unroll 4
        for (int k4 = 0; k4 < cend; k4 += 4) {
            int kk = k4 + grp;
            int jk = __shfl(j, kk, 64);
            float wk = isat ? __shfl(w, kk, 64)
                            : ((base + kk < nnz) ? 1.f : 0.f);
            const uint4* pp = (const uint4*)((const char*)emb + jk * 256 + dim * 16);
            uint4 vv = *pp;
            u32 u[4] = {vv.x, vv.y, vv.z, vv.w};
            #pragma unroll
            for (int cc = 0; cc < 4; cc++) {
                acc[2 * cc + 0] = fmaf(wk, bf2f((u16)(u[cc] & 0xffffu)), acc[2 * cc + 0]);
                acc[2 * cc + 1] = fmaf(wk, bf2f((u16)(u[cc] >> 16)), acc[2 * cc + 1]);
            }
        }
    }

    #pragma unroll
    for (int t = 0; t < 8; t++) {
        acc[t] += __shfl_xor(acc[t], 32, 64);
        acc[t] += __shfl_xor(acc[t], 16, 64);
    }
    if (isat) {
        #pragma unroll
        for (int o = 32; o > 0; o >>= 1) wsuml += __shfl_xor(wsuml, o, 64);
    }

    if (grp == 0) {
        float v[8];
        if (isat) {
            float sc = 1.f / (2048.f + wsuml);
            const float* cs = a.csum[task] + dim * 8;
            #pragma unroll
            for (int t = 0; t < 8; t++) v[t] = (cs[t] + acc[t]) * sc;
        } else {
            float sc = 1.f / ((float)nnz + 1e-8f);
            #pragma unroll
            for (int t = 0; t < 8; t++) v[t] = acc[t] * sc;
        }
        uint4 pk;
        pk.x = (u32)f2bf(v[0]) | ((u32)f2bf(v[1]) << 16);
        pk.y = (u32)f2bf(v[2]) | ((u32)f2bf(v[3]) << 16);
        pk.z = (u32)f2bf(v[4]) | ((u32)f2bf(v[5]) << 16);
        pk.w = (u32)f2bf(v[6]) | ((u32)f2bf(v[7]) << 16);
        *(uint4*)(a.out[task] + (size_t)r * 256 + a.ooff[task] + dim * 8) = pk;
    }
}

// ---------------- MFMA GEMM: canonical LDS-tiled (combine stage) -----------
struct GD4 {
    const void* A[4]; const u16* BT[4]; u16* C[4];
    const u16* bias[4]; const float* rs[4];
    int lda[4], ldb[4], ldc[4], coff[4], kiters[4], act[4], araw[4], rsmode[4];
};

#define PADK 136

__global__ __launch_bounds__(256, 2) void gemmL(GD4 g, const u32* __restrict__ flag) {
    __shared__ __align__(16) u16 As[16][PADK];
    __shared__ __align__(16) u16 Bs[128][PADK];
    int z = blockIdx.y;
    const void* A = g.A[z];
    const u16* BT = g.BT[z];
    int lda = g.lda[z], ldb = g.ldb[z];
    int kiters = g.kiters[z];
    int tid = threadIdx.x;
    int lane = tid & 63, wv = tid >> 6;
    int mrow = lane & 15, quad = lane >> 4;
    int m0 = blockIdx.x * 16;
    int c0 = wv * 32;
    int sr = tid >> 4, sk = (tid & 15) * 8;
    f32x4 acc0 = {0.f, 0.f, 0.f, 0.f}, acc1 = {0.f, 0.f, 0.f, 0.f};

    short8 ra, rb[8];
    auto ldstage = [&](int kb) {
        ra = *(const short8*)((const u16*)A + (size_t)(m0 + sr) * lda + kb + sk);
        const u16* bbase = BT + (size_t)sr * ldb + kb + sk;
        #pragma unroll
        for (int i = 0; i < 8; i++)
            rb[i] = *(const short8*)(bbase + (size_t)i * 16 * ldb);
    };
    auto ststage = [&]() {
        *(short8*)(&As[sr][sk]) = ra;
        #pragma unroll
        for (int i = 0; i < 8; i++)
            *(short8*)(&Bs[i * 16 + sr][sk]) = rb[i];
    };
    auto compute = [&]() {
        #pragma unroll
        for (int ks = 0; ks < 4; ks++) {
            short8 af = *(const short8*)(&As[mrow][ks * 32 + quad * 8]);
            short8 b0 = *(const short8*)(&Bs[c0 + mrow][ks * 32 + quad * 8]);
            short8 b1 = *(const short8*)(&Bs[c0 + 16 + mrow][ks * 32 + quad * 8]);
            acc0 = __builtin_amdgcn_mfma_f32_16x16x32_bf16(af, b0, acc0, 0, 0, 0);
            acc1 = __builtin_amdgcn_mfma_f32_16x16x32_bf16(af, b1, acc1, 0, 0, 0);
        }
    };

    ldstage(0);
    #pragma unroll 1
    for (int it = 0; it < kiters - 1; ++it) {
        ststage();
        __syncthreads();
        ldstage((it + 1) * 128);
        compute();
        __syncthreads();
    }
    ststage();
    __syncthreads();
    compute();

    const float* rs = g.rs[z];
    int rsmode = g.rsmode[z];
    const u16* bi = g.bias[z];
    u16* C = g.C[z];
    int ldc = g.ldc[z], coff = g.coff[z], act = g.act[z];
    int n0 = c0 + mrow, n1 = n0 + 16;
    float bv0 = bi ? bf2f(bi[n0]) : 0.f;
    float bv1 = bi ? bf2f(bi[n1]) : 0.f;
    #pragma unroll
    for (int r = 0; r < 4; r++) {
        int row = m0 + quad * 4 + r;
        float v0 = acc0[r], v1 = acc1[r];
        if (rsmode == 1) { float sc = rs[row]; v0 *= sc; v1 *= sc; }
        else if (rsmode == 2) {
            float t = 0.f;
            #pragma unroll
            for (int p = 0; p < 8; p++) t += rs[row + p * 2048];
            float sc = 1.f / t;
            v0 *= sc; v1 *= sc;
        }
        v0 += bv0; v1 += bv1;
        if (act) { v0 = seluf(v0); v1 = seluf(v1); }
        C[(size_t)row * ldc + coff + n0] = f2bf(v0);
        C[(size_t)row * ldc + coff + n1] = f2bf(v1);
    }
}

// ---------------- fused pair MLP: gather + GEMM1 + GEMM2 + z/sig/loss ------
#define PADX 136
__global__ __launch_bounds__(256, 2) void mlpfused(
    const u16* __restrict__ he, const u16* __restrict__ hp,
    const int* __restrict__ di, const int* __restrict__ dr,
    const u16* __restrict__ W1T, const u16* __restrict__ b1,
    const u16* __restrict__ W2T, const u16* __restrict__ b2,
    const u16* __restrict__ wpred, const u16* __restrict__ bpred,
    const int* __restrict__ labels,
    float* __restrict__ out, float* __restrict__ part) {
    __shared__ __align__(16) u16 Xs[64][PADX];
    __shared__ __align__(16) u16 Ws[128][PADX];
    __shared__ float wred[4];
    int tid = threadIdx.x;
    int lane = tid & 63, wv = tid >> 6;
    int mrow = lane & 15, quad = lane >> 4;
    int p0 = blockIdx.x * 64;

    {
        int row = tid >> 2, sub = tid & 3;
        int b = p0 + row;
        int ia = di[b], ic = dr[b];
        const uint4* pe = (const uint4*)(he + (size_t)ia * 128 + sub * 32);
        const uint4* pp = (const uint4*)(hp + (size_t)ic * 128 + sub * 32);
        #pragma unroll
        for (int q = 0; q < 4; q++) {
            uint4 ue = pe[q], up = pp[q];
            u32 eu[4] = {ue.x, ue.y, ue.z, ue.w};
            u32 pu[4] = {up.x, up.y, up.z, up.w};
            #pragma unroll
            for (int c = 0; c < 4; c++) {
                float lo = bf2f((u16)(eu[c] & 0xffffu)) * bf2f((u16)(pu[c] & 0xffffu));
                float hi = bf2f((u16)(eu[c] >> 16)) * bf2f((u16)(pu[c] >> 16));
                *(u32*)(&Xs[row][sub * 32 + q * 8 + c * 2]) =
                    (u32)f2bf(lo) | ((u32)f2bf(hi) << 16);
            }
        }
    }
    {
        int n = tid >> 1, half = tid & 1;
        const short8* src = (const short8*)(W1T + (size_t)n * 128 + half * 64);
        short8* dst = (short8*)(&Ws[n][half * 64]);
        #pragma unroll
        for (int i = 0; i < 8; i++) dst[i] = src[i];
    }
    __syncthreads();

    f32x4 acc[8];
    #pragma unroll
    for (int nt = 0; nt < 8; nt++) acc[nt] = {0.f, 0.f, 0.f, 0.f};
    #pragma unroll
    for (int ks = 0; ks < 4; ks++) {
        short8 af = *(const short8*)(&Xs[wv * 16 + mrow][ks * 32 + quad * 8]);
        #pragma unroll
        for (int nt = 0; nt < 8; nt++) {
            short8 bfv = *(const short8*)(&Ws[nt * 16 + mrow][ks * 32 + quad * 8]);
            acc[nt] = __builtin_amdgcn_mfma_f32_16x16x32_bf16(af, bfv, acc[nt], 0, 0, 0);
        }
    }
    __syncthreads();
    #pragma unroll
    for (int nt = 0; nt < 8; nt++) {
        int col = nt * 16 + mrow;
        float bv = bf2f(b1[col]);
        #pragma unroll
        for (int r = 0; r < 4; r++) {
            int row = wv * 16 + quad * 4 + r;
            Xs[row][col] = f2bf(seluf(acc[nt][r] + bv));
        }
    }
    {
        int n = tid >> 1, half = tid & 1;
        const short8* src = (const short8*)(W2T + (size_t)n * 128 + half * 64);
        short8* dst = (short8*)(&Ws[n][half * 64]);
        #pragma unroll
        for (int i = 0; i < 8; i++) dst[i] = src[i];
    }
    __syncthreads();

    #pragma unroll
    for (int nt = 0; nt < 8; nt++) acc[nt] = {0.f, 0.f, 0.f, 0.f};
    #pragma unroll
    for (int ks = 0; ks < 4; ks++) {
        short8 af = *(const short8*)(&Xs[wv * 16 + mrow][ks * 32 + quad * 8]);
        #pragma unroll
        for (int nt = 0; nt < 8; nt++) {
            short8 bfv = *(const short8*)(&Ws[nt * 16 + mrow][ks * 32 + quad * 8]);
            acc[nt] = __builtin_amdgcn_mfma_f32_16x16x32_bf16(af, bfv, acc[nt], 0, 0, 0);
        }
    }

    float zp[4] = {0.f, 0.f, 0.f, 0.f};
    #pragma unroll
    for (int nt = 0; nt < 8; nt++) {
        int col = nt * 16 + mrow;
        float bv = bf2f(b2[col]);
        float wp = bf2f(wpred[col]);
        #pragma unroll
        for (int r = 0; r < 4; r++) {
            float x2 = bf2f(f2bf(seluf(acc[nt][r] + bv)));
            zp[r] = fmaf(x2, wp, zp[r]);
        }
    }
    #pragma unroll
    for (int r = 0; r < 4; r++) {
        #pragma unroll
        for (int o = 1; o < 16; o <<= 1) zp[r] += __shfl_xor(zp[r], o, 64);
    }
    float bpv = bf2f(bpred[0]);
    float lsum = 0.f;
    #pragma unroll
    for (int r = 0; r < 4; r++) {
        int b = p0 + wv * 16 + quad * 4 + r;
        float z = zp[r] + bpv;
        float sig = 1.f / (1.f + __expf(-z));
        if (mrow == 0) out[1 + b] = sig;
        float y = (float)labels[b];
        lsum += fmaxf(z, 0.f) - z * y + log1pf(__expf(-fabsf(z)));
    }
    lsum += __shfl_xor(lsum, 16, 64);
    lsum += __shfl_xor(lsum, 32, 64);
    if (lane == 0) wred[wv] = lsum;
    __syncthreads();
    if (tid == 0) part[blockIdx.x] = wred[0] + wred[1] + wred[2] + wred[3];
}

__global__ void finloss(const float* __restrict__ part, float* __restrict__ out) {
    __shared__ float s[256];
    int t = threadIdx.x;
    s[t] = part[t];
    __syncthreads();
    for (int o = 128; o > 0; o >>= 1) {
        if (t < o) s[t] += s[t + o];
        __syncthreads();
    }
    if (t == 0) out[0] = s[0] * (1.f / 16384.f);
}

// ---------------- launch ----------------
extern "C" void kernel_launch(void* const* d_in, const int* in_sizes, int n_in,
                              void* d_out, int out_size, void* d_ws, size_t ws_size,
                              hipStream_t stream) {
    const void* e_p_adj = d_in[0];
    const void* e_e_adj = d_in[1];
    const void* p_p_adj = d_in[2];
    const int* in_dis  = (const int*)d_in[3];
    const int* in_drug = (const int*)d_in[4];
    const int* labels  = (const int*)d_in[5];
    float* out = (float*)d_out;

    // -------- workspace layout --------
    char* ws = (char*)d_ws;
    size_t off = 0;
    auto take = [&](size_t bytes) { char* p = ws + off; off = (off + bytes + 255) & ~(size_t)255; return p; };
    u16*   A_e   = (u16*)take((size_t)2048 * 256 * 2);
    u16*   A_p   = (u16*)take((size_t)2048 * 256 * 2);
    u16*   WcTe  = (u16*)take((size_t)128 * 256 * 2);
    u16*   WcTp  = (u16*)take((size_t)128 * 256 * 2);
    u16*   W1T   = (u16*)take((size_t)128 * 128 * 2);
    u16*   W2T   = (u16*)take((size_t)128 * 128 * 2);
    u16*   b_e   = (u16*)take(256);
    u16*   b_p   = (u16*)take(256);
    u16*   h_e   = (u16*)take((size_t)2048 * 128 * 2);
    u16*   h_p   = (u16*)take((size_t)2048 * 128 * 2);
    float* ko_d  = (float*)take((size_t)2048 * 32 * 4);
    float* qs_d  = (float*)take((size_t)2048 * 32 * 4);
    float* ko_p  = (float*)take((size_t)2048 * 32 * 4);
    float* qs_p  = (float*)take((size_t)2048 * 32 * 4);
    float* cspart = (float*)take((size_t)2 * 32 * 128 * 4);
    float* csd   = (float*)take(128 * 4);
    float* csp   = (float*)take(128 * 4);
    float* part  = (float*)take(256 * 4);
    u32*   flag  = (u32*)take(256);
    u16*   canon = (u16*)take((size_t)700000 * 2);
    u16*   idx0  = (u16*)take((size_t)2048 * 2048 * 2);  // e_p rows (disease)
    u16*   idx1  = (u16*)take((size_t)2048 * 2048 * 2);  // e_p cols (drug)
    u16*   idx2  = (u16*)take((size_t)2048 * 2048 * 2);  // e_e rows
    u16*   idx3  = (u16*)take((size_t)2048 * 2048 * 2);  // p_p rows
    u32*   cnt0  = (u32*)take(2048 * 4);
    u32*   cnt2  = (u32*)take(2048 * 4);
    u32*   cnt3  = (u32*)take(2048 * 4);
    u32*   cntT  = (u32*)take(2048 * 4);                 // e_p col counts

    // -------- canonical parameter table --------
    const int segidx[NSEG] = {6, 7, 14, 18, 8, 22, 11, 24, 26, 28,
                              15, 16, 17, 19, 20, 21,
                              9, 10, 12, 13, 23, 25, 27, 29, 30, 31};
    const int segn[NSEG]   = {262144, 262144, 8192, 8192, 16384, 16384, 16384, 16384, 16384, 16384,
                              32, 32, 1, 32, 32, 1,
                              128, 128, 128, 128, 128, 128, 128, 128, 128, 1};
    CvtArgs ca;
    u16* cp[NSEG];
    {
        int o = 0;
        for (int i = 0; i < NSEG; i++) {
            ca.src[i] = d_in[segidx[i]];
            ca.off[i] = o;
            ca.n[i] = segn[i];
            cp[i] = canon + o;
            o += (segn[i] + 15) & ~15;
        }
    }
    u16 *cdemb = cp[0], *cpemb = cp[1], *cWa1d = cp[2], *cWa1p = cp[3];
    u16 *cWdg = cp[4], *cWd2 = cp[5], *cWpg = cp[6], *cWp3 = cp[7];
    u16 *cW1 = cp[8], *cW2 = cp[9];
    u16 *cba1d = cp[10], *cWa2d = cp[11], *cba2d = cp[12];
    u16 *cba1p = cp[13], *cWa2p = cp[14], *cba2p = cp[15];
    u16 *cbdg_lin = cp[16], *cbdg = cp[17], *cbpg_lin = cp[18], *cbpg = cp[19];
    u16 *cbd2 = cp[20], *cbp3 = cp[21], *cmb1 = cp[22], *cmb2 = cp[23];
    u16 *cWpred = cp[24], *cbpred = cp[25];

    // -------- 0. dtype detection + counter zeroing --------
    detectk<<<1, 256, 0, stream>>>(d_in[6], flag, cntT);

    // -------- 1. merged conversion + CSR row lists --------
    {
        CS cs;
        cs.adj[0] = e_p_adj; cs.ridx[0] = idx0; cs.rcnt[0] = cnt0;
        cs.adj[1] = e_e_adj; cs.ridx[1] = idx2; cs.rcnt[1] = cnt2;
        cs.adj[2] = p_p_adj; cs.ridx[2] = idx3; cs.rcnt[2] = cnt3;
        cvtcsr<<<6144 + 64 * NSEG, 256, 0, stream>>>(ca, canon, cs, flag);
    }

    // -------- 2. merged prep (koqs + colbuild + tpose + colsump) + biasfin --
    PR pr;
    pr.demb = cdemb; pr.pemb = cpemb;
    pr.Wa1d = cWa1d; pr.ba1d = cba1d; pr.Wa1p = cWa1p; pr.ba1p = cba1p;
    pr.ko_d = ko_d; pr.qs_d = qs_d; pr.ko_p = ko_p; pr.qs_p = qs_p;
    pr.idx0 = idx0; pr.cnt0 = cnt0; pr.cidx = idx1; pr.ccnt = cntT;
    pr.ts[0] = cW1; pr.ts[1] = cW2; pr.ts[2] = cWdg;
    pr.ts[3] = cWd2; pr.ts[4] = cWpg; pr.ts[5] = cWp3;
    pr.W1T = W1T; pr.W2T = W2T; pr.WcTe = WcTe; pr.WcTp = WcTp;
    pr.cspart = cspart;
    pr.ba[0] = cbdg_lin; pr.ba[1] = cbdg; pr.ba[2] = cbd2;
    pr.bb[0] = cbpg_lin; pr.bb[1] = cbpg; pr.bb[2] = cbp3;
    pr.b_e = b_e; pr.b_p = b_p; pr.csd = csd; pr.csp = csp;
    prep2<<<6304, 256, 0, stream>>>(pr);
    biasfin<<<1, 128, 0, stream>>>(pr);

    // -------- 3. sparse attention + avg aggregation --------
    {
        SP sp;
        sp.idx[0] = idx0; sp.cnt[0] = cnt0; sp.ko[0] = ko_d; sp.qs[0] = qs_d;
        sp.w2[0] = cWa2d; sp.b2[0] = cba2d; sp.emb[0] = cpemb; sp.csum[0] = csp;
        sp.out[0] = A_e; sp.ooff[0] = 0; sp.attn[0] = 1;
        sp.idx[1] = idx2; sp.cnt[1] = cnt2; sp.ko[1] = ko_d; sp.qs[1] = qs_d;
        sp.w2[1] = cWa2d; sp.b2[1] = cba2d; sp.emb[1] = cdemb; sp.csum[1] = csd;
        sp.out[1] = A_e; sp.ooff[1] = 128; sp.attn[1] = 0;
        sp.idx[2] = idx1; sp.cnt[2] = cntT; sp.ko[2] = ko_p; sp.qs[2] = qs_p;
        sp.w2[2] = cWa2p; sp.b2[2] = cba2p; sp.emb[2] = cdemb; sp.csum[2] = csd;
        sp.out[2] = A_p; sp.ooff[2] = 0; sp.attn[2] = 1;
        sp.idx[3] = idx3; sp.cnt[3] = cnt3; sp.ko[3] = ko_p; sp.qs[3] = qs_p;
        sp.w2[3] = cWa2p; sp.b2[3] = cba2p; sp.emb[3] = cpemb; sp.csum[3] = csp;
        sp.out[3] = A_p; sp.ooff[3] = 128; sp.attn[3] = 0;
        spagg<<<dim3(512, 4), 256, 0, stream>>>(sp);
    }

    auto setd = [](GD4& g, int z, const void* A, int lda, const u16* BT, int ldb,
                   u16* C, int ldc, int coff, int ki, const u16* bi,
                   const float* rs, int act, int araw, int rm) {
        g.A[z] = A; g.lda[z] = lda; g.BT[z] = BT; g.ldb[z] = ldb;
        g.C[z] = C; g.ldc[z] = ldc; g.coff[z] = coff; g.kiters[z] = ki;
        g.bias[z] = bi; g.rs[z] = rs; g.act[z] = act; g.araw[z] = araw; g.rsmode[z] = rm;
    };

    // -------- 4. combine GEMMs (bias + SELU), batched ----------------------
    {
        GD4 g;
        setd(g, 0, A_e, 256, WcTe, 256, h_e, 128, 0, 2, b_e, nullptr, 1, 0, 0);
        setd(g, 1, A_p, 256, WcTp, 256, h_p, 128, 0, 2, b_p, nullptr, 1, 0, 0);
        setd(g, 2, A_e, 256, WcTe, 256, h_e, 128, 0, 2, b_e, nullptr, 1, 0, 0);
        setd(g, 3, A_e, 256, WcTe, 256, h_e, 128, 0, 2, b_e, nullptr, 1, 0, 0);
        gemmL<<<dim3(128, 2), 256, 0, stream>>>(g, flag);
    }

    // -------- 5. fused pair MLP + loss --------
    mlpfused<<<256, 256, 0, stream>>>(h_e, h_p, in_dis, in_drug,
                                      W1T, cmb1, W2T, cmb2,
                                      cWpred, cbpred, labels, out, part);
    finloss<<<1, 256, 0, stream>>>(part, out);
}

// Round 6
// 234.933 us; speedup vs baseline: 1.2168x; 1.0067x over previous
//
#include <hip/hip_runtime.h>

#define ND   2048
#define BB   16384

typedef unsigned short u16;
typedef unsigned int u32;
typedef __attribute__((ext_vector_type(8))) short short8;
typedef __attribute__((ext_vector_type(4))) float f32x4;

__device__ inline float bf2f(u16 u) {
    union { u32 i; float f; } v; v.i = ((u32)u) << 16; return v.f;
}
__device__ inline u16 f2bf(float f) {
    union { float f; u32 i; } v; v.f = f;
    u32 i = v.i + 0x7fffu + ((v.i >> 16) & 1u);
    return (u16)(i >> 16);
}
__device__ inline float seluf(float x) {
    const float sc = 1.0507009873554805f, al = 1.6732632423543772f;
    return x > 0.f ? sc * x : sc * al * expm1f(x);
}

// ---------------- dtype sniffer + per-iteration zeroing ----------------
__global__ void detectk(const void* __restrict__ demb, u32* __restrict__ flag,
                        u32* __restrict__ cntT, float* __restrict__ lossacc,
                        u32* __restrict__ losscnt) {
    const u16* p = (const u16*)demb;
    int tid = threadIdx.x;  // 256
    #pragma unroll
    for (int i = 0; i < 8; i++) cntT[i * 256 + tid] = 0u;
    if (tid == 0) { lossacc[0] = 0.f; losscnt[0] = 0u; }
    int sane = 0;
    #pragma unroll
    for (int i = 0; i < 2; i++) {
        u16 u = p[4 * tid + 2 * i];
        int e = (u >> 7) & 0xFF;
        if (u == 0 || (e >= 0x66 && e <= 0x8C)) sane++;
    }
    __shared__ int red[256];
    red[tid] = sane; __syncthreads();
    for (int o = 128; o > 0; o >>= 1) {
        if (tid < o) red[tid] += red[tid + o];
        __syncthreads();
    }
    if (tid == 0) flag[0] = (red[0] < 300) ? 1u : 0u;
}

// ---------------- merged: canonical conversion + CSR row lists -------------
// blocks [0,1536): csr role, 4 rows/block (m = bx>>9, r0 = (bx&511)*4)
// blocks [1536,3200): cvt role (seg = idx>>6, 64 blocks/segment)
#define NSEG 26
struct CvtArgs { const void* src[NSEG]; int off[NSEG]; int n[NSEG]; };
struct CS {
    const void* adj[3];
    u16* ridx[3]; u32* rcnt[3];
};

__global__ __launch_bounds__(256) void cvtcsr(CvtArgs a, u16* __restrict__ base,
                                              CS c, const u32* __restrict__ flag) {
    int bx = blockIdx.x;
    int t = threadIdx.x;
    bool f32 = flag[0] != 0;
    if (bx < 1536) {
        int m = bx >> 9;
        int r0 = (bx & 511) * 4;
        int lane = t & 63;
        __shared__ u32 lcnt[4];
        if (t < 4) lcnt[t] = 0;
        __syncthreads();
        float v[4][8];
        int c0 = t * 8;
        if (f32) {
            #pragma unroll
            for (int rr = 0; rr < 4; rr++) {
                const float4* p = (const float4*)((const float*)c.adj[m] +
                                                  (size_t)(r0 + rr) * 2048 + c0);
                float4 x = p[0], y = p[1];
                v[rr][0] = x.x; v[rr][1] = x.y; v[rr][2] = x.z; v[rr][3] = x.w;
                v[rr][4] = y.x; v[rr][5] = y.y; v[rr][6] = y.z; v[rr][7] = y.w;
            }
        } else {
            #pragma unroll
            for (int rr = 0; rr < 4; rr++) {
                const uint4* p = (const uint4*)((const u16*)c.adj[m] +
                                                (size_t)(r0 + rr) * 2048 + c0);
                uint4 x = p[0];
                u32 u[4] = {x.x, x.y, x.z, x.w};
                #pragma unroll
                for (int i = 0; i < 4; i++) {
                    v[rr][2 * i + 0] = (u[i] & 0xffffu) ? 1.f : 0.f;
                    v[rr][2 * i + 1] = (u[i] >> 16)     ? 1.f : 0.f;
                }
            }
        }
        #pragma unroll
        for (int rr = 0; rr < 4; rr++) {
            int cnt = 0;
            #pragma unroll
            for (int i = 0; i < 8; i++) cnt += (v[rr][i] != 0.f) ? 1 : 0;
            int pfx = cnt;
            #pragma unroll
            for (int o = 1; o < 64; o <<= 1) {
                int s = __shfl_up(pfx, o, 64);
                if (lane >= o) pfx += s;
            }
            int wtot = __shfl(pfx, 63, 64);
            u32 wb = 0;
            if (lane == 0) wb = atomicAdd(&lcnt[rr], (u32)wtot);
            wb = __shfl((int)wb, 0, 64);
            int o = (int)wb + pfx - cnt;
            u16* ridx = c.ridx[m] + (size_t)(r0 + rr) * 2048;
            #pragma unroll
            for (int i = 0; i < 8; i++) {
                if (v[rr][i] != 0.f) ridx[o++] = (u16)(c0 + i);
            }
        }
        __syncthreads();
        if (t < 4) c.rcnt[m][r0 + t] = lcnt[t];
    } else {
        int idx = bx - 1536;
        int seg = idx >> 6, xb = idx & 63;
        int n = a.n[seg];
        const void* s = a.src[seg];
        u16* d = base + a.off[seg];
        for (int i = xb * 256 + t; i < n; i += 16384)
            d[i] = f32 ? f2bf(((const float*)s)[i]) : ((const u16*)s)[i];
    }
}

// ---------------- merged prep ------------------------------------------
// [0,4096):     koqs (2 row-units per block)
// [4096,6144):  colbuild (e_p column lists, entry-parallel atomics)
// [6144,6240):  tpose_smalls (96 tiles)
// [6240,7264):  avg aggregation (task = (id>>9): 0=e_e->A_e+128, 1=p_p->A_p+128)
// [7264,7268):  colsum + bias combine (id: m = id>>1, half = id&1) — each block
//               fully owns a 64-dim half-column sum -> no cross-block dep.
struct PR {
    const u16* demb; const u16* pemb;
    const u16* Wa1d; const u16* ba1d;
    const u16* Wa1p; const u16* ba1p;
    float* ko_d; float* qs_d; float* ko_p; float* qs_p;
    const u16* idx0; const u32* cnt0; u16* cidx; u32* ccnt;
    const u16* ts[6]; u16* W1T; u16* W2T; u16* WcTe; u16* WcTp;
    const u16* ba[3]; const u16* bb[3]; u16* b_e; u16* b_p;
    float* csd; float* csp;
    const u16* avgidx[2]; const u32* avgcnt[2]; const u16* avgemb[2]; u16* avgout[2];
};

__global__ __launch_bounds__(256) void prep2(PR p) {
    int bx = blockIdx.x;
    int tid = threadIdx.x;
    __shared__ float sx[2][128];
    __shared__ float sred[2][128];
    __shared__ u16 stile[32][33];
    __shared__ float st0[256], st1[256];

    if (bx < 4096) {
        // ---- koqs
        int sub = tid >> 7, t = tid & 127;
        int unit = bx * 2 + sub;
        int row = unit & 2047, m = unit >> 11;
        const u16* src; const u16* W; const u16* bias; float* out;
        switch (m) {
            case 0:  src = p.pemb; W = p.Wa1d;            bias = nullptr; out = p.ko_d; break;
            case 1:  src = p.demb; W = p.Wa1d + 128 * 32; bias = p.ba1d;  out = p.qs_d; break;
            case 2:  src = p.demb; W = p.Wa1p;            bias = nullptr; out = p.ko_p; break;
            default: src = p.pemb; W = p.Wa1p + 128 * 32; bias = p.ba1p;  out = p.qs_p; break;
        }
        sx[sub][t] = bf2f(src[(size_t)row * 128 + t]);
        __syncthreads();
        int a = t & 31, part = t >> 5;
        float s = 0.f;
        #pragma unroll
        for (int k = 0; k < 32; k++)
            s += sx[sub][part * 32 + k] * bf2f(W[(part * 32 + k) * 32 + a]);
        sred[sub][t] = s;
        __syncthreads();
        if (part == 0) {
            float tt = sred[sub][a] + sred[sub][a + 32] + sred[sub][a + 64] + sred[sub][a + 96];
            if (bias) tt += bf2f(bias[a]);
            out[(size_t)row * 32 + a] = tt;
        }
    } else if (bx < 6144) {
        // ---- colbuild
        int r = bx - 4096;
        int n = (int)p.cnt0[r];
        const u16* row = p.idx0 + (size_t)r * 2048;
        for (int i = tid; i < n; i += 256) {
            int cc = (int)row[i];
            u32 q = atomicAdd(&p.ccnt[cc], 1u);
            p.cidx[(size_t)cc * 2048 + q] = (u16)r;
        }
    } else if (bx < 6240) {
        // ---- tpose_smalls
        int id = bx - 6144;
        int z = id >> 4, rem = id & 15;
        int c0 = (rem & 3) * 32, r0 = (rem >> 2) * 32;
        const u16* in = p.ts[z];
        u16* out; int ldo, ooff;
        switch (z) {
            case 0:  out = p.W1T;  ldo = 128; ooff = 0;   break;
            case 1:  out = p.W2T;  ldo = 128; ooff = 0;   break;
            case 2:  out = p.WcTe; ldo = 256; ooff = 0;   break;
            case 3:  out = p.WcTe; ldo = 256; ooff = 128; break;
            case 4:  out = p.WcTp; ldo = 256; ooff = 0;   break;
            default: out = p.WcTp; ldo = 256; ooff = 128; break;
        }
        int tx = tid & 31, ty = tid >> 5;
        int x = c0 + tx;
        for (int i = ty; i < 32; i += 8)
            stile[i][tx] = in[(size_t)(r0 + i) * 128 + x];
        __syncthreads();
        int rr = r0 + tx;
        for (int i = ty; i < 32; i += 8)
            out[(size_t)(c0 + i) * ldo + ooff + rr] = stile[tx][i];
    } else if (bx < 7264) {
        // ---- avg aggregation (knn branch): 4 rows per block
        int id = bx - 6240;
        int task = id >> 9, blk = id & 511;
        int wv = tid >> 6, lane = tid & 63;
        int grp = lane >> 4, dim = lane & 15;
        int r = blk * 4 + wv;
        const u16* idx = p.avgidx[task] + (size_t)r * 2048;
        int nnz = (int)p.avgcnt[task][r];
        const u16* emb = p.avgemb[task];
        float acc[8];
        #pragma unroll
        for (int t = 0; t < 8; t++) acc[t] = 0.f;
        for (int base = 0; base < nnz; base += 64) {
            int i = base + lane;
            int j = (i < nnz) ? (int)idx[i] : 0;
            int cend = min(64, nnz - base);
            #pragma unroll 4
            for (int k4 = 0; k4 < cend; k4 += 4) {
                int kk = k4 + grp;
                int jk = __shfl(j, kk, 64);
                float wk = (base + kk < nnz) ? 1.f : 0.f;
                const uint4* pp = (const uint4*)((const char*)emb + jk * 256 + dim * 16);
                uint4 vv = *pp;
                u32 u[4] = {vv.x, vv.y, vv.z, vv.w};
                #pragma unroll
                for (int cc = 0; cc < 4; cc++) {
                    acc[2 * cc + 0] = fmaf(wk, bf2f((u16)(u[cc] & 0xffffu)), acc[2 * cc + 0]);
                    acc[2 * cc + 1] = fmaf(wk, bf2f((u16)(u[cc] >> 16)), acc[2 * cc + 1]);
                }
            }
        }
        #pragma unroll
        for (int t = 0; t < 8; t++) {
            acc[t] += __shfl_xor(acc[t], 32, 64);
            acc[t] += __shfl_xor(acc[t], 16, 64);
        }
        if (grp == 0) {
            float sc = 1.f / ((float)nnz + 1e-8f);
            float v[8];
            #pragma unroll
            for (int t = 0; t < 8; t++) v[t] = acc[t] * sc;
            uint4 pk;
            pk.x = (u32)f2bf(v[0]) | ((u32)f2bf(v[1]) << 16);
            pk.y = (u32)f2bf(v[2]) | ((u32)f2bf(v[3]) << 16);
            pk.z = (u32)f2bf(v[4]) | ((u32)f2bf(v[5]) << 16);
            pk.w = (u32)f2bf(v[6]) | ((u32)f2bf(v[7]) << 16);
            *(uint4*)(p.avgout[task] + (size_t)r * 256 + dim * 8) = pk;
        }
    } else {
        // ---- colsum (f32) + bias combine; block owns 64 dims of one matrix
        int id = bx - 7264;      // 0..3
        int m = id >> 1, half = id & 1;
        const u16* e = m ? p.pemb : p.demb;
        int c2 = tid & 31, rg = tid >> 5;     // 32 dim-pairs x 8 row-groups
        int dbase = half * 64;
        float s0 = 0.f, s1 = 0.f;
        for (int it = 0; it < 256; it++) {
            int row = it * 8 + rg;
            u32 v = *(const u32*)(e + (size_t)row * 128 + dbase + c2 * 2);
            s0 += bf2f((u16)(v & 0xffffu));
            s1 += bf2f((u16)(v >> 16));
        }
        st0[tid] = s0; st1[tid] = s1;
        __syncthreads();
        if (tid < 32) {
            float a0 = 0.f, a1 = 0.f;
            #pragma unroll
            for (int g = 0; g < 8; g++) { a0 += st0[g * 32 + tid]; a1 += st1[g * 32 + tid]; }
            float* cs = m ? p.csp : p.csd;
            cs[dbase + tid * 2 + 0] = a0;
            cs[dbase + tid * 2 + 1] = a1;
        }
        if (tid < 64) {
            int d = dbase + tid;
            if (m == 0)
                p.b_e[d] = f2bf(bf2f(p.ba[0][d]) + bf2f(p.ba[1][d]) + bf2f(p.ba[2][d]));
            else
                p.b_p[d] = f2bf(bf2f(p.bb[0][d]) + bf2f(p.bb[1][d]) + bf2f(p.bb[2][d]));
        }
    }
}

// ---------------- sparse attention aggregation (2 attn tasks only) ---------
struct SP {
    const u16* idx[2]; const u32* cnt[2];
    const float* ko[2]; const float* qs[2];
    const u16* w2[2]; const u16* b2[2];
    const u16* emb[2]; const float* csum[2];
    u16* out[2];
};

__global__ __launch_bounds__(256) void spagg(SP a) {
    int task = blockIdx.y;
    int tid = threadIdx.x;
    int wv = tid >> 6, lane = tid & 63;
    int grp = lane >> 4, dim = lane & 15;
    int r = blockIdx.x * 4 + wv;
    const u16* idx = a.idx[task] + (size_t)r * 2048;
    int nnz = (int)a.cnt[task][r];
    const u16* emb = a.emb[task];
    const float* ko = a.ko[task];

    float qsr[32], w2h[32];
    {
        const float4* qp = (const float4*)(a.qs[task] + (size_t)r * 32);
        #pragma unroll
        for (int i = 0; i < 8; i++) {
            float4 v = qp[i];
            qsr[4 * i + 0] = v.x; qsr[4 * i + 1] = v.y;
            qsr[4 * i + 2] = v.z; qsr[4 * i + 3] = v.w;
        }
        #pragma unroll
        for (int i = 0; i < 32; i++) w2h[i] = bf2f(a.w2[task][i]);
    }
    float b2v = bf2f(a.b2[task][0]);

    float acc[8];
    #pragma unroll
    for (int t = 0; t < 8; t++) acc[t] = 0.f;
    float wsuml = 0.f;

    for (int base = 0; base < nnz; base += 64) {
        int i = base + lane;
        float w = 0.f;
        int j = 0;
        if (i < nnz) {
            j = (int)idx[i];
            const float4* kp = (const float4*)(ko + (size_t)j * 32);
            float s = 0.f;
            #pragma unroll
            for (int q = 0; q < 8; q++) {
                float4 kv = kp[q];
                s += fmaxf(qsr[4 * q + 0] + kv.x, 0.f) * w2h[4 * q + 0];
                s += fmaxf(qsr[4 * q + 1] + kv.y, 0.f) * w2h[4 * q + 1];
                s += fmaxf(qsr[4 * q + 2] + kv.z, 0.f) * w2h[4 * q + 2];
                s += fmaxf(qsr[4 * q + 3] + kv.w, 0.f) * w2h[4 * q + 3];
            }
            w = __expf(fmaxf(s + b2v, 0.f)) - 1.f;
            wsuml += w;
        }
        int cend = min(64, nnz - base);
        #pragma unroll 4
        for (int k4 = 0; k4 < cend; k4 += 4) {
            int kk = k4 + grp;
            float wk = __shfl(w, kk, 64);
            int jk = __shfl(j, kk, 64);
            const uint4* pp = (const uint4*)((const char*)emb + jk * 256 + dim * 16);
            uint4 vv = *pp;
            u32 u[4] = {vv.x, vv.y, vv.z, vv.w};
            #pragma unroll
            for (int cc = 0; cc < 4; cc++) {
                acc[2 * cc + 0] = fmaf(wk, bf2f((u16)(u[cc] & 0xffffu)), acc[2 * cc + 0]);
                acc[2 * cc + 1] = fmaf(wk, bf2f((u16)(u[cc] >> 16)), acc[2 * cc + 1]);
            }
        }
    }

    #pragma unroll
    for (int t = 0; t < 8; t++) {
        acc[t] += __shfl_xor(acc[t], 32, 64);
        acc[t] += __shfl_xor(acc[t], 16, 64);
    }
    #pragma unroll
    for (int o = 32; o > 0; o >>= 1) wsuml += __shfl_xor(wsuml, o, 64);

    if (grp == 0) {
        float sc = 1.f / (2048.f + wsuml);
        const float* cs = a.csum[task] + dim * 8;
        float v[8];
        #pragma unroll
        for (int t = 0; t < 8; t++) v[t] = (cs[t] + acc[t]) * sc;
        uint4 pk;
        pk.x = (u32)f2bf(v[0]) | ((u32)f2bf(v[1]) << 16);
        pk.y = (u32)f2bf(v[2]) | ((u32)f2bf(v[3]) << 16);
        pk.z = (u32)f2bf(v[4]) | ((u32)f2bf(v[5]) << 16);
        pk.w = (u32)f2bf(v[6]) | ((u32)f2bf(v[7]) << 16);
        *(uint4*)(a.out[task] + (size_t)r * 256 + dim * 8) = pk;
    }
}

// ---------------- MFMA GEMM: canonical LDS-tiled (combine stage) -----------
struct GD4 {
    const void* A[4]; const u16* BT[4]; u16* C[4];
    const u16* bias[4]; const float* rs[4];
    int lda[4], ldb[4], ldc[4], coff[4], kiters[4], act[4], araw[4], rsmode[4];
};

#define PADK 136

__global__ __launch_bounds__(256, 2) void gemmL(GD4 g, const u32* __restrict__ flag) {
    __shared__ __align__(16) u16 As[16][PADK];
    __shared__ __align__(16) u16 Bs[128][PADK];
    int z = blockIdx.y;
    const void* A = g.A[z];
    const u16* BT = g.BT[z];
    int lda = g.lda[z], ldb = g.ldb[z];
    int kiters = g.kiters[z];
    int tid = threadIdx.x;
    int lane = tid & 63, wv = tid >> 6;
    int mrow = lane & 15, quad = lane >> 4;
    int m0 = blockIdx.x * 16;
    int c0 = wv * 32;
    int sr = tid >> 4, sk = (tid & 15) * 8;
    f32x4 acc0 = {0.f, 0.f, 0.f, 0.f}, acc1 = {0.f, 0.f, 0.f, 0.f};

    short8 ra, rb[8];
    auto ldstage = [&](int kb) {
        ra = *(const short8*)((const u16*)A + (size_t)(m0 + sr) * lda + kb + sk);
        const u16* bbase = BT + (size_t)sr * ldb + kb + sk;
        #pragma unroll
        for (int i = 0; i < 8; i++)
            rb[i] = *(const short8*)(bbase + (size_t)i * 16 * ldb);
    };
    auto ststage = [&]() {
        *(short8*)(&As[sr][sk]) = ra;
        #pragma unroll
        for (int i = 0; i < 8; i++)
            *(short8*)(&Bs[i * 16 + sr][sk]) = rb[i];
    };
    auto compute = [&]() {
        #pragma unroll
        for (int ks = 0; ks < 4; ks++) {
            short8 af = *(const short8*)(&As[mrow][ks * 32 + quad * 8]);
            short8 b0 = *(const short8*)(&Bs[c0 + mrow][ks * 32 + quad * 8]);
            short8 b1 = *(const short8*)(&Bs[c0 + 16 + mrow][ks * 32 + quad * 8]);
            acc0 = __builtin_amdgcn_mfma_f32_16x16x32_bf16(af, b0, acc0, 0, 0, 0);
            acc1 = __builtin_amdgcn_mfma_f32_16x16x32_bf16(af, b1, acc1, 0, 0, 0);
        }
    };

    ldstage(0);
    #pragma unroll 1
    for (int it = 0; it < kiters - 1; ++it) {
        ststage();
        __syncthreads();
        ldstage((it + 1) * 128);
        compute();
        __syncthreads();
    }
    ststage();
    __syncthreads();
    compute();

    const float* rs = g.rs[z];
    int rsmode = g.rsmode[z];
    const u16* bi = g.bias[z];
    u16* C = g.C[z];
    int ldc = g.ldc[z], coff = g.coff[z], act = g.act[z];
    int n0 = c0 + mrow, n1 = n0 + 16;
    float bv0 = bi ? bf2f(bi[n0]) : 0.f;
    float bv1 = bi ? bf2f(bi[n1]) : 0.f;
    #pragma unroll
    for (int r = 0; r < 4; r++) {
        int row = m0 + quad * 4 + r;
        float v0 = acc0[r], v1 = acc1[r];
        if (rsmode == 1) { float sc = rs[row]; v0 *= sc; v1 *= sc; }
        else if (rsmode == 2) {
            float t = 0.f;
            #pragma unroll
            for (int p = 0; p < 8; p++) t += rs[row + p * 2048];
            float sc = 1.f / t;
            v0 *= sc; v1 *= sc;
        }
        v0 += bv0; v1 += bv1;
        if (act) { v0 = seluf(v0); v1 = seluf(v1); }
        C[(size_t)row * ldc + coff + n0] = f2bf(v0);
        C[(size_t)row * ldc + coff + n1] = f2bf(v1);
    }
}

// ---------------- fused pair MLP + loss finalization -----------------------
#define PADX 136
__global__ __launch_bounds__(256, 2) void mlpfused(
    const u16* __restrict__ he, const u16* __restrict__ hp,
    const int* __restrict__ di, const int* __restrict__ dr,
    const u16* __restrict__ W1T, const u16* __restrict__ b1,
    const u16* __restrict__ W2T, const u16* __restrict__ b2,
    const u16* __restrict__ wpred, const u16* __restrict__ bpred,
    const int* __restrict__ labels,
    float* __restrict__ out, float* __restrict__ lossacc,
    u32* __restrict__ losscnt) {
    __shared__ __align__(16) u16 Xs[64][PADX];
    __shared__ __align__(16) u16 Ws[128][PADX];
    __shared__ float wred[4];
    int tid = threadIdx.x;
    int lane = tid & 63, wv = tid >> 6;
    int mrow = lane & 15, quad = lane >> 4;
    int p0 = blockIdx.x * 64;

    {
        int row = tid >> 2, sub = tid & 3;
        int b = p0 + row;
        int ia = di[b], ic = dr[b];
        const uint4* pe = (const uint4*)(he + (size_t)ia * 128 + sub * 32);
        const uint4* pp = (const uint4*)(hp + (size_t)ic * 128 + sub * 32);
        #pragma unroll
        for (int q = 0; q < 4; q++) {
            uint4 ue = pe[q], up = pp[q];
            u32 eu[4] = {ue.x, ue.y, ue.z, ue.w};
            u32 pu[4] = {up.x, up.y, up.z, up.w};
            #pragma unroll
            for (int c = 0; c < 4; c++) {
                float lo = bf2f((u16)(eu[c] & 0xffffu)) * bf2f((u16)(pu[c] & 0xffffu));
                float hi = bf2f((u16)(eu[c] >> 16)) * bf2f((u16)(pu[c] >> 16));
                *(u32*)(&Xs[row][sub * 32 + q * 8 + c * 2]) =
                    (u32)f2bf(lo) | ((u32)f2bf(hi) << 16);
            }
        }
    }
    {
        int n = tid >> 1, half = tid & 1;
        const short8* src = (const short8*)(W1T + (size_t)n * 128 + half * 64);
        short8* dst = (short8*)(&Ws[n][half * 64]);
        #pragma unroll
        for (int i = 0; i < 8; i++) dst[i] = src[i];
    }
    __syncthreads();

    f32x4 acc[8];
    #pragma unroll
    for (int nt = 0; nt < 8; nt++) acc[nt] = {0.f, 0.f, 0.f, 0.f};
    #pragma unroll
    for (int ks = 0; ks < 4; ks++) {
        short8 af = *(const short8*)(&Xs[wv * 16 + mrow][ks * 32 + quad * 8]);
        #pragma unroll
        for (int nt = 0; nt < 8; nt++) {
            short8 bfv = *(const short8*)(&Ws[nt * 16 + mrow][ks * 32 + quad * 8]);
            acc[nt] = __builtin_amdgcn_mfma_f32_16x16x32_bf16(af, bfv, acc[nt], 0, 0, 0);
        }
    }
    __syncthreads();
    #pragma unroll
    for (int nt = 0; nt < 8; nt++) {
        int col = nt * 16 + mrow;
        float bv = bf2f(b1[col]);
        #pragma unroll
        for (int r = 0; r < 4; r++) {
            int row = wv * 16 + quad * 4 + r;
            Xs[row][col] = f2bf(seluf(acc[nt][r] + bv));
        }
    }
    {
        int n = tid >> 1, half = tid & 1;
        const short8* src = (const short8*)(W2T + (size_t)n * 128 + half * 64);
        short8* dst = (short8*)(&Ws[n][half * 64]);
        #pragma unroll
        for (int i = 0; i < 8; i++) dst[i] = src[i];
    }
    __syncthreads();

    #pragma unroll
    for (int nt = 0; nt < 8; nt++) acc[nt] = {0.f, 0.f, 0.f, 0.f};
    #pragma unroll
    for (int ks = 0; ks < 4; ks++) {
        short8 af = *(const short8*)(&Xs[wv * 16 + mrow][ks * 32 + quad * 8]);
        #pragma unroll
        for (int nt = 0; nt < 8; nt++) {
            short8 bfv = *(const short8*)(&Ws[nt * 16 + mrow][ks * 32 + quad * 8]);
            acc[nt] = __builtin_amdgcn_mfma_f32_16x16x32_bf16(af, bfv, acc[nt], 0, 0, 0);
        }
    }

    float zp[4] = {0.f, 0.f, 0.f, 0.f};
    #pragma unroll
    for (int nt = 0; nt < 8; nt++) {
        int col = nt * 16 + mrow;
        float bv = bf2f(b2[col]);
        float wp = bf2f(wpred[col]);
        #pragma unroll
        for (int r = 0; r < 4; r++) {
            float x2 = bf2f(f2bf(seluf(acc[nt][r] + bv)));
            zp[r] = fmaf(x2, wp, zp[r]);
        }
    }
    #pragma unroll
    for (int r = 0; r < 4; r++) {
        #pragma unroll
        for (int o = 1; o < 16; o <<= 1) zp[r] += __shfl_xor(zp[r], o, 64);
    }
    float bpv = bf2f(bpred[0]);
    float lsum = 0.f;
    #pragma unroll
    for (int r = 0; r < 4; r++) {
        int b = p0 + wv * 16 + quad * 4 + r;
        float z = zp[r] + bpv;
        float sig = 1.f / (1.f + __expf(-z));
        if (mrow == 0) out[1 + b] = sig;
        float y = (float)labels[b];
        lsum += fmaxf(z, 0.f) - z * y + log1pf(__expf(-fabsf(z)));
    }
    // quad-only butterfly: 16 mrow lanes hold identical lsum (zp reduced over
    // mrow), so the result is the exact 16-row wave sum on every lane.
    lsum += __shfl_xor(lsum, 16, 64);
    lsum += __shfl_xor(lsum, 32, 64);
    if (lane == 0) wred[wv] = lsum;
    __syncthreads();
    if (tid == 0) {
        float bs = wred[0] + wred[1] + wred[2] + wred[3];
        atomicAdd(lossacc, bs);
        __threadfence();
        u32 old = atomicAdd(losscnt, 1u);
        if (old == 255u) {
            // coherent read via atomic RMW (per-XCD L2s are not coherent)
            float tot = atomicAdd(lossacc, 0.f);
            out[0] = tot * (1.f / 16384.f);
        }
    }
}

// ---------------- launch ----------------
extern "C" void kernel_launch(void* const* d_in, const int* in_sizes, int n_in,
                              void* d_out, int out_size, void* d_ws, size_t ws_size,
                              hipStream_t stream) {
    const void* e_p_adj = d_in[0];
    const void* e_e_adj = d_in[1];
    const void* p_p_adj = d_in[2];
    const int* in_dis  = (const int*)d_in[3];
    const int* in_drug = (const int*)d_in[4];
    const int* labels  = (const int*)d_in[5];
    float* out = (float*)d_out;

    // -------- workspace layout --------
    char* ws = (char*)d_ws;
    size_t off = 0;
    auto take = [&](size_t bytes) { char* p = ws + off; off = (off + bytes + 255) & ~(size_t)255; return p; };
    u16*   A_e   = (u16*)take((size_t)2048 * 256 * 2);
    u16*   A_p   = (u16*)take((size_t)2048 * 256 * 2);
    u16*   WcTe  = (u16*)take((size_t)128 * 256 * 2);
    u16*   WcTp  = (u16*)take((size_t)128 * 256 * 2);
    u16*   W1T   = (u16*)take((size_t)128 * 128 * 2);
    u16*   W2T   = (u16*)take((size_t)128 * 128 * 2);
    u16*   b_e   = (u16*)take(256);
    u16*   b_p   = (u16*)take(256);
    u16*   h_e   = (u16*)take((size_t)2048 * 128 * 2);
    u16*   h_p   = (u16*)take((size_t)2048 * 128 * 2);
    float* ko_d  = (float*)take((size_t)2048 * 32 * 4);
    float* qs_d  = (float*)take((size_t)2048 * 32 * 4);
    float* ko_p  = (float*)take((size_t)2048 * 32 * 4);
    float* qs_p  = (float*)take((size_t)2048 * 32 * 4);
    float* csd   = (float*)take(128 * 4);
    float* csp   = (float*)take(128 * 4);
    float* lossacc = (float*)take(256);
    u32*   losscnt = (u32*)((char*)lossacc + 4);
    u32*   flag  = (u32*)take(256);
    u16*   canon = (u16*)take((size_t)700000 * 2);
    u16*   idx0  = (u16*)take((size_t)2048 * 2048 * 2);  // e_p rows (disease)
    u16*   idx1  = (u16*)take((size_t)2048 * 2048 * 2);  // e_p cols (drug)
    u16*   idx2  = (u16*)take((size_t)2048 * 2048 * 2);  // e_e rows
    u16*   idx3  = (u16*)take((size_t)2048 * 2048 * 2);  // p_p rows
    u32*   cnt0  = (u32*)take(2048 * 4);
    u32*   cnt2  = (u32*)take(2048 * 4);
    u32*   cnt3  = (u32*)take(2048 * 4);
    u32*   cntT  = (u32*)take(2048 * 4);                 // e_p col counts

    // -------- canonical parameter table --------
    const int segidx[NSEG] = {6, 7, 14, 18, 8, 22, 11, 24, 26, 28,
                              15, 16, 17, 19, 20, 21,
                              9, 10, 12, 13, 23, 25, 27, 29, 30, 31};
    const int segn[NSEG]   = {262144, 262144, 8192, 8192, 16384, 16384, 16384, 16384, 16384, 16384,
                              32, 32, 1, 32, 32, 1,
                              128, 128, 128, 128, 128, 128, 128, 128, 128, 1};
    CvtArgs ca;
    u16* cp[NSEG];
    {
        int o = 0;
        for (int i = 0; i < NSEG; i++) {
            ca.src[i] = d_in[segidx[i]];
            ca.off[i] = o;
            ca.n[i] = segn[i];
            cp[i] = canon + o;
            o += (segn[i] + 15) & ~15;
        }
    }
    u16 *cdemb = cp[0], *cpemb = cp[1], *cWa1d = cp[2], *cWa1p = cp[3];
    u16 *cWdg = cp[4], *cWd2 = cp[5], *cWpg = cp[6], *cWp3 = cp[7];
    u16 *cW1 = cp[8], *cW2 = cp[9];
    u16 *cba1d = cp[10], *cWa2d = cp[11], *cba2d = cp[12];
    u16 *cba1p = cp[13], *cWa2p = cp[14], *cba2p = cp[15];
    u16 *cbdg_lin = cp[16], *cbdg = cp[17], *cbpg_lin = cp[18], *cbpg = cp[19];
    u16 *cbd2 = cp[20], *cbp3 = cp[21], *cmb1 = cp[22], *cmb2 = cp[23];
    u16 *cWpred = cp[24], *cbpred = cp[25];

    // -------- 0. dtype detection + per-iteration zeroing --------
    detectk<<<1, 256, 0, stream>>>(d_in[6], flag, cntT, lossacc, losscnt);

    // -------- 1. merged conversion + CSR row lists --------
    {
        CS cs;
        cs.adj[0] = e_p_adj; cs.ridx[0] = idx0; cs.rcnt[0] = cnt0;
        cs.adj[1] = e_e_adj; cs.ridx[1] = idx2; cs.rcnt[1] = cnt2;
        cs.adj[2] = p_p_adj; cs.ridx[2] = idx3; cs.rcnt[2] = cnt3;
        cvtcsr<<<1536 + 64 * NSEG, 256, 0, stream>>>(ca, canon, cs, flag);
    }

    // -------- 2. merged prep (koqs + colbuild + tpose + avg-agg + colsum) ---
    PR pr;
    pr.demb = cdemb; pr.pemb = cpemb;
    pr.Wa1d = cWa1d; pr.ba1d = cba1d; pr.Wa1p = cWa1p; pr.ba1p = cba1p;
    pr.ko_d = ko_d; pr.qs_d = qs_d; pr.ko_p = ko_p; pr.qs_p = qs_p;
    pr.idx0 = idx0; pr.cnt0 = cnt0; pr.cidx = idx1; pr.ccnt = cntT;
    pr.ts[0] = cW1; pr.ts[1] = cW2; pr.ts[2] = cWdg;
    pr.ts[3] = cWd2; pr.ts[4] = cWpg; pr.ts[5] = cWp3;
    pr.W1T = W1T; pr.W2T = W2T; pr.WcTe = WcTe; pr.WcTp = WcTp;
    pr.ba[0] = cbdg_lin; pr.ba[1] = cbdg; pr.ba[2] = cbd2;
    pr.bb[0] = cbpg_lin; pr.bb[1] = cbpg; pr.bb[2] = cbp3;
    pr.b_e = b_e; pr.b_p = b_p; pr.csd = csd; pr.csp = csp;
    pr.avgidx[0] = idx2; pr.avgcnt[0] = cnt2; pr.avgemb[0] = cdemb; pr.avgout[0] = A_e + 128;
    pr.avgidx[1] = idx3; pr.avgcnt[1] = cnt3; pr.avgemb[1] = cpemb; pr.avgout[1] = A_p + 128;
    prep2<<<7268, 256, 0, stream>>>(pr);

    // -------- 3. sparse attention aggregation (2 tasks) --------
    {
        SP sp;
        sp.idx[0] = idx0; sp.cnt[0] = cnt0; sp.ko[0] = ko_d; sp.qs[0] = qs_d;
        sp.w2[0] = cWa2d; sp.b2[0] = cba2d; sp.emb[0] = cpemb; sp.csum[0] = csp;
        sp.out[0] = A_e;
        sp.idx[1] = idx1; sp.cnt[1] = cntT; sp.ko[1] = ko_p; sp.qs[1] = qs_p;
        sp.w2[1] = cWa2p; sp.b2[1] = cba2p; sp.emb[1] = cdemb; sp.csum[1] = csd;
        sp.out[1] = A_p;
        spagg<<<dim3(512, 2), 256, 0, stream>>>(sp);
    }

    auto setd = [](GD4& g, int z, const void* A, int lda, const u16* BT, int ldb,
                   u16* C, int ldc, int coff, int ki, const u16* bi,
                   const float* rs, int act, int araw, int rm) {
        g.A[z] = A; g.lda[z] = lda; g.BT[z] = BT; g.ldb[z] = ldb;
        g.C[z] = C; g.ldc[z] = ldc; g.coff[z] = coff; g.kiters[z] = ki;
        g.bias[z] = bi; g.rs[z] = rs; g.act[z] = act; g.araw[z] = araw; g.rsmode[z] = rm;
    };

    // -------- 4. combine GEMMs (bias + SELU), batched ----------------------
    {
        GD4 g;
        setd(g, 0, A_e, 256, WcTe, 256, h_e, 128, 0, 2, b_e, nullptr, 1, 0, 0);
        setd(g, 1, A_p, 256, WcTp, 256, h_p, 128, 0, 2, b_p, nullptr, 1, 0, 0);
        setd(g, 2, A_e, 256, WcTe, 256, h_e, 128, 0, 2, b_e, nullptr, 1, 0, 0);
        setd(g, 3, A_e, 256, WcTe, 256, h_e, 128, 0, 2, b_e, nullptr, 1, 0, 0);
        gemmL<<<dim3(128, 2), 256, 0, stream>>>(g, flag);
    }

    // -------- 5. fused pair MLP + loss --------
    mlpfused<<<256, 256, 0, stream>>>(h_e, h_p, in_dis, in_drug,
                                      W1T, cmb1, W2T, cmb2,
                                      cWpred, cbpred, labels, out,
                                      lossacc, losscnt);
}

// Round 7
// 232.887 us; speedup vs baseline: 1.2275x; 1.0088x over previous
//
#include <hip/hip_runtime.h>

#define ND   2048
#define BB   16384

typedef unsigned short u16;
typedef unsigned int u32;
typedef __attribute__((ext_vector_type(8))) short short8;
typedef __attribute__((ext_vector_type(4))) float f32x4;

__device__ inline float bf2f(u16 u) {
    union { u32 i; float f; } v; v.i = ((u32)u) << 16; return v.f;
}
__device__ inline u16 f2bf(float f) {
    union { float f; u32 i; } v; v.f = f;
    u32 i = v.i + 0x7fffu + ((v.i >> 16) & 1u);
    return (u16)(i >> 16);
}
__device__ inline float seluf(float x) {
    const float sc = 1.0507009873554805f, al = 1.6732632423543772f;
    return x > 0.f ? sc * x : sc * al * expm1f(x);
}

// ---------------- dtype sniffer + per-iteration zeroing ----------------
__global__ void detectk(const void* __restrict__ demb, u32* __restrict__ flag,
                        u32* __restrict__ cntT, float* __restrict__ lossacc,
                        u32* __restrict__ losscnt) {
    const u16* p = (const u16*)demb;
    int tid = threadIdx.x;  // 256
    #pragma unroll
    for (int i = 0; i < 8; i++) cntT[i * 256 + tid] = 0u;
    if (tid == 0) { lossacc[0] = 0.f; losscnt[0] = 0u; }
    int sane = 0;
    #pragma unroll
    for (int i = 0; i < 2; i++) {
        u16 u = p[4 * tid + 2 * i];
        int e = (u >> 7) & 0xFF;
        if (u == 0 || (e >= 0x66 && e <= 0x8C)) sane++;
    }
    __shared__ int red[256];
    red[tid] = sane; __syncthreads();
    for (int o = 128; o > 0; o >>= 1) {
        if (tid < o) red[tid] += red[tid + o];
        __syncthreads();
    }
    if (tid == 0) flag[0] = (red[0] < 300) ? 1u : 0u;
}

// ---------------- merged: conversion + CSR row lists + e_p col scatter -----
// blocks [0,1536): csr role, 4 rows/block (m = bx>>9, r0 = (bx&511)*4)
//                  m==0 additionally scatters entries into column lists.
// blocks [1536,3200): cvt role (seg = idx>>6, 64 blocks/segment), u32-wide
#define NSEG 26
struct CvtArgs { const void* src[NSEG]; int off[NSEG]; int n[NSEG]; };
struct CS {
    const void* adj[3];
    u16* ridx[3]; u32* rcnt[3];
    u16* cidx; u32* ccnt;        // e_p column lists (ccnt zeroed in detectk)
};

__global__ __launch_bounds__(256) void cvtcsr(CvtArgs a, u16* __restrict__ base,
                                              CS c, const u32* __restrict__ flag) {
    int bx = blockIdx.x;
    int t = threadIdx.x;
    bool f32 = flag[0] != 0;
    if (bx < 1536) {
        int m = bx >> 9;
        int r0 = (bx & 511) * 4;
        int lane = t & 63;
        __shared__ u32 lcnt[4];
        if (t < 4) lcnt[t] = 0;
        __syncthreads();
        float v[4][8];
        int c0 = t * 8;
        if (f32) {
            #pragma unroll
            for (int rr = 0; rr < 4; rr++) {
                const float4* p = (const float4*)((const float*)c.adj[m] +
                                                  (size_t)(r0 + rr) * 2048 + c0);
                float4 x = p[0], y = p[1];
                v[rr][0] = x.x; v[rr][1] = x.y; v[rr][2] = x.z; v[rr][3] = x.w;
                v[rr][4] = y.x; v[rr][5] = y.y; v[rr][6] = y.z; v[rr][7] = y.w;
            }
        } else {
            #pragma unroll
            for (int rr = 0; rr < 4; rr++) {
                const uint4* p = (const uint4*)((const u16*)c.adj[m] +
                                                (size_t)(r0 + rr) * 2048 + c0);
                uint4 x = p[0];
                u32 u[4] = {x.x, x.y, x.z, x.w};
                #pragma unroll
                for (int i = 0; i < 4; i++) {
                    v[rr][2 * i + 0] = (u[i] & 0xffffu) ? 1.f : 0.f;
                    v[rr][2 * i + 1] = (u[i] >> 16)     ? 1.f : 0.f;
                }
            }
        }
        #pragma unroll
        for (int rr = 0; rr < 4; rr++) {
            int cnt = 0;
            #pragma unroll
            for (int i = 0; i < 8; i++) cnt += (v[rr][i] != 0.f) ? 1 : 0;
            int pfx = cnt;
            #pragma unroll
            for (int o = 1; o < 64; o <<= 1) {
                int s = __shfl_up(pfx, o, 64);
                if (lane >= o) pfx += s;
            }
            int wtot = __shfl(pfx, 63, 64);
            u32 wb = 0;
            if (lane == 0) wb = atomicAdd(&lcnt[rr], (u32)wtot);
            wb = __shfl((int)wb, 0, 64);
            int o = (int)wb + pfx - cnt;
            u16* ridx = c.ridx[m] + (size_t)(r0 + rr) * 2048;
            #pragma unroll
            for (int i = 0; i < 8; i++) {
                if (v[rr][i] != 0.f) {
                    ridx[o++] = (u16)(c0 + i);
                    if (m == 0) {
                        int ccol = c0 + i;
                        u32 q = atomicAdd(&c.ccnt[ccol], 1u);
                        c.cidx[(size_t)ccol * 2048 + q] = (u16)(r0 + rr);
                    }
                }
            }
        }
        __syncthreads();
        if (t < 4) c.rcnt[m][r0 + t] = lcnt[t];
    } else {
        int idx = bx - 1536;
        int seg = idx >> 6, xb = idx & 63;
        int n = a.n[seg];
        const void* s = a.src[seg];
        u16* d = base + a.off[seg];
        int nw = n >> 1;
        if (f32) {
            const float2* sf = (const float2*)s;
            u32* dw = (u32*)d;
            for (int i = xb * 256 + t; i < nw; i += 16384) {
                float2 v = sf[i];
                dw[i] = (u32)f2bf(v.x) | ((u32)f2bf(v.y) << 16);
            }
        } else {
            const u32* sw = (const u32*)s;
            u32* dw = (u32*)d;
            for (int i = xb * 256 + t; i < nw; i += 16384) dw[i] = sw[i];
        }
        if ((n & 1) && xb == 0 && t == 0)
            d[n - 1] = f32 ? f2bf(((const float*)s)[n - 1]) : ((const u16*)s)[n - 1];
    }
}

// ---------------- merged prep ------------------------------------------
// [0,4):        colsum + bias combine (longest per-block, start first)
// [4,1028):     avg aggregation (task = (id>>9): 0=e_e->A_e+128, 1=p_p->A_p+128)
// [1028,2052):  koqs-v2 (8 row-units/block, W staged in LDS)
// [2052,2148):  tpose_smalls (96 tiles)
struct PR {
    const u16* demb; const u16* pemb;
    const u16* Wa1d; const u16* ba1d;
    const u16* Wa1p; const u16* ba1p;
    float* ko_d; float* qs_d; float* ko_p; float* qs_p;
    const u16* ts[6]; u16* W1T; u16* W2T; u16* WcTe; u16* WcTp;
    const u16* ba[3]; const u16* bb[3]; u16* b_e; u16* b_p;
    float* csd; float* csp;
    const u16* avgidx[2]; const u32* avgcnt[2]; const u16* avgemb[2]; u16* avgout[2];
};

__global__ __launch_bounds__(256) void prep2(PR p) {
    int bx = blockIdx.x;
    int tid = threadIdx.x;
    __shared__ float sx[2][128];
    __shared__ float sred[2][128];
    __shared__ u16 stile[32][33];
    __shared__ float st0[256], st1[256];
    __shared__ u16 Wl[4096];

    if (bx < 4) {
        // ---- colsum (f32) + bias combine; block owns 64 dims of one matrix
        int id = bx;             // 0..3
        int m = id >> 1, half = id & 1;
        const u16* e = m ? p.pemb : p.demb;
        int c2 = tid & 31, rg = tid >> 5;     // 32 dim-pairs x 8 row-groups
        int dbase = half * 64;
        float s0 = 0.f, s1 = 0.f;
        for (int it = 0; it < 256; it++) {
            int row = it * 8 + rg;
            u32 v = *(const u32*)(e + (size_t)row * 128 + dbase + c2 * 2);
            s0 += bf2f((u16)(v & 0xffffu));
            s1 += bf2f((u16)(v >> 16));
        }
        st0[tid] = s0; st1[tid] = s1;
        __syncthreads();
        if (tid < 32) {
            float a0 = 0.f, a1 = 0.f;
            #pragma unroll
            for (int g = 0; g < 8; g++) { a0 += st0[g * 32 + tid]; a1 += st1[g * 32 + tid]; }
            float* cs = m ? p.csp : p.csd;
            cs[dbase + tid * 2 + 0] = a0;
            cs[dbase + tid * 2 + 1] = a1;
        }
        if (tid < 64) {
            int d = dbase + tid;
            if (m == 0)
                p.b_e[d] = f2bf(bf2f(p.ba[0][d]) + bf2f(p.ba[1][d]) + bf2f(p.ba[2][d]));
            else
                p.b_p[d] = f2bf(bf2f(p.bb[0][d]) + bf2f(p.bb[1][d]) + bf2f(p.bb[2][d]));
        }
    } else if (bx < 1028) {
        // ---- avg aggregation (knn branch): 4 rows per block
        int id = bx - 4;
        int task = id >> 9, blk = id & 511;
        int wv = tid >> 6, lane = tid & 63;
        int grp = lane >> 4, dim = lane & 15;
        int r = blk * 4 + wv;
        const u16* idx = p.avgidx[task] + (size_t)r * 2048;
        int nnz = (int)p.avgcnt[task][r];
        const u16* emb = p.avgemb[task];
        float acc[8];
        #pragma unroll
        for (int t = 0; t < 8; t++) acc[t] = 0.f;
        for (int base = 0; base < nnz; base += 64) {
            int i = base + lane;
            int j = (i < nnz) ? (int)idx[i] : 0;
            int cend = min(64, nnz - base);
            #pragma unroll 4
            for (int k4 = 0; k4 < cend; k4 += 4) {
                int kk = k4 + grp;
                int jk = __shfl(j, kk, 64);
                float wk = (base + kk < nnz) ? 1.f : 0.f;
                const uint4* pp = (const uint4*)((const char*)emb + jk * 256 + dim * 16);
                uint4 vv = *pp;
                u32 u[4] = {vv.x, vv.y, vv.z, vv.w};
                #pragma unroll
                for (int cc = 0; cc < 4; cc++) {
                    acc[2 * cc + 0] = fmaf(wk, bf2f((u16)(u[cc] & 0xffffu)), acc[2 * cc + 0]);
                    acc[2 * cc + 1] = fmaf(wk, bf2f((u16)(u[cc] >> 16)), acc[2 * cc + 1]);
                }
            }
        }
        #pragma unroll
        for (int t = 0; t < 8; t++) {
            acc[t] += __shfl_xor(acc[t], 32, 64);
            acc[t] += __shfl_xor(acc[t], 16, 64);
        }
        if (grp == 0) {
            float sc = 1.f / ((float)nnz + 1e-8f);
            float v[8];
            #pragma unroll
            for (int t = 0; t < 8; t++) v[t] = acc[t] * sc;
            uint4 pk;
            pk.x = (u32)f2bf(v[0]) | ((u32)f2bf(v[1]) << 16);
            pk.y = (u32)f2bf(v[2]) | ((u32)f2bf(v[3]) << 16);
            pk.z = (u32)f2bf(v[4]) | ((u32)f2bf(v[5]) << 16);
            pk.w = (u32)f2bf(v[6]) | ((u32)f2bf(v[7]) << 16);
            *(uint4*)(p.avgout[task] + (size_t)r * 256 + dim * 8) = pk;
        }
    } else if (bx < 2052) {
        // ---- koqs-v2: 8 row-units per block, W staged in LDS (8 KB)
        int blk = bx - 1028;       // 0..1023
        int m = blk >> 8;          // 256 blocks per matrix m
        int r0 = (blk & 255) * 8;  // 8 rows per block
        const u16* src; const u16* W; const u16* bias; float* out;
        switch (m) {
            case 0:  src = p.pemb; W = p.Wa1d;            bias = nullptr; out = p.ko_d; break;
            case 1:  src = p.demb; W = p.Wa1d + 128 * 32; bias = p.ba1d;  out = p.qs_d; break;
            case 2:  src = p.demb; W = p.Wa1p;            bias = nullptr; out = p.ko_p; break;
            default: src = p.pemb; W = p.Wa1p + 128 * 32; bias = p.ba1p;  out = p.qs_p; break;
        }
        {
            const uint4* wsrc = (const uint4*)W;    // 4096 u16 = 512 uint4
            uint4* wdst = (uint4*)Wl;
            #pragma unroll
            for (int i = 0; i < 2; i++) wdst[i * 256 + tid] = wsrc[i * 256 + tid];
        }
        __syncthreads();
        int sub = tid >> 7, t = tid & 127;
        int a = t & 31, part = t >> 5;
        #pragma unroll 1
        for (int rp = 0; rp < 4; rp++) {
            int row = r0 + rp * 2 + sub;
            sx[sub][t] = bf2f(src[(size_t)row * 128 + t]);
            __syncthreads();
            float s = 0.f;
            #pragma unroll
            for (int k = 0; k < 32; k++)
                s += sx[sub][part * 32 + k] * bf2f(Wl[(part * 32 + k) * 32 + a]);
            sred[sub][t] = s;
            __syncthreads();
            if (part == 0) {
                float tt = sred[sub][a] + sred[sub][a + 32] + sred[sub][a + 64] + sred[sub][a + 96];
                if (bias) tt += bf2f(bias[a]);
                out[(size_t)row * 32 + a] = tt;
            }
            __syncthreads();
        }
    } else {
        // ---- tpose_smalls
        int id = bx - 2052;
        int z = id >> 4, rem = id & 15;
        int c0 = (rem & 3) * 32, r0 = (rem >> 2) * 32;
        const u16* in = p.ts[z];
        u16* out; int ldo, ooff;
        switch (z) {
            case 0:  out = p.W1T;  ldo = 128; ooff = 0;   break;
            case 1:  out = p.W2T;  ldo = 128; ooff = 0;   break;
            case 2:  out = p.WcTe; ldo = 256; ooff = 0;   break;
            case 3:  out = p.WcTe; ldo = 256; ooff = 128; break;
            case 4:  out = p.WcTp; ldo = 256; ooff = 0;   break;
            default: out = p.WcTp; ldo = 256; ooff = 128; break;
        }
        int tx = tid & 31, ty = tid >> 5;
        int x = c0 + tx;
        for (int i = ty; i < 32; i += 8)
            stile[i][tx] = in[(size_t)(r0 + i) * 128 + x];
        __syncthreads();
        int rr = r0 + tx;
        for (int i = ty; i < 32; i += 8)
            out[(size_t)(c0 + i) * ldo + ooff + rr] = stile[tx][i];
    }
}

// ---------------- sparse attention aggregation (2 attn tasks only) ---------
struct SP {
    const u16* idx[2]; const u32* cnt[2];
    const float* ko[2]; const float* qs[2];
    const u16* w2[2]; const u16* b2[2];
    const u16* emb[2]; const float* csum[2];
    u16* out[2];
};

__global__ __launch_bounds__(256) void spagg(SP a) {
    int task = blockIdx.y;
    int tid = threadIdx.x;
    int wv = tid >> 6, lane = tid & 63;
    int grp = lane >> 4, dim = lane & 15;
    int r = blockIdx.x * 4 + wv;
    const u16* idx = a.idx[task] + (size_t)r * 2048;
    int nnz = (int)a.cnt[task][r];
    const u16* emb = a.emb[task];
    const float* ko = a.ko[task];

    float qsr[32], w2h[32];
    {
        const float4* qp = (const float4*)(a.qs[task] + (size_t)r * 32);
        #pragma unroll
        for (int i = 0; i < 8; i++) {
            float4 v = qp[i];
            qsr[4 * i + 0] = v.x; qsr[4 * i + 1] = v.y;
            qsr[4 * i + 2] = v.z; qsr[4 * i + 3] = v.w;
        }
        #pragma unroll
        for (int i = 0; i < 32; i++) w2h[i] = bf2f(a.w2[task][i]);
    }
    float b2v = bf2f(a.b2[task][0]);

    float acc[8];
    #pragma unroll
    for (int t = 0; t < 8; t++) acc[t] = 0.f;
    float wsuml = 0.f;

    for (int base = 0; base < nnz; base += 64) {
        int i = base + lane;
        float w = 0.f;
        int j = 0;
        if (i < nnz) {
            j = (int)idx[i];
            const float4* kp = (const float4*)(ko + (size_t)j * 32);
            float s = 0.f;
            #pragma unroll
            for (int q = 0; q < 8; q++) {
                float4 kv = kp[q];
                s += fmaxf(qsr[4 * q + 0] + kv.x, 0.f) * w2h[4 * q + 0];
                s += fmaxf(qsr[4 * q + 1] + kv.y, 0.f) * w2h[4 * q + 1];
                s += fmaxf(qsr[4 * q + 2] + kv.z, 0.f) * w2h[4 * q + 2];
                s += fmaxf(qsr[4 * q + 3] + kv.w, 0.f) * w2h[4 * q + 3];
            }
            w = __expf(fmaxf(s + b2v, 0.f)) - 1.f;
            wsuml += w;
        }
        int cend = min(64, nnz - base);
        #pragma unroll 4
        for (int k4 = 0; k4 < cend; k4 += 4) {
            int kk = k4 + grp;
            float wk = __shfl(w, kk, 64);
            int jk = __shfl(j, kk, 64);
            const uint4* pp = (const uint4*)((const char*)emb + jk * 256 + dim * 16);
            uint4 vv = *pp;
            u32 u[4] = {vv.x, vv.y, vv.z, vv.w};
            #pragma unroll
            for (int cc = 0; cc < 4; cc++) {
                acc[2 * cc + 0] = fmaf(wk, bf2f((u16)(u[cc] & 0xffffu)), acc[2 * cc + 0]);
                acc[2 * cc + 1] = fmaf(wk, bf2f((u16)(u[cc] >> 16)), acc[2 * cc + 1]);
            }
        }
    }

    #pragma unroll
    for (int t = 0; t < 8; t++) {
        acc[t] += __shfl_xor(acc[t], 32, 64);
        acc[t] += __shfl_xor(acc[t], 16, 64);
    }
    #pragma unroll
    for (int o = 32; o > 0; o >>= 1) wsuml += __shfl_xor(wsuml, o, 64);

    if (grp == 0) {
        float sc = 1.f / (2048.f + wsuml);
        const float* cs = a.csum[task] + dim * 8;
        float v[8];
        #pragma unroll
        for (int t = 0; t < 8; t++) v[t] = (cs[t] + acc[t]) * sc;
        uint4 pk;
        pk.x = (u32)f2bf(v[0]) | ((u32)f2bf(v[1]) << 16);
        pk.y = (u32)f2bf(v[2]) | ((u32)f2bf(v[3]) << 16);
        pk.z = (u32)f2bf(v[4]) | ((u32)f2bf(v[5]) << 16);
        pk.w = (u32)f2bf(v[6]) | ((u32)f2bf(v[7]) << 16);
        *(uint4*)(a.out[task] + (size_t)r * 256 + dim * 8) = pk;
    }
}

// ---------------- MFMA GEMM: canonical LDS-tiled (combine stage) -----------
struct GD4 {
    const void* A[4]; const u16* BT[4]; u16* C[4];
    const u16* bias[4]; const float* rs[4];
    int lda[4], ldb[4], ldc[4], coff[4], kiters[4], act[4], araw[4], rsmode[4];
};

#define PADK 136

__global__ __launch_bounds__(256, 2) void gemmL(GD4 g, const u32* __restrict__ flag) {
    __shared__ __align__(16) u16 As[16][PADK];
    __shared__ __align__(16) u16 Bs[128][PADK];
    int z = blockIdx.y;
    const void* A = g.A[z];
    const u16* BT = g.BT[z];
    int lda = g.lda[z], ldb = g.ldb[z];
    int kiters = g.kiters[z];
    int tid = threadIdx.x;
    int lane = tid & 63, wv = tid >> 6;
    int mrow = lane & 15, quad = lane >> 4;
    int m0 = blockIdx.x * 16;
    int c0 = wv * 32;
    int sr = tid >> 4, sk = (tid & 15) * 8;
    f32x4 acc0 = {0.f, 0.f, 0.f, 0.f}, acc1 = {0.f, 0.f, 0.f, 0.f};

    short8 ra, rb[8];
    auto ldstage = [&](int kb) {
        ra = *(const short8*)((const u16*)A + (size_t)(m0 + sr) * lda + kb + sk);
        const u16* bbase = BT + (size_t)sr * ldb + kb + sk;
        #pragma unroll
        for (int i = 0; i < 8; i++)
            rb[i] = *(const short8*)(bbase + (size_t)i * 16 * ldb);
    };
    auto ststage = [&]() {
        *(short8*)(&As[sr][sk]) = ra;
        #pragma unroll
        for (int i = 0; i < 8; i++)
            *(short8*)(&Bs[i * 16 + sr][sk]) = rb[i];
    };
    auto compute = [&]() {
        #pragma unroll
        for (int ks = 0; ks < 4; ks++) {
            short8 af = *(const short8*)(&As[mrow][ks * 32 + quad * 8]);
            short8 b0 = *(const short8*)(&Bs[c0 + mrow][ks * 32 + quad * 8]);
            short8 b1 = *(const short8*)(&Bs[c0 + 16 + mrow][ks * 32 + quad * 8]);
            acc0 = __builtin_amdgcn_mfma_f32_16x16x32_bf16(af, b0, acc0, 0, 0, 0);
            acc1 = __builtin_amdgcn_mfma_f32_16x16x32_bf16(af, b1, acc1, 0, 0, 0);
        }
    };

    ldstage(0);
    #pragma unroll 1
    for (int it = 0; it < kiters - 1; ++it) {
        ststage();
        __syncthreads();
        ldstage((it + 1) * 128);
        compute();
        __syncthreads();
    }
    ststage();
    __syncthreads();
    compute();

    const float* rs = g.rs[z];
    int rsmode = g.rsmode[z];
    const u16* bi = g.bias[z];
    u16* C = g.C[z];
    int ldc = g.ldc[z], coff = g.coff[z], act = g.act[z];
    int n0 = c0 + mrow, n1 = n0 + 16;
    float bv0 = bi ? bf2f(bi[n0]) : 0.f;
    float bv1 = bi ? bf2f(bi[n1]) : 0.f;
    #pragma unroll
    for (int r = 0; r < 4; r++) {
        int row = m0 + quad * 4 + r;
        float v0 = acc0[r], v1 = acc1[r];
        if (rsmode == 1) { float sc = rs[row]; v0 *= sc; v1 *= sc; }
        else if (rsmode == 2) {
            float t = 0.f;
            #pragma unroll
            for (int p = 0; p < 8; p++) t += rs[row + p * 2048];
            float sc = 1.f / t;
            v0 *= sc; v1 *= sc;
        }
        v0 += bv0; v1 += bv1;
        if (act) { v0 = seluf(v0); v1 = seluf(v1); }
        C[(size_t)row * ldc + coff + n0] = f2bf(v0);
        C[(size_t)row * ldc + coff + n1] = f2bf(v1);
    }
}

// ---------------- fused pair MLP + loss finalization -----------------------
#define PADX 136
__global__ __launch_bounds__(256, 2) void mlpfused(
    const u16* __restrict__ he, const u16* __restrict__ hp,
    const int* __restrict__ di, const int* __restrict__ dr,
    const u16* __restrict__ W1T, const u16* __restrict__ b1,
    const u16* __restrict__ W2T, const u16* __restrict__ b2,
    const u16* __restrict__ wpred, const u16* __restrict__ bpred,
    const int* __restrict__ labels,
    float* __restrict__ out, float* __restrict__ lossacc,
    u32* __restrict__ losscnt) {
    __shared__ __align__(16) u16 Xs[64][PADX];
    __shared__ __align__(16) u16 Ws[128][PADX];
    __shared__ float wred[4];
    int tid = threadIdx.x;
    int lane = tid & 63, wv = tid >> 6;
    int mrow = lane & 15, quad = lane >> 4;
    int p0 = blockIdx.x * 64;

    {
        int row = tid >> 2, sub = tid & 3;
        int b = p0 + row;
        int ia = di[b], ic = dr[b];
        const uint4* pe = (const uint4*)(he + (size_t)ia * 128 + sub * 32);
        const uint4* pp = (const uint4*)(hp + (size_t)ic * 128 + sub * 32);
        #pragma unroll
        for (int q = 0; q < 4; q++) {
            uint4 ue = pe[q], up = pp[q];
            u32 eu[4] = {ue.x, ue.y, ue.z, ue.w};
            u32 pu[4] = {up.x, up.y, up.z, up.w};
            #pragma unroll
            for (int c = 0; c < 4; c++) {
                float lo = bf2f((u16)(eu[c] & 0xffffu)) * bf2f((u16)(pu[c] & 0xffffu));
                float hi = bf2f((u16)(eu[c] >> 16)) * bf2f((u16)(pu[c] >> 16));
                *(u32*)(&Xs[row][sub * 32 + q * 8 + c * 2]) =
                    (u32)f2bf(lo) | ((u32)f2bf(hi) << 16);
            }
        }
    }
    {
        int n = tid >> 1, half = tid & 1;
        const short8* src = (const short8*)(W1T + (size_t)n * 128 + half * 64);
        short8* dst = (short8*)(&Ws[n][half * 64]);
        #pragma unroll
        for (int i = 0; i < 8; i++) dst[i] = src[i];
    }
    __syncthreads();

    f32x4 acc[8];
    #pragma unroll
    for (int nt = 0; nt < 8; nt++) acc[nt] = {0.f, 0.f, 0.f, 0.f};
    #pragma unroll
    for (int ks = 0; ks < 4; ks++) {
        short8 af = *(const short8*)(&Xs[wv * 16 + mrow][ks * 32 + quad * 8]);
        #pragma unroll
        for (int nt = 0; nt < 8; nt++) {
            short8 bfv = *(const short8*)(&Ws[nt * 16 + mrow][ks * 32 + quad * 8]);
            acc[nt] = __builtin_amdgcn_mfma_f32_16x16x32_bf16(af, bfv, acc[nt], 0, 0, 0);
        }
    }
    __syncthreads();
    #pragma unroll
    for (int nt = 0; nt < 8; nt++) {
        int col = nt * 16 + mrow;
        float bv = bf2f(b1[col]);
        #pragma unroll
        for (int r = 0; r < 4; r++) {
            int row = wv * 16 + quad * 4 + r;
            Xs[row][col] = f2bf(seluf(acc[nt][r] + bv));
        }
    }
    {
        int n = tid >> 1, half = tid & 1;
        const short8* src = (const short8*)(W2T + (size_t)n * 128 + half * 64);
        short8* dst = (short8*)(&Ws[n][half * 64]);
        #pragma unroll
        for (int i = 0; i < 8; i++) dst[i] = src[i];
    }
    __syncthreads();

    #pragma unroll
    for (int nt = 0; nt < 8; nt++) acc[nt] = {0.f, 0.f, 0.f, 0.f};
    #pragma unroll
    for (int ks = 0; ks < 4; ks++) {
        short8 af = *(const short8*)(&Xs[wv * 16 + mrow][ks * 32 + quad * 8]);
        #pragma unroll
        for (int nt = 0; nt < 8; nt++) {
            short8 bfv = *(const short8*)(&Ws[nt * 16 + mrow][ks * 32 + quad * 8]);
            acc[nt] = __builtin_amdgcn_mfma_f32_16x16x32_bf16(af, bfv, acc[nt], 0, 0, 0);
        }
    }

    float zp[4] = {0.f, 0.f, 0.f, 0.f};
    #pragma unroll
    for (int nt = 0; nt < 8; nt++) {
        int col = nt * 16 + mrow;
        float bv = bf2f(b2[col]);
        float wp = bf2f(wpred[col]);
        #pragma unroll
        for (int r = 0; r < 4; r++) {
            float x2 = bf2f(f2bf(seluf(acc[nt][r] + bv)));
            zp[r] = fmaf(x2, wp, zp[r]);
        }
    }
    #pragma unroll
    for (int r = 0; r < 4; r++) {
        #pragma unroll
        for (int o = 1; o < 16; o <<= 1) zp[r] += __shfl_xor(zp[r], o, 64);
    }
    float bpv = bf2f(bpred[0]);
    float lsum = 0.f;
    #pragma unroll
    for (int r = 0; r < 4; r++) {
        int b = p0 + wv * 16 + quad * 4 + r;
        float z = zp[r] + bpv;
        float sig = 1.f / (1.f + __expf(-z));
        if (mrow == 0) out[1 + b] = sig;
        float y = (float)labels[b];
        lsum += fmaxf(z, 0.f) - z * y + log1pf(__expf(-fabsf(z)));
    }
    // quad-only butterfly: 16 mrow lanes hold identical lsum (zp reduced over
    // mrow), so the result is the exact 16-row wave sum on every lane.
    lsum += __shfl_xor(lsum, 16, 64);
    lsum += __shfl_xor(lsum, 32, 64);
    if (lane == 0) wred[wv] = lsum;
    __syncthreads();
    if (tid == 0) {
        float bs = wred[0] + wred[1] + wred[2] + wred[3];
        atomicAdd(lossacc, bs);
        __threadfence();
        u32 old = atomicAdd(losscnt, 1u);
        if (old == 255u) {
            float tot = atomicAdd(lossacc, 0.f);
            out[0] = tot * (1.f / 16384.f);
        }
    }
}

// ---------------- launch ----------------
extern "C" void kernel_launch(void* const* d_in, const int* in_sizes, int n_in,
                              void* d_out, int out_size, void* d_ws, size_t ws_size,
                              hipStream_t stream) {
    const void* e_p_adj = d_in[0];
    const void* e_e_adj = d_in[1];
    const void* p_p_adj = d_in[2];
    const int* in_dis  = (const int*)d_in[3];
    const int* in_drug = (const int*)d_in[4];
    const int* labels  = (const int*)d_in[5];
    float* out = (float*)d_out;

    // -------- workspace layout --------
    char* ws = (char*)d_ws;
    size_t off = 0;
    auto take = [&](size_t bytes) { char* p = ws + off; off = (off + bytes + 255) & ~(size_t)255; return p; };
    u16*   A_e   = (u16*)take((size_t)2048 * 256 * 2);
    u16*   A_p   = (u16*)take((size_t)2048 * 256 * 2);
    u16*   WcTe  = (u16*)take((size_t)128 * 256 * 2);
    u16*   WcTp  = (u16*)take((size_t)128 * 256 * 2);
    u16*   W1T   = (u16*)take((size_t)128 * 128 * 2);
    u16*   W2T   = (u16*)take((size_t)128 * 128 * 2);
    u16*   b_e   = (u16*)take(256);
    u16*   b_p   = (u16*)take(256);
    u16*   h_e   = (u16*)take((size_t)2048 * 128 * 2);
    u16*   h_p   = (u16*)take((size_t)2048 * 128 * 2);
    float* ko_d  = (float*)take((size_t)2048 * 32 * 4);
    float* qs_d  = (float*)take((size_t)2048 * 32 * 4);
    float* ko_p  = (float*)take((size_t)2048 * 32 * 4);
    float* qs_p  = (float*)take((size_t)2048 * 32 * 4);
    float* csd   = (float*)take(128 * 4);
    float* csp   = (float*)take(128 * 4);
    float* lossacc = (float*)take(256);
    u32*   losscnt = (u32*)((char*)lossacc + 4);
    u32*   flag  = (u32*)take(256);
    u16*   canon = (u16*)take((size_t)700000 * 2);
    u16*   idx0  = (u16*)take((size_t)2048 * 2048 * 2);  // e_p rows (disease)
    u16*   idx1  = (u16*)take((size_t)2048 * 2048 * 2);  // e_p cols (drug)
    u16*   idx2  = (u16*)take((size_t)2048 * 2048 * 2);  // e_e rows
    u16*   idx3  = (u16*)take((size_t)2048 * 2048 * 2);  // p_p rows
    u32*   cnt0  = (u32*)take(2048 * 4);
    u32*   cnt2  = (u32*)take(2048 * 4);
    u32*   cnt3  = (u32*)take(2048 * 4);
    u32*   cntT  = (u32*)take(2048 * 4);                 // e_p col counts

    // -------- canonical parameter table --------
    const int segidx[NSEG] = {6, 7, 14, 18, 8, 22, 11, 24, 26, 28,
                              15, 16, 17, 19, 20, 21,
                              9, 10, 12, 13, 23, 25, 27, 29, 30, 31};
    const int segn[NSEG]   = {262144, 262144, 8192, 8192, 16384, 16384, 16384, 16384, 16384, 16384,
                              32, 32, 1, 32, 32, 1,
                              128, 128, 128, 128, 128, 128, 128, 128, 128, 1};
    CvtArgs ca;
    u16* cp[NSEG];
    {
        int o = 0;
        for (int i = 0; i < NSEG; i++) {
            ca.src[i] = d_in[segidx[i]];
            ca.off[i] = o;
            ca.n[i] = segn[i];
            cp[i] = canon + o;
            o += (segn[i] + 15) & ~15;
        }
    }
    u16 *cdemb = cp[0], *cpemb = cp[1], *cWa1d = cp[2], *cWa1p = cp[3];
    u16 *cWdg = cp[4], *cWd2 = cp[5], *cWpg = cp[6], *cWp3 = cp[7];
    u16 *cW1 = cp[8], *cW2 = cp[9];
    u16 *cba1d = cp[10], *cWa2d = cp[11], *cba2d = cp[12];
    u16 *cba1p = cp[13], *cWa2p = cp[14], *cba2p = cp[15];
    u16 *cbdg_lin = cp[16], *cbdg = cp[17], *cbpg_lin = cp[18], *cbpg = cp[19];
    u16 *cbd2 = cp[20], *cbp3 = cp[21], *cmb1 = cp[22], *cmb2 = cp[23];
    u16 *cWpred = cp[24], *cbpred = cp[25];

    // -------- 0. dtype detection + per-iteration zeroing --------
    detectk<<<1, 256, 0, stream>>>(d_in[6], flag, cntT, lossacc, losscnt);

    // -------- 1. merged conversion + CSR row lists + e_p col scatter --------
    {
        CS cs;
        cs.adj[0] = e_p_adj; cs.ridx[0] = idx0; cs.rcnt[0] = cnt0;
        cs.adj[1] = e_e_adj; cs.ridx[1] = idx2; cs.rcnt[1] = cnt2;
        cs.adj[2] = p_p_adj; cs.ridx[2] = idx3; cs.rcnt[2] = cnt3;
        cs.cidx = idx1; cs.ccnt = cntT;
        cvtcsr<<<1536 + 64 * NSEG, 256, 0, stream>>>(ca, canon, cs, flag);
    }

    // -------- 2. merged prep (colsum + avg-agg + koqs-v2 + tpose) --------
    PR pr;
    pr.demb = cdemb; pr.pemb = cpemb;
    pr.Wa1d = cWa1d; pr.ba1d = cba1d; pr.Wa1p = cWa1p; pr.ba1p = cba1p;
    pr.ko_d = ko_d; pr.qs_d = qs_d; pr.ko_p = ko_p; pr.qs_p = qs_p;
    pr.ts[0] = cW1; pr.ts[1] = cW2; pr.ts[2] = cWdg;
    pr.ts[3] = cWd2; pr.ts[4] = cWpg; pr.ts[5] = cWp3;
    pr.W1T = W1T; pr.W2T = W2T; pr.WcTe = WcTe; pr.WcTp = WcTp;
    pr.ba[0] = cbdg_lin; pr.ba[1] = cbdg; pr.ba[2] = cbd2;
    pr.bb[0] = cbpg_lin; pr.bb[1] = cbpg; pr.bb[2] = cbp3;
    pr.b_e = b_e; pr.b_p = b_p; pr.csd = csd; pr.csp = csp;
    pr.avgidx[0] = idx2; pr.avgcnt[0] = cnt2; pr.avgemb[0] = cdemb; pr.avgout[0] = A_e + 128;
    pr.avgidx[1] = idx3; pr.avgcnt[1] = cnt3; pr.avgemb[1] = cpemb; pr.avgout[1] = A_p + 128;
    prep2<<<2148, 256, 0, stream>>>(pr);

    // -------- 3. sparse attention aggregation (2 tasks) --------
    {
        SP sp;
        sp.idx[0] = idx0; sp.cnt[0] = cnt0; sp.ko[0] = ko_d; sp.qs[0] = qs_d;
        sp.w2[0] = cWa2d; sp.b2[0] = cba2d; sp.emb[0] = cpemb; sp.csum[0] = csp;
        sp.out[0] = A_e;
        sp.idx[1] = idx1; sp.cnt[1] = cntT; sp.ko[1] = ko_p; sp.qs[1] = qs_p;
        sp.w2[1] = cWa2p; sp.b2[1] = cba2p; sp.emb[1] = cdemb; sp.csum[1] = csd;
        sp.out[1] = A_p;
        spagg<<<dim3(512, 2), 256, 0, stream>>>(sp);
    }

    auto setd = [](GD4& g, int z, const void* A, int lda, const u16* BT, int ldb,
                   u16* C, int ldc, int coff, int ki, const u16* bi,
                   const float* rs, int act, int araw, int rm) {
        g.A[z] = A; g.lda[z] = lda; g.BT[z] = BT; g.ldb[z] = ldb;
        g.C[z] = C; g.ldc[z] = ldc; g.coff[z] = coff; g.kiters[z] = ki;
        g.bias[z] = bi; g.rs[z] = rs; g.act[z] = act; g.araw[z] = araw; g.rsmode[z] = rm;
    };

    // -------- 4. combine GEMMs (bias + SELU), batched ----------------------
    {
        GD4 g;
        setd(g, 0, A_e, 256, WcTe, 256, h_e, 128, 0, 2, b_e, nullptr, 1, 0, 0);
        setd(g, 1, A_p, 256, WcTp, 256, h_p, 128, 0, 2, b_p, nullptr, 1, 0, 0);
        setd(g, 2, A_e, 256, WcTe, 256, h_e, 128, 0, 2, b_e, nullptr, 1, 0, 0);
        setd(g, 3, A_e, 256, WcTe, 256, h_e, 128, 0, 2, b_e, nullptr, 1, 0, 0);
        gemmL<<<dim3(128, 2), 256, 0, stream>>>(g, flag);
    }

    // -------- 5. fused pair MLP + loss --------
    mlpfused<<<256, 256, 0, stream>>>(h_e, h_p, in_dis, in_drug,
                                      W1T, cmb1, W2T, cmb2,
                                      cWpred, cbpred, labels, out,
                                      lossacc, losscnt);
}

// Round 8
// 231.726 us; speedup vs baseline: 1.2337x; 1.0050x over previous
//
#include <hip/hip_runtime.h>

#define ND   2048
#define BB   16384

typedef unsigned short u16;
typedef unsigned int u32;
typedef __attribute__((ext_vector_type(8))) short short8;
typedef __attribute__((ext_vector_type(4))) float f32x4;

__device__ inline float bf2f(u16 u) {
    union { u32 i; float f; } v; v.i = ((u32)u) << 16; return v.f;
}
__device__ inline u16 f2bf(float f) {
    union { float f; u32 i; } v; v.f = f;
    u32 i = v.i + 0x7fffu + ((v.i >> 16) & 1u);
    return (u16)(i >> 16);
}
__device__ inline float seluf(float x) {
    const float sc = 1.0507009873554805f, al = 1.6732632423543772f;
    return x > 0.f ? sc * x : sc * al * expm1f(x);
}

// ---------------- dtype sniffer + per-iteration zeroing ----------------
__global__ void detectk(const void* __restrict__ demb, u32* __restrict__ flag,
                        u32* __restrict__ cntT, float* __restrict__ lossacc,
                        u32* __restrict__ losscnt) {
    const u16* p = (const u16*)demb;
    int tid = threadIdx.x;  // 256
    #pragma unroll
    for (int i = 0; i < 8; i++) cntT[i * 256 + tid] = 0u;
    if (tid == 0) { lossacc[0] = 0.f; losscnt[0] = 0u; }
    int sane = 0;
    #pragma unroll
    for (int i = 0; i < 2; i++) {
        u16 u = p[4 * tid + 2 * i];
        int e = (u >> 7) & 0xFF;
        if (u == 0 || (e >= 0x66 && e <= 0x8C)) sane++;
    }
    __shared__ int red[256];
    red[tid] = sane; __syncthreads();
    for (int o = 128; o > 0; o >>= 1) {
        if (tid < o) red[tid] += red[tid + o];
        __syncthreads();
    }
    if (tid == 0) flag[0] = (red[0] < 300) ? 1u : 0u;
}

// ---------------- merged: conversion + CSR row lists -----------------------
// blocks [0,1536): csr role, 4 rows/block (m = bx>>9, r0 = (bx&511)*4)
// blocks [1536,3200): cvt role (seg = idx>>6, 64 blocks/segment), u32-wide
#define NSEG 26
struct CvtArgs { const void* src[NSEG]; int off[NSEG]; int n[NSEG]; };
struct CS {
    const void* adj[3];
    u16* ridx[3]; u32* rcnt[3];
};

__global__ __launch_bounds__(256) void cvtcsr(CvtArgs a, u16* __restrict__ base,
                                              CS c, const u32* __restrict__ flag) {
    int bx = blockIdx.x;
    int t = threadIdx.x;
    bool f32 = flag[0] != 0;
    if (bx < 1536) {
        int m = bx >> 9;
        int r0 = (bx & 511) * 4;
        int lane = t & 63;
        __shared__ u32 lcnt[4];
        if (t < 4) lcnt[t] = 0;
        __syncthreads();
        float v[4][8];
        int c0 = t * 8;
        if (f32) {
            #pragma unroll
            for (int rr = 0; rr < 4; rr++) {
                const float4* p = (const float4*)((const float*)c.adj[m] +
                                                  (size_t)(r0 + rr) * 2048 + c0);
                float4 x = p[0], y = p[1];
                v[rr][0] = x.x; v[rr][1] = x.y; v[rr][2] = x.z; v[rr][3] = x.w;
                v[rr][4] = y.x; v[rr][5] = y.y; v[rr][6] = y.z; v[rr][7] = y.w;
            }
        } else {
            #pragma unroll
            for (int rr = 0; rr < 4; rr++) {
                const uint4* p = (const uint4*)((const u16*)c.adj[m] +
                                                (size_t)(r0 + rr) * 2048 + c0);
                uint4 x = p[0];
                u32 u[4] = {x.x, x.y, x.z, x.w};
                #pragma unroll
                for (int i = 0; i < 4; i++) {
                    v[rr][2 * i + 0] = (u[i] & 0xffffu) ? 1.f : 0.f;
                    v[rr][2 * i + 1] = (u[i] >> 16)     ? 1.f : 0.f;
                }
            }
        }
        #pragma unroll
        for (int rr = 0; rr < 4; rr++) {
            int cnt = 0;
            #pragma unroll
            for (int i = 0; i < 8; i++) cnt += (v[rr][i] != 0.f) ? 1 : 0;
            int pfx = cnt;
            #pragma unroll
            for (int o = 1; o < 64; o <<= 1) {
                int s = __shfl_up(pfx, o, 64);
                if (lane >= o) pfx += s;
            }
            int wtot = __shfl(pfx, 63, 64);
            u32 wb = 0;
            if (lane == 0) wb = atomicAdd(&lcnt[rr], (u32)wtot);
            wb = __shfl((int)wb, 0, 64);
            int o = (int)wb + pfx - cnt;
            u16* ridx = c.ridx[m] + (size_t)(r0 + rr) * 2048;
            #pragma unroll
            for (int i = 0; i < 8; i++) {
                if (v[rr][i] != 0.f) ridx[o++] = (u16)(c0 + i);
            }
        }
        __syncthreads();
        if (t < 4) c.rcnt[m][r0 + t] = lcnt[t];
    } else {
        int idx = bx - 1536;
        int seg = idx >> 6, xb = idx & 63;
        int n = a.n[seg];
        const void* s = a.src[seg];
        u16* d = base + a.off[seg];
        int nw = n >> 1;
        if (f32) {
            const float2* sf = (const float2*)s;
            u32* dw = (u32*)d;
            for (int i = xb * 256 + t; i < nw; i += 16384) {
                float2 v = sf[i];
                dw[i] = (u32)f2bf(v.x) | ((u32)f2bf(v.y) << 16);
            }
        } else {
            const u32* sw = (const u32*)s;
            u32* dw = (u32*)d;
            for (int i = xb * 256 + t; i < nw; i += 16384) dw[i] = sw[i];
        }
        if ((n & 1) && xb == 0 && t == 0)
            d[n - 1] = f32 ? f2bf(((const float*)s)[n - 1]) : ((const u16*)s)[n - 1];
    }
}

// ---------------- merged prep ------------------------------------------
// [0,4):        colsum + bias combine
// [4,2052):     colbuild (e_p column lists; ~0.4 entries/thread, latency
//               hidden by ~8K resident waves)
// [2052,3076):  avg aggregation (task = (id>>9): 0=e_e->A_e+128, 1=p_p->A_p+128)
// [3076,4100):  koqs-v2 (8 row-units/block, W staged in LDS)
// [4100,4196):  tpose_smalls (96 tiles)
struct PR {
    const u16* demb; const u16* pemb;
    const u16* Wa1d; const u16* ba1d;
    const u16* Wa1p; const u16* ba1p;
    float* ko_d; float* qs_d; float* ko_p; float* qs_p;
    const u16* idx0; const u32* cnt0; u16* cidx; u32* ccnt;
    const u16* ts[6]; u16* W1T; u16* W2T; u16* WcTe; u16* WcTp;
    const u16* ba[3]; const u16* bb[3]; u16* b_e; u16* b_p;
    float* csd; float* csp;
    const u16* avgidx[2]; const u32* avgcnt[2]; const u16* avgemb[2]; u16* avgout[2];
};

__global__ __launch_bounds__(256) void prep2(PR p) {
    int bx = blockIdx.x;
    int tid = threadIdx.x;
    __shared__ float sx[2][128];
    __shared__ float sred[2][128];
    __shared__ u16 stile[32][33];
    __shared__ float st0[256], st1[256];
    __shared__ u16 Wl[4096];

    if (bx < 4) {
        // ---- colsum (f32) + bias combine; block owns 64 dims of one matrix
        int id = bx;             // 0..3
        int m = id >> 1, half = id & 1;
        const u16* e = m ? p.pemb : p.demb;
        int c2 = tid & 31, rg = tid >> 5;     // 32 dim-pairs x 8 row-groups
        int dbase = half * 64;
        float s0 = 0.f, s1 = 0.f;
        for (int it = 0; it < 256; it++) {
            int row = it * 8 + rg;
            u32 v = *(const u32*)(e + (size_t)row * 128 + dbase + c2 * 2);
            s0 += bf2f((u16)(v & 0xffffu));
            s1 += bf2f((u16)(v >> 16));
        }
        st0[tid] = s0; st1[tid] = s1;
        __syncthreads();
        if (tid < 32) {
            float a0 = 0.f, a1 = 0.f;
            #pragma unroll
            for (int g = 0; g < 8; g++) { a0 += st0[g * 32 + tid]; a1 += st1[g * 32 + tid]; }
            float* cs = m ? p.csp : p.csd;
            cs[dbase + tid * 2 + 0] = a0;
            cs[dbase + tid * 2 + 1] = a1;
        }
        if (tid < 64) {
            int d = dbase + tid;
            if (m == 0)
                p.b_e[d] = f2bf(bf2f(p.ba[0][d]) + bf2f(p.ba[1][d]) + bf2f(p.ba[2][d]));
            else
                p.b_p[d] = f2bf(bf2f(p.bb[0][d]) + bf2f(p.bb[1][d]) + bf2f(p.bb[2][d]));
        }
    } else if (bx < 2052) {
        // ---- colbuild: e_p column lists from row CSR (entry-parallel)
        int r = bx - 4;
        int n = (int)p.cnt0[r];
        const u16* row = p.idx0 + (size_t)r * 2048;
        for (int i = tid; i < n; i += 256) {
            int cc = (int)row[i];
            u32 q = atomicAdd(&p.ccnt[cc], 1u);
            p.cidx[(size_t)cc * 2048 + q] = (u16)r;
        }
    } else if (bx < 3076) {
        // ---- avg aggregation (knn branch): 4 rows per block
        int id = bx - 2052;
        int task = id >> 9, blk = id & 511;
        int wv = tid >> 6, lane = tid & 63;
        int grp = lane >> 4, dim = lane & 15;
        int r = blk * 4 + wv;
        const u16* idx = p.avgidx[task] + (size_t)r * 2048;
        int nnz = (int)p.avgcnt[task][r];
        const u16* emb = p.avgemb[task];
        float acc[8];
        #pragma unroll
        for (int t = 0; t < 8; t++) acc[t] = 0.f;
        for (int base = 0; base < nnz; base += 64) {
            int i = base + lane;
            int j = (i < nnz) ? (int)idx[i] : 0;
            int cend = min(64, nnz - base);
            #pragma unroll 4
            for (int k4 = 0; k4 < cend; k4 += 4) {
                int kk = k4 + grp;
                int jk = __shfl(j, kk, 64);
                float wk = (base + kk < nnz) ? 1.f : 0.f;
                const uint4* pp = (const uint4*)((const char*)emb + jk * 256 + dim * 16);
                uint4 vv = *pp;
                u32 u[4] = {vv.x, vv.y, vv.z, vv.w};
                #pragma unroll
                for (int cc = 0; cc < 4; cc++) {
                    acc[2 * cc + 0] = fmaf(wk, bf2f((u16)(u[cc] & 0xffffu)), acc[2 * cc + 0]);
                    acc[2 * cc + 1] = fmaf(wk, bf2f((u16)(u[cc] >> 16)), acc[2 * cc + 1]);
                }
            }
        }
        #pragma unroll
        for (int t = 0; t < 8; t++) {
            acc[t] += __shfl_xor(acc[t], 32, 64);
            acc[t] += __shfl_xor(acc[t], 16, 64);
        }
        if (grp == 0) {
            float sc = 1.f / ((float)nnz + 1e-8f);
            float v[8];
            #pragma unroll
            for (int t = 0; t < 8; t++) v[t] = acc[t] * sc;
            uint4 pk;
            pk.x = (u32)f2bf(v[0]) | ((u32)f2bf(v[1]) << 16);
            pk.y = (u32)f2bf(v[2]) | ((u32)f2bf(v[3]) << 16);
            pk.z = (u32)f2bf(v[4]) | ((u32)f2bf(v[5]) << 16);
            pk.w = (u32)f2bf(v[6]) | ((u32)f2bf(v[7]) << 16);
            *(uint4*)(p.avgout[task] + (size_t)r * 256 + dim * 8) = pk;
        }
    } else if (bx < 4100) {
        // ---- koqs-v2: 8 row-units per block, W staged in LDS (8 KB)
        int blk = bx - 3076;       // 0..1023
        int m = blk >> 8;          // 256 blocks per matrix m
        int r0 = (blk & 255) * 8;  // 8 rows per block
        const u16* src; const u16* W; const u16* bias; float* out;
        switch (m) {
            case 0:  src = p.pemb; W = p.Wa1d;            bias = nullptr; out = p.ko_d; break;
            case 1:  src = p.demb; W = p.Wa1d + 128 * 32; bias = p.ba1d;  out = p.qs_d; break;
            case 2:  src = p.demb; W = p.Wa1p;            bias = nullptr; out = p.ko_p; break;
            default: src = p.pemb; W = p.Wa1p + 128 * 32; bias = p.ba1p;  out = p.qs_p; break;
        }
        {
            const uint4* wsrc = (const uint4*)W;    // 4096 u16 = 512 uint4
            uint4* wdst = (uint4*)Wl;
            #pragma unroll
            for (int i = 0; i < 2; i++) wdst[i * 256 + tid] = wsrc[i * 256 + tid];
        }
        __syncthreads();
        int sub = tid >> 7, t = tid & 127;
        int a = t & 31, part = t >> 5;
        #pragma unroll 1
        for (int rp = 0; rp < 4; rp++) {
            int row = r0 + rp * 2 + sub;
            sx[sub][t] = bf2f(src[(size_t)row * 128 + t]);
            __syncthreads();
            float s = 0.f;
            #pragma unroll
            for (int k = 0; k < 32; k++)
                s += sx[sub][part * 32 + k] * bf2f(Wl[(part * 32 + k) * 32 + a]);
            sred[sub][t] = s;
            __syncthreads();
            if (part == 0) {
                float tt = sred[sub][a] + sred[sub][a + 32] + sred[sub][a + 64] + sred[sub][a + 96];
                if (bias) tt += bf2f(bias[a]);
                out[(size_t)row * 32 + a] = tt;
            }
            __syncthreads();
        }
    } else {
        // ---- tpose_smalls
        int id = bx - 4100;
        int z = id >> 4, rem = id & 15;
        int c0 = (rem & 3) * 32, r0 = (rem >> 2) * 32;
        const u16* in = p.ts[z];
        u16* out; int ldo, ooff;
        switch (z) {
            case 0:  out = p.W1T;  ldo = 128; ooff = 0;   break;
            case 1:  out = p.W2T;  ldo = 128; ooff = 0;   break;
            case 2:  out = p.WcTe; ldo = 256; ooff = 0;   break;
            case 3:  out = p.WcTe; ldo = 256; ooff = 128; break;
            case 4:  out = p.WcTp; ldo = 256; ooff = 0;   break;
            default: out = p.WcTp; ldo = 256; ooff = 128; break;
        }
        int tx = tid & 31, ty = tid >> 5;
        int x = c0 + tx;
        for (int i = ty; i < 32; i += 8)
            stile[i][tx] = in[(size_t)(r0 + i) * 128 + x];
        __syncthreads();
        int rr = r0 + tx;
        for (int i = ty; i < 32; i += 8)
            out[(size_t)(c0 + i) * ldo + ooff + rr] = stile[tx][i];
    }
}

// ---------------- sparse attention aggregation (2 attn tasks only) ---------
struct SP {
    const u16* idx[2]; const u32* cnt[2];
    const float* ko[2]; const float* qs[2];
    const u16* w2[2]; const u16* b2[2];
    const u16* emb[2]; const float* csum[2];
    u16* out[2];
};

__global__ __launch_bounds__(256) void spagg(SP a) {
    int task = blockIdx.y;
    int tid = threadIdx.x;
    int wv = tid >> 6, lane = tid & 63;
    int grp = lane >> 4, dim = lane & 15;
    int r = blockIdx.x * 4 + wv;
    const u16* idx = a.idx[task] + (size_t)r * 2048;
    int nnz = (int)a.cnt[task][r];
    const u16* emb = a.emb[task];
    const float* ko = a.ko[task];

    float qsr[32], w2h[32];
    {
        const float4* qp = (const float4*)(a.qs[task] + (size_t)r * 32);
        #pragma unroll
        for (int i = 0; i < 8; i++) {
            float4 v = qp[i];
            qsr[4 * i + 0] = v.x; qsr[4 * i + 1] = v.y;
            qsr[4 * i + 2] = v.z; qsr[4 * i + 3] = v.w;
        }
        #pragma unroll
        for (int i = 0; i < 32; i++) w2h[i] = bf2f(a.w2[task][i]);
    }
    float b2v = bf2f(a.b2[task][0]);

    float acc[8];
    #pragma unroll
    for (int t = 0; t < 8; t++) acc[t] = 0.f;
    float wsuml = 0.f;

    for (int base = 0; base < nnz; base += 64) {
        int i = base + lane;
        float w = 0.f;
        int j = 0;
        if (i < nnz) {
            j = (int)idx[i];
            const float4* kp = (const float4*)(ko + (size_t)j * 32);
            float s = 0.f;
            #pragma unroll
            for (int q = 0; q < 8; q++) {
                float4 kv = kp[q];
                s += fmaxf(qsr[4 * q + 0] + kv.x, 0.f) * w2h[4 * q + 0];
                s += fmaxf(qsr[4 * q + 1] + kv.y, 0.f) * w2h[4 * q + 1];
                s += fmaxf(qsr[4 * q + 2] + kv.z, 0.f) * w2h[4 * q + 2];
                s += fmaxf(qsr[4 * q + 3] + kv.w, 0.f) * w2h[4 * q + 3];
            }
            w = __expf(fmaxf(s + b2v, 0.f)) - 1.f;
            wsuml += w;
        }
        int cend = min(64, nnz - base);
        #pragma unroll 4
        for (int k4 = 0; k4 < cend; k4 += 4) {
            int kk = k4 + grp;
            float wk = __shfl(w, kk, 64);
            int jk = __shfl(j, kk, 64);
            const uint4* pp = (const uint4*)((const char*)emb + jk * 256 + dim * 16);
            uint4 vv = *pp;
            u32 u[4] = {vv.x, vv.y, vv.z, vv.w};
            #pragma unroll
            for (int cc = 0; cc < 4; cc++) {
                acc[2 * cc + 0] = fmaf(wk, bf2f((u16)(u[cc] & 0xffffu)), acc[2 * cc + 0]);
                acc[2 * cc + 1] = fmaf(wk, bf2f((u16)(u[cc] >> 16)), acc[2 * cc + 1]);
            }
        }
    }

    #pragma unroll
    for (int t = 0; t < 8; t++) {
        acc[t] += __shfl_xor(acc[t], 32, 64);
        acc[t] += __shfl_xor(acc[t], 16, 64);
    }
    #pragma unroll
    for (int o = 32; o > 0; o >>= 1) wsuml += __shfl_xor(wsuml, o, 64);

    if (grp == 0) {
        float sc = 1.f / (2048.f + wsuml);
        const float* cs = a.csum[task] + dim * 8;
        float v[8];
        #pragma unroll
        for (int t = 0; t < 8; t++) v[t] = (cs[t] + acc[t]) * sc;
        uint4 pk;
        pk.x = (u32)f2bf(v[0]) | ((u32)f2bf(v[1]) << 16);
        pk.y = (u32)f2bf(v[2]) | ((u32)f2bf(v[3]) << 16);
        pk.z = (u32)f2bf(v[4]) | ((u32)f2bf(v[5]) << 16);
        pk.w = (u32)f2bf(v[6]) | ((u32)f2bf(v[7]) << 16);
        *(uint4*)(a.out[task] + (size_t)r * 256 + dim * 8) = pk;
    }
}

// ---------------- MFMA GEMM: canonical LDS-tiled (combine stage) -----------
struct GD4 {
    const void* A[4]; const u16* BT[4]; u16* C[4];
    const u16* bias[4]; const float* rs[4];
    int lda[4], ldb[4], ldc[4], coff[4], kiters[4], act[4], araw[4], rsmode[4];
};

#define PADK 136

__global__ __launch_bounds__(256, 2) void gemmL(GD4 g, const u32* __restrict__ flag) {
    __shared__ __align__(16) u16 As[16][PADK];
    __shared__ __align__(16) u16 Bs[128][PADK];
    int z = blockIdx.y;
    const void* A = g.A[z];
    const u16* BT = g.BT[z];
    int lda = g.lda[z], ldb = g.ldb[z];
    int kiters = g.kiters[z];
    int tid = threadIdx.x;
    int lane = tid & 63, wv = tid >> 6;
    int mrow = lane & 15, quad = lane >> 4;
    int m0 = blockIdx.x * 16;
    int c0 = wv * 32;
    int sr = tid >> 4, sk = (tid & 15) * 8;
    f32x4 acc0 = {0.f, 0.f, 0.f, 0.f}, acc1 = {0.f, 0.f, 0.f, 0.f};

    short8 ra, rb[8];
    auto ldstage = [&](int kb) {
        ra = *(const short8*)((const u16*)A + (size_t)(m0 + sr) * lda + kb + sk);
        const u16* bbase = BT + (size_t)sr * ldb + kb + sk;
        #pragma unroll
        for (int i = 0; i < 8; i++)
            rb[i] = *(const short8*)(bbase + (size_t)i * 16 * ldb);
    };
    auto ststage = [&]() {
        *(short8*)(&As[sr][sk]) = ra;
        #pragma unroll
        for (int i = 0; i < 8; i++)
            *(short8*)(&Bs[i * 16 + sr][sk]) = rb[i];
    };
    auto compute = [&]() {
        #pragma unroll
        for (int ks = 0; ks < 4; ks++) {
            short8 af = *(const short8*)(&As[mrow][ks * 32 + quad * 8]);
            short8 b0 = *(const short8*)(&Bs[c0 + mrow][ks * 32 + quad * 8]);
            short8 b1 = *(const short8*)(&Bs[c0 + 16 + mrow][ks * 32 + quad * 8]);
            acc0 = __builtin_amdgcn_mfma_f32_16x16x32_bf16(af, b0, acc0, 0, 0, 0);
            acc1 = __builtin_amdgcn_mfma_f32_16x16x32_bf16(af, b1, acc1, 0, 0, 0);
        }
    };

    ldstage(0);
    #pragma unroll 1
    for (int it = 0; it < kiters - 1; ++it) {
        ststage();
        __syncthreads();
        ldstage((it + 1) * 128);
        compute();
        __syncthreads();
    }
    ststage();
    __syncthreads();
    compute();

    const float* rs = g.rs[z];
    int rsmode = g.rsmode[z];
    const u16* bi = g.bias[z];
    u16* C = g.C[z];
    int ldc = g.ldc[z], coff = g.coff[z], act = g.act[z];
    int n0 = c0 + mrow, n1 = n0 + 16;
    float bv0 = bi ? bf2f(bi[n0]) : 0.f;
    float bv1 = bi ? bf2f(bi[n1]) : 0.f;
    #pragma unroll
    for (int r = 0; r < 4; r++) {
        int row = m0 + quad * 4 + r;
        float v0 = acc0[r], v1 = acc1[r];
        if (rsmode == 1) { float sc = rs[row]; v0 *= sc; v1 *= sc; }
        else if (rsmode == 2) {
            float t = 0.f;
            #pragma unroll
            for (int p = 0; p < 8; p++) t += rs[row + p * 2048];
            float sc = 1.f / t;
            v0 *= sc; v1 *= sc;
        }
        v0 += bv0; v1 += bv1;
        if (act) { v0 = seluf(v0); v1 = seluf(v1); }
        C[(size_t)row * ldc + coff + n0] = f2bf(v0);
        C[(size_t)row * ldc + coff + n1] = f2bf(v1);
    }
}

// ---------------- fused pair MLP + loss finalization -----------------------
#define PADX 136
__global__ __launch_bounds__(256, 2) void mlpfused(
    const u16* __restrict__ he, const u16* __restrict__ hp,
    const int* __restrict__ di, const int* __restrict__ dr,
    const u16* __restrict__ W1T, const u16* __restrict__ b1,
    const u16* __restrict__ W2T, const u16* __restrict__ b2,
    const u16* __restrict__ wpred, const u16* __restrict__ bpred,
    const int* __restrict__ labels,
    float* __restrict__ out, float* __restrict__ lossacc,
    u32* __restrict__ losscnt) {
    __shared__ __align__(16) u16 Xs[64][PADX];
    __shared__ __align__(16) u16 Ws[128][PADX];
    __shared__ float wred[4];
    int tid = threadIdx.x;
    int lane = tid & 63, wv = tid >> 6;
    int mrow = lane & 15, quad = lane >> 4;
    int p0 = blockIdx.x * 64;

    {
        int row = tid >> 2, sub = tid & 3;
        int b = p0 + row;
        int ia = di[b], ic = dr[b];
        const uint4* pe = (const uint4*)(he + (size_t)ia * 128 + sub * 32);
        const uint4* pp = (const uint4*)(hp + (size_t)ic * 128 + sub * 32);
        #pragma unroll
        for (int q = 0; q < 4; q++) {
            uint4 ue = pe[q], up = pp[q];
            u32 eu[4] = {ue.x, ue.y, ue.z, ue.w};
            u32 pu[4] = {up.x, up.y, up.z, up.w};
            #pragma unroll
            for (int c = 0; c < 4; c++) {
                float lo = bf2f((u16)(eu[c] & 0xffffu)) * bf2f((u16)(pu[c] & 0xffffu));
                float hi = bf2f((u16)(eu[c] >> 16)) * bf2f((u16)(pu[c] >> 16));
                *(u32*)(&Xs[row][sub * 32 + q * 8 + c * 2]) =
                    (u32)f2bf(lo) | ((u32)f2bf(hi) << 16);
            }
        }
    }
    {
        int n = tid >> 1, half = tid & 1;
        const short8* src = (const short8*)(W1T + (size_t)n * 128 + half * 64);
        short8* dst = (short8*)(&Ws[n][half * 64]);
        #pragma unroll
        for (int i = 0; i < 8; i++) dst[i] = src[i];
    }
    __syncthreads();

    f32x4 acc[8];
    #pragma unroll
    for (int nt = 0; nt < 8; nt++) acc[nt] = {0.f, 0.f, 0.f, 0.f};
    #pragma unroll
    for (int ks = 0; ks < 4; ks++) {
        short8 af = *(const short8*)(&Xs[wv * 16 + mrow][ks * 32 + quad * 8]);
        #pragma unroll
        for (int nt = 0; nt < 8; nt++) {
            short8 bfv = *(const short8*)(&Ws[nt * 16 + mrow][ks * 32 + quad * 8]);
            acc[nt] = __builtin_amdgcn_mfma_f32_16x16x32_bf16(af, bfv, acc[nt], 0, 0, 0);
        }
    }
    __syncthreads();
    #pragma unroll
    for (int nt = 0; nt < 8; nt++) {
        int col = nt * 16 + mrow;
        float bv = bf2f(b1[col]);
        #pragma unroll
        for (int r = 0; r < 4; r++) {
            int row = wv * 16 + quad * 4 + r;
            Xs[row][col] = f2bf(seluf(acc[nt][r] + bv));
        }
    }
    {
        int n = tid >> 1, half = tid & 1;
        const short8* src = (const short8*)(W2T + (size_t)n * 128 + half * 64);
        short8* dst = (short8*)(&Ws[n][half * 64]);
        #pragma unroll
        for (int i = 0; i < 8; i++) dst[i] = src[i];
    }
    __syncthreads();

    #pragma unroll
    for (int nt = 0; nt < 8; nt++) acc[nt] = {0.f, 0.f, 0.f, 0.f};
    #pragma unroll
    for (int ks = 0; ks < 4; ks++) {
        short8 af = *(const short8*)(&Xs[wv * 16 + mrow][ks * 32 + quad * 8]);
        #pragma unroll
        for (int nt = 0; nt < 8; nt++) {
            short8 bfv = *(const short8*)(&Ws[nt * 16 + mrow][ks * 32 + quad * 8]);
            acc[nt] = __builtin_amdgcn_mfma_f32_16x16x32_bf16(af, bfv, acc[nt], 0, 0, 0);
        }
    }

    float zp[4] = {0.f, 0.f, 0.f, 0.f};
    #pragma unroll
    for (int nt = 0; nt < 8; nt++) {
        int col = nt * 16 + mrow;
        float bv = bf2f(b2[col]);
        float wp = bf2f(wpred[col]);
        #pragma unroll
        for (int r = 0; r < 4; r++) {
            float x2 = bf2f(f2bf(seluf(acc[nt][r] + bv)));
            zp[r] = fmaf(x2, wp, zp[r]);
        }
    }
    #pragma unroll
    for (int r = 0; r < 4; r++) {
        #pragma unroll
        for (int o = 1; o < 16; o <<= 1) zp[r] += __shfl_xor(zp[r], o, 64);
    }
    float bpv = bf2f(bpred[0]);
    float lsum = 0.f;
    #pragma unroll
    for (int r = 0; r < 4; r++) {
        int b = p0 + wv * 16 + quad * 4 + r;
        float z = zp[r] + bpv;
        float sig = 1.f / (1.f + __expf(-z));
        if (mrow == 0) out[1 + b] = sig;
        float y = (float)labels[b];
        lsum += fmaxf(z, 0.f) - z * y + log1pf(__expf(-fabsf(z)));
    }
    // quad-only butterfly: 16 mrow lanes hold identical lsum (zp reduced over
    // mrow), so the result is the exact 16-row wave sum on every lane.
    lsum += __shfl_xor(lsum, 16, 64);
    lsum += __shfl_xor(lsum, 32, 64);
    if (lane == 0) wred[wv] = lsum;
    __syncthreads();
    if (tid == 0) {
        float bs = wred[0] + wred[1] + wred[2] + wred[3];
        atomicAdd(lossacc, bs);
        __threadfence();
        u32 old = atomicAdd(losscnt, 1u);
        if (old == 255u) {
            float tot = atomicAdd(lossacc, 0.f);
            out[0] = tot * (1.f / 16384.f);
        }
    }
}

// ---------------- launch ----------------
extern "C" void kernel_launch(void* const* d_in, const int* in_sizes, int n_in,
                              void* d_out, int out_size, void* d_ws, size_t ws_size,
                              hipStream_t stream) {
    const void* e_p_adj = d_in[0];
    const void* e_e_adj = d_in[1];
    const void* p_p_adj = d_in[2];
    const int* in_dis  = (const int*)d_in[3];
    const int* in_drug = (const int*)d_in[4];
    const int* labels  = (const int*)d_in[5];
    float* out = (float*)d_out;

    // -------- workspace layout --------
    char* ws = (char*)d_ws;
    size_t off = 0;
    auto take = [&](size_t bytes) { char* p = ws + off; off = (off + bytes + 255) & ~(size_t)255; return p; };
    u16*   A_e   = (u16*)take((size_t)2048 * 256 * 2);
    u16*   A_p   = (u16*)take((size_t)2048 * 256 * 2);
    u16*   WcTe  = (u16*)take((size_t)128 * 256 * 2);
    u16*   WcTp  = (u16*)take((size_t)128 * 256 * 2);
    u16*   W1T   = (u16*)take((size_t)128 * 128 * 2);
    u16*   W2T   = (u16*)take((size_t)128 * 128 * 2);
    u16*   b_e   = (u16*)take(256);
    u16*   b_p   = (u16*)take(256);
    u16*   h_e   = (u16*)take((size_t)2048 * 128 * 2);
    u16*   h_p   = (u16*)take((size_t)2048 * 128 * 2);
    float* ko_d  = (float*)take((size_t)2048 * 32 * 4);
    float* qs_d  = (float*)take((size_t)2048 * 32 * 4);
    float* ko_p  = (float*)take((size_t)2048 * 32 * 4);
    float* qs_p  = (float*)take((size_t)2048 * 32 * 4);
    float* csd   = (float*)take(128 * 4);
    float* csp   = (float*)take(128 * 4);
    float* lossacc = (float*)take(256);
    u32*   losscnt = (u32*)((char*)lossacc + 4);
    u32*   flag  = (u32*)take(256);
    u16*   canon = (u16*)take((size_t)700000 * 2);
    u16*   idx0  = (u16*)take((size_t)2048 * 2048 * 2);  // e_p rows (disease)
    u16*   idx1  = (u16*)take((size_t)2048 * 2048 * 2);  // e_p cols (drug)
    u16*   idx2  = (u16*)take((size_t)2048 * 2048 * 2);  // e_e rows
    u16*   idx3  = (u16*)take((size_t)2048 * 2048 * 2);  // p_p rows
    u32*   cnt0  = (u32*)take(2048 * 4);
    u32*   cnt2  = (u32*)take(2048 * 4);
    u32*   cnt3  = (u32*)take(2048 * 4);
    u32*   cntT  = (u32*)take(2048 * 4);                 // e_p col counts

    // -------- canonical parameter table --------
    const int segidx[NSEG] = {6, 7, 14, 18, 8, 22, 11, 24, 26, 28,
                              15, 16, 17, 19, 20, 21,
                              9, 10, 12, 13, 23, 25, 27, 29, 30, 31};
    const int segn[NSEG]   = {262144, 262144, 8192, 8192, 16384, 16384, 16384, 16384, 16384, 16384,
                              32, 32, 1, 32, 32, 1,
                              128, 128, 128, 128, 128, 128, 128, 128, 128, 1};
    CvtArgs ca;
    u16* cp[NSEG];
    {
        int o = 0;
        for (int i = 0; i < NSEG; i++) {
            ca.src[i] = d_in[segidx[i]];
            ca.off[i] = o;
            ca.n[i] = segn[i];
            cp[i] = canon + o;
            o += (segn[i] + 15) & ~15;
        }
    }
    u16 *cdemb = cp[0], *cpemb = cp[1], *cWa1d = cp[2], *cWa1p = cp[3];
    u16 *cWdg = cp[4], *cWd2 = cp[5], *cWpg = cp[6], *cWp3 = cp[7];
    u16 *cW1 = cp[8], *cW2 = cp[9];
    u16 *cba1d = cp[10], *cWa2d = cp[11], *cba2d = cp[12];
    u16 *cba1p = cp[13], *cWa2p = cp[14], *cba2p = cp[15];
    u16 *cbdg_lin = cp[16], *cbdg = cp[17], *cbpg_lin = cp[18], *cbpg = cp[19];
    u16 *cbd2 = cp[20], *cbp3 = cp[21], *cmb1 = cp[22], *cmb2 = cp[23];
    u16 *cWpred = cp[24], *cbpred = cp[25];

    // -------- 0. dtype detection + per-iteration zeroing --------
    detectk<<<1, 256, 0, stream>>>(d_in[6], flag, cntT, lossacc, losscnt);

    // -------- 1. merged conversion + CSR row lists --------
    {
        CS cs;
        cs.adj[0] = e_p_adj; cs.ridx[0] = idx0; cs.rcnt[0] = cnt0;
        cs.adj[1] = e_e_adj; cs.ridx[1] = idx2; cs.rcnt[1] = cnt2;
        cs.adj[2] = p_p_adj; cs.ridx[2] = idx3; cs.rcnt[2] = cnt3;
        cvtcsr<<<1536 + 64 * NSEG, 256, 0, stream>>>(ca, canon, cs, flag);
    }

    // -------- 2. merged prep (colsum + colbuild + avg-agg + koqs + tpose) ---
    PR pr;
    pr.demb = cdemb; pr.pemb = cpemb;
    pr.Wa1d = cWa1d; pr.ba1d = cba1d; pr.Wa1p = cWa1p; pr.ba1p = cba1p;
    pr.ko_d = ko_d; pr.qs_d = qs_d; pr.ko_p = ko_p; pr.qs_p = qs_p;
    pr.idx0 = idx0; pr.cnt0 = cnt0; pr.cidx = idx1; pr.ccnt = cntT;
    pr.ts[0] = cW1; pr.ts[1] = cW2; pr.ts[2] = cWdg;
    pr.ts[3] = cWd2; pr.ts[4] = cWpg; pr.ts[5] = cWp3;
    pr.W1T = W1T; pr.W2T = W2T; pr.WcTe = WcTe; pr.WcTp = WcTp;
    pr.ba[0] = cbdg_lin; pr.ba[1] = cbdg; pr.ba[2] = cbd2;
    pr.bb[0] = cbpg_lin; pr.bb[1] = cbpg; pr.bb[2] = cbp3;
    pr.b_e = b_e; pr.b_p = b_p; pr.csd = csd; pr.csp = csp;
    pr.avgidx[0] = idx2; pr.avgcnt[0] = cnt2; pr.avgemb[0] = cdemb; pr.avgout[0] = A_e + 128;
    pr.avgidx[1] = idx3; pr.avgcnt[1] = cnt3; pr.avgemb[1] = cpemb; pr.avgout[1] = A_p + 128;
    prep2<<<4196, 256, 0, stream>>>(pr);

    // -------- 3. sparse attention aggregation (2 tasks) --------
    {
        SP sp;
        sp.idx[0] = idx0; sp.cnt[0] = cnt0; sp.ko[0] = ko_d; sp.qs[0] = qs_d;
        sp.w2[0] = cWa2d; sp.b2[0] = cba2d; sp.emb[0] = cpemb; sp.csum[0] = csp;
        sp.out[0] = A_e;
        sp.idx[1] = idx1; sp.cnt[1] = cntT; sp.ko[1] = ko_p; sp.qs[1] = qs_p;
        sp.w2[1] = cWa2p; sp.b2[1] = cba2p; sp.emb[1] = cdemb; sp.csum[1] = csd;
        sp.out[1] = A_p;
        spagg<<<dim3(512, 2), 256, 0, stream>>>(sp);
    }

    auto setd = [](GD4& g, int z, const void* A, int lda, const u16* BT, int ldb,
                   u16* C, int ldc, int coff, int ki, const u16* bi,
                   const float* rs, int act, int araw, int rm) {
        g.A[z] = A; g.lda[z] = lda; g.BT[z] = BT; g.ldb[z] = ldb;
        g.C[z] = C; g.ldc[z] = ldc; g.coff[z] = coff; g.kiters[z] = ki;
        g.bias[z] = bi; g.rs[z] = rs; g.act[z] = act; g.araw[z] = araw; g.rsmode[z] = rm;
    };

    // -------- 4. combine GEMMs (bias + SELU), batched ----------------------
    {
        GD4 g;
        setd(g, 0, A_e, 256, WcTe, 256, h_e, 128, 0, 2, b_e, nullptr, 1, 0, 0);
        setd(g, 1, A_p, 256, WcTp, 256, h_p, 128, 0, 2, b_p, nullptr, 1, 0, 0);
        setd(g, 2, A_e, 256, WcTe, 256, h_e, 128, 0, 2, b_e, nullptr, 1, 0, 0);
        setd(g, 3, A_e, 256, WcTe, 256, h_e, 128, 0, 2, b_e, nullptr, 1, 0, 0);
        gemmL<<<dim3(128, 2), 256, 0, stream>>>(g, flag);
    }

    // -------- 5. fused pair MLP + loss --------
    mlpfused<<<256, 256, 0, stream>>>(h_e, h_p, in_dis, in_drug,
                                      W1T, cmb1, W2T, cmb2,
                                      cWpred, cbpred, labels, out,
                                      lossacc, losscnt);
}